// Round 6
// baseline (641.591 us; speedup 1.0000x reference)
//
#include <hip/hip_runtime.h>
#include <math.h>

#define F 128
#define OUTDIM 64
#define NEG 0.2f
#define BN3 128
#define KT2 32

// ---------------- utility ----------------
__global__ void zero_ints(int* __restrict__ p, int n) {
    int i = blockIdx.x * blockDim.x + threadIdx.x;
    if (i < n) p[i] = 0;
}

// ---------------- CSR build ----------------
__global__ void hist_kernel(const int* __restrict__ src, const int* __restrict__ dst,
                            int* __restrict__ degF, int* __restrict__ degR, int E) {
    int e = blockIdx.x * blockDim.x + threadIdx.x;
    if (e < E) {
        atomicAdd(&degF[dst[e]], 1);
        atomicAdd(&degR[src[e]], 1);
    }
}

__global__ void scan_pass1(const int* __restrict__ degF, const int* __restrict__ degR,
                           int* __restrict__ rsF, int* __restrict__ rsR,
                           int* __restrict__ bsums, int N) {
    const int arr = blockIdx.y;
    const int* deg = arr ? degR : degF;
    int* rs = arr ? rsR : rsF;
    int tid = threadIdx.x;
    int base = blockIdx.x * 1024 + tid * 4;
    int v[4];
#pragma unroll
    for (int i = 0; i < 4; i++) v[i] = (base + i < N) ? deg[base + i] : 0;
    int s1 = v[0] + v[1] + v[2] + v[3];
    __shared__ int sd[256];
    sd[tid] = s1;
    __syncthreads();
    for (int off = 1; off < 256; off <<= 1) {
        int t = (tid >= off) ? sd[tid - off] : 0;
        __syncthreads();
        sd[tid] += t;
        __syncthreads();
    }
    int run = sd[tid] - s1;
#pragma unroll
    for (int i = 0; i < 4; i++) {
        run += v[i];
        if (base + i < N) rs[base + i + 1] = run;
    }
    if (tid == 255) bsums[arr * 128 + blockIdx.x] = sd[255];
    if (tid == 0 && blockIdx.x == 0) rs[0] = 0;
}

__global__ void scan_pass2(int* __restrict__ bsums, int nb) {
    int arr = blockIdx.y;
    int tid = threadIdx.x;  // 128
    __shared__ int sd[128];
    int v = (tid < nb) ? bsums[arr * 128 + tid] : 0;
    sd[tid] = v;
    __syncthreads();
    for (int off = 1; off < 128; off <<= 1) {
        int t = (tid >= off) ? sd[tid - off] : 0;
        __syncthreads();
        sd[tid] += t;
        __syncthreads();
    }
    bsums[arr * 128 + tid] = sd[tid];
}

__global__ void scan_pass3(int* __restrict__ rsF, int* __restrict__ rsR,
                           const int* __restrict__ bsums, int N) {
    int arr = blockIdx.y;
    if (blockIdx.x == 0) return;
    int* rs = arr ? rsR : rsF;
    int off = bsums[arr * 128 + blockIdx.x - 1];
    int base = blockIdx.x * 1024 + threadIdx.x * 4;
#pragma unroll
    for (int i = 0; i < 4; i++)
        if (base + i < N) rs[base + i + 1] += off;
}

__global__ void scatter_kernel(const int* __restrict__ src, const int* __restrict__ dst,
                               const int* __restrict__ rsF, const int* __restrict__ rsR,
                               int* __restrict__ curF, int* __restrict__ curR,
                               int* __restrict__ colF, int* __restrict__ colR, int E) {
    int e = blockIdx.x * blockDim.x + threadIdx.x;
    if (e < E) {
        int s = src[e], d = dst[e];
        int pf = rsF[d] + atomicAdd(&curF[d], 1);
        colF[pf] = s;
        int pr = rsR[s] + atomicAdd(&curR[s], 1);
        colR[pr] = d;
    }
}

// ---------------- per-node attention scalars ----------------
__global__ void sd4_kernel(const float* __restrict__ x,
                           const float* __restrict__ af_s, const float* __restrict__ af_d,
                           const float* __restrict__ ar_s, const float* __restrict__ ar_d,
                           float* __restrict__ sf, float* __restrict__ df,
                           float* __restrict__ sr, float* __restrict__ dr, int N) {
    int node = blockIdx.x * 4 + (threadIdx.x >> 6);
    int lane = threadIdx.x & 63;
    if (node >= N) return;
    const float2 xv = *(const float2*)&x[(size_t)node * F + 2 * lane];
    float2 a;
    a = *(const float2*)&af_s[2 * lane]; float vsf = xv.x * a.x + xv.y * a.y;
    a = *(const float2*)&af_d[2 * lane]; float vdf = xv.x * a.x + xv.y * a.y;
    a = *(const float2*)&ar_s[2 * lane]; float vsr = xv.x * a.x + xv.y * a.y;
    a = *(const float2*)&ar_d[2 * lane]; float vdr = xv.x * a.x + xv.y * a.y;
#pragma unroll
    for (int off = 32; off > 0; off >>= 1) {
        vsf += __shfl_xor(vsf, off);
        vdf += __shfl_xor(vdf, off);
        vsr += __shfl_xor(vsr, off);
        vdr += __shfl_xor(vdr, off);
    }
    if (lane == 0) { sf[node] = vsf; df[node] = vdf; sr[node] = vsr; dr[node] = vdr; }
}

// ---------------- fused dual-direction attention hop ----------------
// quarter-wave (16 lanes x 8 floats) per node; blockIdx.y selects direction.
// 8-deep pipelined row gather, 2 float4 per row-lane -> 16 outstanding loads.
struct AggDir {
    const float* hin;   // [N][128]
    const float* s;     // [N]
    const float* d;     // [N]
    const int* rs;      // [N+1]
    const int* col;     // [E]
    float* hout;        // [N][128]
    const float* a_s;   // nullable: fused next-hop dots
    const float* a_d;
    float* s_out;
    float* d_out;
};

__global__ __launch_bounds__(256) void agg_kernel(AggDir D0, AggDir D1, int N) {
    AggDir P = blockIdx.y ? D1 : D0;
    int node = blockIdx.x * 16 + (threadIdx.x >> 4);
    int lane = threadIdx.x & 15;           // within quarter-wave
    int qbase = threadIdx.x & 48;          // quarter offset inside the wave
    if (node >= N) return;
    float di = P.d[node];
    int beg = P.rs[node], end = P.rs[node + 1];
    int deg = end - beg;
    float m = -INFINITY, l = 0.f;
    float4 a0 = make_float4(0.f, 0.f, 0.f, 0.f);
    float4 a1 = make_float4(0.f, 0.f, 0.f, 0.f);

    for (int base = 0; base < deg; base += 16) {
        int cnt = min(16, deg - base);
        int sj_l = 0;
        float e_l = -INFINITY;
        if (lane < cnt) {
            sj_l = P.col[beg + base + lane];
            float e = P.s[sj_l] + di;
            e_l = (e >= 0.f) ? e : NEG * e;
        }
        float bm = e_l;
#pragma unroll
        for (int off = 8; off > 0; off >>= 1) bm = fmaxf(bm, __shfl_xor(bm, off));
        float nm = fmaxf(m, bm);
        float p_l = (lane < cnt) ? __expf(e_l - nm) : 0.f;
        float ps = p_l;
#pragma unroll
        for (int off = 8; off > 0; off >>= 1) ps += __shfl_xor(ps, off);
        float sc = (m == -INFINITY) ? 0.f : __expf(m - nm);
        l = l * sc + ps;
        a0.x *= sc; a0.y *= sc; a0.z *= sc; a0.w *= sc;
        a1.x *= sc; a1.y *= sc; a1.z *= sc; a1.w *= sc;
        // 8-deep pipelined weighted row gather (p=0 for pad lanes -> harmless row-0 loads)
        for (int j0 = 0; j0 < cnt; j0 += 8) {
            int sj[8]; float p[8]; float4 h0[8], h1[8];
#pragma unroll
            for (int u = 0; u < 8; u++) {
                sj[u] = __shfl(sj_l, qbase + j0 + u);
                p[u]  = __shfl(p_l,  qbase + j0 + u);
            }
#pragma unroll
            for (int u = 0; u < 8; u++) {
                const float* rp = &P.hin[(size_t)sj[u] * F + 8 * lane];
                h0[u] = *(const float4*)(rp);
                h1[u] = *(const float4*)(rp + 4);
            }
#pragma unroll
            for (int u = 0; u < 8; u++) {
                a0.x += p[u] * h0[u].x; a0.y += p[u] * h0[u].y;
                a0.z += p[u] * h0[u].z; a0.w += p[u] * h0[u].w;
                a1.x += p[u] * h1[u].x; a1.y += p[u] * h1[u].y;
                a1.z += p[u] * h1[u].z; a1.w += p[u] * h1[u].w;
            }
        }
        m = nm;
    }

    float4 o0, o1;
    if (deg > 0) {
        float inv = 1.f / (l + 1e-16f);
        o0.x = a0.x * inv; o0.y = a0.y * inv; o0.z = a0.z * inv; o0.w = a0.w * inv;
        o1.x = a1.x * inv; o1.y = a1.y * inv; o1.z = a1.z * inv; o1.w = a1.w * inv;
    } else {
        o0 = make_float4(0.f, 0.f, 0.f, 0.f);
        o1 = o0;
    }
    float* op = &P.hout[(size_t)node * F + 8 * lane];
    *(float4*)(op) = o0;
    *(float4*)(op + 4) = o1;
    if (P.a_s) {
        float4 b0, b1;
        b0 = *(const float4*)&P.a_s[8 * lane];
        b1 = *(const float4*)&P.a_s[8 * lane + 4];
        float vs = o0.x * b0.x + o0.y * b0.y + o0.z * b0.z + o0.w * b0.w
                 + o1.x * b1.x + o1.y * b1.y + o1.z * b1.z + o1.w * b1.w;
        b0 = *(const float4*)&P.a_d[8 * lane];
        b1 = *(const float4*)&P.a_d[8 * lane + 4];
        float vd = o0.x * b0.x + o0.y * b0.y + o0.z * b0.z + o0.w * b0.w
                 + o1.x * b1.x + o1.y * b1.y + o1.z * b1.z + o1.w * b1.w;
#pragma unroll
        for (int off = 8; off > 0; off >>= 1) {
            vs += __shfl_xor(vs, off);
            vd += __shfl_xor(vd, off);
        }
        if (lane == 0) { P.s_out[node] = vs; P.d_out[node] = vd; }
    }
}

// ---------------- fold W blocks: Weff[640][64] ----------------
__global__ void weff_kernel(const float* __restrict__ W, float* __restrict__ Weff) {
    int i = blockIdx.x * blockDim.x + threadIdx.x;
    if (i >= 640 * 64) return;
    int r = i >> 6, o = i & 63;
    float v;
    if (r < 128)      v = W[r * 64 + o] + W[(r + 384) * 64 + o];
    else if (r < 384) v = W[r * 64 + o];
    else              v = W[(r + 128) * 64 + o];
    Weff[i] = v;
}

// ---------------- final dense: out = [x|h1f|h2f|h1r|h2r] @ Weff + b ----------------
// 128 threads, 8x8 micro-tile (1 B LDS per FMA -> LDS-BW balanced with FMA).
// Xs stride 132 (=4 mod 32): staging writes consecutive-row = 2-way free;
// reads ty*8 stride -> 2 rows per bank group = 2-way free. b128 16B-aligned.
__global__ __launch_bounds__(128, 3) void gemm_kernel(
    const float* __restrict__ X0, const float* __restrict__ H1F,
    const float* __restrict__ H2F, const float* __restrict__ H1R,
    const float* __restrict__ H2R,
    const float* __restrict__ Weff, const float* __restrict__ bias,
    float* __restrict__ out, int N) {
    __shared__ float Xs[KT2][BN3 + 4];  // 32 x 132
    __shared__ float Ws[KT2][68];
    const float* srcs[5] = {X0, H1F, H2F, H1R, H2R};
    int tid = threadIdx.x;              // 0..127
    int tx = tid & 7, ty = tid >> 3;    // col group tx*8, row group ty*8 (ty 0..15)
    int nodeBase = blockIdx.x * BN3;
    float acc[8][8];
#pragma unroll
    for (int i = 0; i < 8; i++)
#pragma unroll
        for (int j = 0; j < 8; j++) acc[i][j] = 0.f;

    for (int t = 0; t < 20; ++t) {
        const float* srcp = srcs[t >> 2];
        int cb = (t & 3) * 32;
        // stage X: one full row (32 k) per thread
        {
            int n = nodeBase + tid;
            float4 v[8];
            if (n < N) {
                const float* p = srcp + (size_t)n * 128 + cb;
#pragma unroll
                for (int q = 0; q < 8; q++) v[q] = *(const float4*)(p + q * 4);
            } else {
#pragma unroll
                for (int q = 0; q < 8; q++) v[q] = make_float4(0.f, 0.f, 0.f, 0.f);
            }
#pragma unroll
            for (int q = 0; q < 8; q++) {
                Xs[q * 4 + 0][tid] = v[q].x;
                Xs[q * 4 + 1][tid] = v[q].y;
                Xs[q * 4 + 2][tid] = v[q].z;
                Xs[q * 4 + 3][tid] = v[q].w;
            }
        }
        // stage W: 4 float4 per thread
#pragma unroll
        for (int q = 0; q < 4; q++) {
            int f = tid * 4 + q;            // 0..511
            int wr = f >> 4, wc4 = f & 15;
            *(float4*)&Ws[wr][wc4 * 4] =
                *(const float4*)&Weff[(size_t)(t * 32 + wr) * 64 + wc4 * 4];
        }
        __syncthreads();
#pragma unroll
        for (int k = 0; k < KT2; k++) {
            float4 x0 = *(const float4*)&Xs[k][ty * 8];
            float4 x1 = *(const float4*)&Xs[k][ty * 8 + 4];
            float4 w0 = *(const float4*)&Ws[k][tx * 8];
            float4 w1 = *(const float4*)&Ws[k][tx * 8 + 4];
            float xv[8] = {x0.x, x0.y, x0.z, x0.w, x1.x, x1.y, x1.z, x1.w};
            float wv[8] = {w0.x, w0.y, w0.z, w0.w, w1.x, w1.y, w1.z, w1.w};
#pragma unroll
            for (int i = 0; i < 8; i++)
#pragma unroll
                for (int j = 0; j < 8; j++) acc[i][j] += xv[i] * wv[j];
        }
        __syncthreads();
    }
    float4 bv0 = *(const float4*)&bias[tx * 8];
    float4 bv1 = *(const float4*)&bias[tx * 8 + 4];
#pragma unroll
    for (int i = 0; i < 8; i++) {
        int n = nodeBase + ty * 8 + i;
        if (n < N) {
            float4 o;
            float* po = &out[(size_t)n * 64 + tx * 8];
            o.x = acc[i][0] + bv0.x; o.y = acc[i][1] + bv0.y;
            o.z = acc[i][2] + bv0.z; o.w = acc[i][3] + bv0.w;
            *(float4*)(po) = o;
            o.x = acc[i][4] + bv1.x; o.y = acc[i][5] + bv1.y;
            o.z = acc[i][6] + bv1.z; o.w = acc[i][7] + bv1.w;
            *(float4*)(po + 4) = o;
        }
    }
}

extern "C" void kernel_launch(void* const* d_in, const int* in_sizes, int n_in,
                              void* d_out, int out_size, void* d_ws, size_t ws_size,
                              hipStream_t stream) {
    const float* feature = (const float*)d_in[0];
    const int*   eidx    = (const int*)d_in[1];
    const float* af_s    = (const float*)d_in[2];
    const float* af_d    = (const float*)d_in[3];
    const float* ar_s    = (const float*)d_in[4];
    const float* ar_d    = (const float*)d_in[5];
    const float* W       = (const float*)d_in[6];
    const float* bias    = (const float*)d_in[7];
    float* out = (float*)d_out;
    const int N = in_sizes[0] / F;
    const int E = in_sizes[1] / 2;
    const int* src = eidx;
    const int* dst = eidx + E;

    char* ws = (char*)d_ws;
    size_t off = 0;
    auto alloc = [&](size_t b) { size_t r = off; off = (off + b + 255) & ~(size_t)255; return r; };
    float* h1f = (float*)(ws + alloc((size_t)N * F * 4));
    float* h2f = (float*)(ws + alloc((size_t)N * F * 4));
    float* h1r = (float*)(ws + alloc((size_t)N * F * 4));
    float* h2r = (float*)(ws + alloc((size_t)N * F * 4));
    int*   rsF   = (int*)(ws + alloc((size_t)(N + 1) * 4));
    int*   rsR   = (int*)(ws + alloc((size_t)(N + 1) * 4));
    int*   colF  = (int*)(ws + alloc((size_t)E * 4));
    int*   colR  = (int*)(ws + alloc((size_t)E * 4));
    int*   ints4 = (int*)(ws + alloc((size_t)4 * N * 4));
    int *degF = ints4, *degR = ints4 + N, *curF = ints4 + 2 * N, *curR = ints4 + 3 * N;
    float* fls8 = (float*)(ws + alloc((size_t)8 * N * 4));
    float *sf = fls8, *df = fls8 + N, *sr = fls8 + 2 * (size_t)N, *dr = fls8 + 3 * (size_t)N;
    float *s2f = fls8 + 4 * (size_t)N, *d2f = fls8 + 5 * (size_t)N;
    float *s2r = fls8 + 6 * (size_t)N, *d2r = fls8 + 7 * (size_t)N;
    int*   bsums = (int*)(ws + alloc(256 * 4));
    float* Weff  = (float*)(ws + alloc(640 * 64 * 4));

    const int nb = (N + 1023) / 1024;
    zero_ints<<<(4 * N + 255) / 256, 256, 0, stream>>>(ints4, 4 * N);
    hist_kernel<<<(E + 255) / 256, 256, 0, stream>>>(src, dst, degF, degR, E);
    scan_pass1<<<dim3(nb, 2), 256, 0, stream>>>(degF, degR, rsF, rsR, bsums, N);
    scan_pass2<<<dim3(1, 2), 128, 0, stream>>>(bsums, nb);
    scan_pass3<<<dim3(nb, 2), 256, 0, stream>>>(rsF, rsR, bsums, N);
    scatter_kernel<<<(E + 255) / 256, 256, 0, stream>>>(src, dst, rsF, rsR, curF, curR, colF, colR, E);
    sd4_kernel<<<(N + 3) / 4, 256, 0, stream>>>(feature, af_s, af_d, ar_s, ar_d, sf, df, sr, dr, N);

    AggDir F1{feature, sf, df, rsF, colF, h1f, af_s, af_d, s2f, d2f};
    AggDir R1{feature, sr, dr, rsR, colR, h1r, ar_s, ar_d, s2r, d2r};
    agg_kernel<<<dim3((N + 15) / 16, 2), 256, 0, stream>>>(F1, R1, N);
    AggDir F2{h1f, s2f, d2f, rsF, colF, h2f, nullptr, nullptr, nullptr, nullptr};
    AggDir R2{h1r, s2r, d2r, rsR, colR, h2r, nullptr, nullptr, nullptr, nullptr};
    agg_kernel<<<dim3((N + 15) / 16, 2), 256, 0, stream>>>(F2, R2, N);

    weff_kernel<<<(640 * 64 + 255) / 256, 256, 0, stream>>>(W, Weff);
    gemm_kernel<<<(N + BN3 - 1) / BN3, 128, 0, stream>>>(feature, h1f, h2f, h1r, h2r, Weff, bias, out, N);
}

// Round 7
// 589.873 us; speedup vs baseline: 1.0877x; 1.0877x over previous
//
#include <hip/hip_runtime.h>
#include <math.h>

#define F 128
#define OUTDIM 64
#define NEG 0.2f
#define BN 128
#define KT2 32

// ---------------- utility ----------------
__global__ void zero_ints(int* __restrict__ p, int n) {
    int i = blockIdx.x * blockDim.x + threadIdx.x;
    if (i < n) p[i] = 0;
}

// ---------------- CSR build ----------------
__global__ void hist_kernel(const int* __restrict__ src, const int* __restrict__ dst,
                            int* __restrict__ degF, int* __restrict__ degR, int E) {
    int e = blockIdx.x * blockDim.x + threadIdx.x;
    if (e < E) {
        atomicAdd(&degF[dst[e]], 1);
        atomicAdd(&degR[src[e]], 1);
    }
}

__global__ void scan_pass1(const int* __restrict__ degF, const int* __restrict__ degR,
                           int* __restrict__ rsF, int* __restrict__ rsR,
                           int* __restrict__ bsums, int N) {
    const int arr = blockIdx.y;
    const int* deg = arr ? degR : degF;
    int* rs = arr ? rsR : rsF;
    int tid = threadIdx.x;
    int base = blockIdx.x * 1024 + tid * 4;
    int v[4];
#pragma unroll
    for (int i = 0; i < 4; i++) v[i] = (base + i < N) ? deg[base + i] : 0;
    int s1 = v[0] + v[1] + v[2] + v[3];
    __shared__ int sd[256];
    sd[tid] = s1;
    __syncthreads();
    for (int off = 1; off < 256; off <<= 1) {
        int t = (tid >= off) ? sd[tid - off] : 0;
        __syncthreads();
        sd[tid] += t;
        __syncthreads();
    }
    int run = sd[tid] - s1;
#pragma unroll
    for (int i = 0; i < 4; i++) {
        run += v[i];
        if (base + i < N) rs[base + i + 1] = run;
    }
    if (tid == 255) bsums[arr * 128 + blockIdx.x] = sd[255];
    if (tid == 0 && blockIdx.x == 0) rs[0] = 0;
}

__global__ void scan_pass2(int* __restrict__ bsums, int nb) {
    int arr = blockIdx.y;
    int tid = threadIdx.x;  // 128
    __shared__ int sd[128];
    int v = (tid < nb) ? bsums[arr * 128 + tid] : 0;
    sd[tid] = v;
    __syncthreads();
    for (int off = 1; off < 128; off <<= 1) {
        int t = (tid >= off) ? sd[tid - off] : 0;
        __syncthreads();
        sd[tid] += t;
        __syncthreads();
    }
    bsums[arr * 128 + tid] = sd[tid];
}

__global__ void scan_pass3(int* __restrict__ rsF, int* __restrict__ rsR,
                           const int* __restrict__ bsums, int N) {
    int arr = blockIdx.y;
    if (blockIdx.x == 0) return;
    int* rs = arr ? rsR : rsF;
    int off = bsums[arr * 128 + blockIdx.x - 1];
    int base = blockIdx.x * 1024 + threadIdx.x * 4;
#pragma unroll
    for (int i = 0; i < 4; i++)
        if (base + i < N) rs[base + i + 1] += off;
}

__global__ void scatter_kernel(const int* __restrict__ src, const int* __restrict__ dst,
                               const int* __restrict__ rsF, const int* __restrict__ rsR,
                               int* __restrict__ curF, int* __restrict__ curR,
                               int* __restrict__ colF, int* __restrict__ colR, int E) {
    int e = blockIdx.x * blockDim.x + threadIdx.x;
    if (e < E) {
        int s = src[e], d = dst[e];
        int pf = rsF[d] + atomicAdd(&curF[d], 1);
        colF[pf] = s;
        int pr = rsR[s] + atomicAdd(&curR[s], 1);
        colR[pr] = d;
    }
}

// ---------------- per-node attention scalars ----------------
__global__ void sd4_kernel(const float* __restrict__ x,
                           const float* __restrict__ af_s, const float* __restrict__ af_d,
                           const float* __restrict__ ar_s, const float* __restrict__ ar_d,
                           float* __restrict__ sf, float* __restrict__ df,
                           float* __restrict__ sr, float* __restrict__ dr, int N) {
    int node = blockIdx.x * 4 + (threadIdx.x >> 6);
    int lane = threadIdx.x & 63;
    if (node >= N) return;
    const float2 xv = *(const float2*)&x[(size_t)node * F + 2 * lane];
    float2 a;
    a = *(const float2*)&af_s[2 * lane]; float vsf = xv.x * a.x + xv.y * a.y;
    a = *(const float2*)&af_d[2 * lane]; float vdf = xv.x * a.x + xv.y * a.y;
    a = *(const float2*)&ar_s[2 * lane]; float vsr = xv.x * a.x + xv.y * a.y;
    a = *(const float2*)&ar_d[2 * lane]; float vdr = xv.x * a.x + xv.y * a.y;
#pragma unroll
    for (int off = 32; off > 0; off >>= 1) {
        vsf += __shfl_xor(vsf, off);
        vdf += __shfl_xor(vdf, off);
        vsr += __shfl_xor(vsr, off);
        vdr += __shfl_xor(vdr, off);
    }
    if (lane == 0) { sf[node] = vsf; df[node] = vdf; sr[node] = vsr; dr[node] = vdr; }
}

// ---------------- fused dual-direction attention hop ----------------
// quarter-wave (16 lanes x 8 floats) per node; blockIdx.y selects direction.
// 8-deep pipelined row gather, 2 float4 per row-lane -> 16 outstanding loads.
struct AggDir {
    const float* hin;   // [N][128]
    const float* s;     // [N]
    const float* d;     // [N]
    const int* rs;      // [N+1]
    const int* col;     // [E]
    float* hout;        // [N][128]
    const float* a_s;   // nullable: fused next-hop dots
    const float* a_d;
    float* s_out;
    float* d_out;
};

__global__ __launch_bounds__(256) void agg_kernel(AggDir D0, AggDir D1, int N) {
    AggDir P = blockIdx.y ? D1 : D0;
    int node = blockIdx.x * 16 + (threadIdx.x >> 4);
    int lane = threadIdx.x & 15;           // within quarter-wave
    int qbase = threadIdx.x & 48;          // quarter offset inside the wave
    if (node >= N) return;
    float di = P.d[node];
    int beg = P.rs[node], end = P.rs[node + 1];
    int deg = end - beg;
    float m = -INFINITY, l = 0.f;
    float4 a0 = make_float4(0.f, 0.f, 0.f, 0.f);
    float4 a1 = make_float4(0.f, 0.f, 0.f, 0.f);

    for (int base = 0; base < deg; base += 16) {
        int cnt = min(16, deg - base);
        int sj_l = 0;
        float e_l = -INFINITY;
        if (lane < cnt) {
            sj_l = P.col[beg + base + lane];
            float e = P.s[sj_l] + di;
            e_l = (e >= 0.f) ? e : NEG * e;
        }
        float bm = e_l;
#pragma unroll
        for (int off = 8; off > 0; off >>= 1) bm = fmaxf(bm, __shfl_xor(bm, off));
        float nm = fmaxf(m, bm);
        float p_l = (lane < cnt) ? __expf(e_l - nm) : 0.f;
        float ps = p_l;
#pragma unroll
        for (int off = 8; off > 0; off >>= 1) ps += __shfl_xor(ps, off);
        float sc = (m == -INFINITY) ? 0.f : __expf(m - nm);
        l = l * sc + ps;
        a0.x *= sc; a0.y *= sc; a0.z *= sc; a0.w *= sc;
        a1.x *= sc; a1.y *= sc; a1.z *= sc; a1.w *= sc;
        // 8-deep pipelined weighted row gather (p=0 for pad lanes -> harmless row-0 loads)
        for (int j0 = 0; j0 < cnt; j0 += 8) {
            int sj[8]; float p[8]; float4 h0[8], h1[8];
#pragma unroll
            for (int u = 0; u < 8; u++) {
                sj[u] = __shfl(sj_l, qbase + j0 + u);
                p[u]  = __shfl(p_l,  qbase + j0 + u);
            }
#pragma unroll
            for (int u = 0; u < 8; u++) {
                const float* rp = &P.hin[(size_t)sj[u] * F + 8 * lane];
                h0[u] = *(const float4*)(rp);
                h1[u] = *(const float4*)(rp + 4);
            }
#pragma unroll
            for (int u = 0; u < 8; u++) {
                a0.x += p[u] * h0[u].x; a0.y += p[u] * h0[u].y;
                a0.z += p[u] * h0[u].z; a0.w += p[u] * h0[u].w;
                a1.x += p[u] * h1[u].x; a1.y += p[u] * h1[u].y;
                a1.z += p[u] * h1[u].z; a1.w += p[u] * h1[u].w;
            }
        }
        m = nm;
    }

    float4 o0, o1;
    if (deg > 0) {
        float inv = 1.f / (l + 1e-16f);
        o0.x = a0.x * inv; o0.y = a0.y * inv; o0.z = a0.z * inv; o0.w = a0.w * inv;
        o1.x = a1.x * inv; o1.y = a1.y * inv; o1.z = a1.z * inv; o1.w = a1.w * inv;
    } else {
        o0 = make_float4(0.f, 0.f, 0.f, 0.f);
        o1 = o0;
    }
    float* op = &P.hout[(size_t)node * F + 8 * lane];
    *(float4*)(op) = o0;
    *(float4*)(op + 4) = o1;
    if (P.a_s) {
        float4 b0, b1;
        b0 = *(const float4*)&P.a_s[8 * lane];
        b1 = *(const float4*)&P.a_s[8 * lane + 4];
        float vs = o0.x * b0.x + o0.y * b0.y + o0.z * b0.z + o0.w * b0.w
                 + o1.x * b1.x + o1.y * b1.y + o1.z * b1.z + o1.w * b1.w;
        b0 = *(const float4*)&P.a_d[8 * lane];
        b1 = *(const float4*)&P.a_d[8 * lane + 4];
        float vd = o0.x * b0.x + o0.y * b0.y + o0.z * b0.z + o0.w * b0.w
                 + o1.x * b1.x + o1.y * b1.y + o1.z * b1.z + o1.w * b1.w;
#pragma unroll
        for (int off = 8; off > 0; off >>= 1) {
            vs += __shfl_xor(vs, off);
            vd += __shfl_xor(vd, off);
        }
        if (lane == 0) { P.s_out[node] = vs; P.d_out[node] = vd; }
    }
}

// ---------------- fold W blocks: Weff[640][64] ----------------
__global__ void weff_kernel(const float* __restrict__ W, float* __restrict__ Weff) {
    int i = blockIdx.x * blockDim.x + threadIdx.x;
    if (i >= 640 * 64) return;
    int r = i >> 6, o = i & 63;
    float v;
    if (r < 128)      v = W[r * 64 + o] + W[(r + 384) * 64 + o];
    else if (r < 384) v = W[r * 64 + o];
    else              v = W[(r + 128) * 64 + o];
    Weff[i] = v;
}

// ---------------- final dense: out = [x|h1f|h2f|h1r|h2r] @ Weff + b ----------------
// 512 threads, 4x4 micro-tile (R5 shape: best measured), register-prefetch
// double-buffered LDS, ONE barrier per tile: global-load latency for tile t+1
// hides under tile t's 512 FMAs. 51.2KB LDS -> 3 blocks/CU, ~24 waves/CU.
__global__ __launch_bounds__(512) void gemm_kernel(
    const float* __restrict__ X0, const float* __restrict__ H1F,
    const float* __restrict__ H2F, const float* __restrict__ H1R,
    const float* __restrict__ H2R,
    const float* __restrict__ Weff, const float* __restrict__ bias,
    float* __restrict__ out, int N) {
    __shared__ float Xs[2][KT2][BN + 4];  // 2 x 32 x 132
    __shared__ float Ws[2][KT2][68];
    const float* srcs[5] = {X0, H1F, H2F, H1R, H2R};
    int tid = threadIdx.x;
    int tx = tid & 15, ty = tid >> 4;   // ty 0..31
    int nodeBase = blockIdx.x * BN;
    int srow = tid >> 2;                // 0..127
    int q = tid & 3;                    // k-quarter (8 k each)
    int rowx = srow ^ (q << 4);
    int kb = q * 8;
    int wr = tid >> 4, wc4 = tid & 15;  // W stage coords
    float acc[4][4];
#pragma unroll
    for (int i = 0; i < 4; i++)
#pragma unroll
        for (int j = 0; j < 4; j++) acc[i][j] = 0.f;

    float4 rx0, rx1, rw;
    const int nrow = nodeBase + srow;

    // LOAD tile 0
    {
        const float* p = srcs[0] + (size_t)nrow * 128 + kb;
        if (nrow < N) { rx0 = *(const float4*)(p); rx1 = *(const float4*)(p + 4); }
        else { rx0 = make_float4(0.f, 0.f, 0.f, 0.f); rx1 = rx0; }
        rw = *(const float4*)&Weff[(size_t)wr * 64 + wc4 * 4];
    }
    // WRITE tile 0 -> buf 0
    {
        Xs[0][kb + 0][rowx] = rx0.x; Xs[0][kb + 1][rowx] = rx0.y;
        Xs[0][kb + 2][rowx] = rx0.z; Xs[0][kb + 3][rowx] = rx0.w;
        Xs[0][kb + 4][rowx] = rx1.x; Xs[0][kb + 5][rowx] = rx1.y;
        Xs[0][kb + 6][rowx] = rx1.z; Xs[0][kb + 7][rowx] = rx1.w;
        *(float4*)&Ws[0][wr][wc4 * 4] = rw;
    }

    int cur = 0;
    for (int t = 0; t < 20; ++t) {
        if (t < 19) {  // LOAD tile t+1 into regs
            const float* srcp = srcs[(t + 1) >> 2];
            int cb = ((t + 1) & 3) * 32;
            const float* p = srcp + (size_t)nrow * 128 + cb + kb;
            if (nrow < N) { rx0 = *(const float4*)(p); rx1 = *(const float4*)(p + 4); }
            else { rx0 = make_float4(0.f, 0.f, 0.f, 0.f); rx1 = rx0; }
            rw = *(const float4*)&Weff[(size_t)((t + 1) * 32 + wr) * 64 + wc4 * 4];
        }
        __syncthreads();  // buf[cur] fully written by all waves
#pragma unroll
        for (int k = 0; k < KT2; k++) {
            const int flip = (k >> 3) << 4;
            float4 x4 = *(const float4*)&Xs[cur][k][(ty * 4) ^ flip];
            float4 w4 = *(const float4*)&Ws[cur][k][tx * 4];
            float xv[4] = {x4.x, x4.y, x4.z, x4.w};
            float wv[4] = {w4.x, w4.y, w4.z, w4.w};
#pragma unroll
            for (int i = 0; i < 4; i++)
#pragma unroll
                for (int j = 0; j < 4; j++) acc[i][j] += xv[i] * wv[j];
        }
        if (t < 19) {  // WRITE tile t+1 -> buf cur^1
            int b = cur ^ 1;
            Xs[b][kb + 0][rowx] = rx0.x; Xs[b][kb + 1][rowx] = rx0.y;
            Xs[b][kb + 2][rowx] = rx0.z; Xs[b][kb + 3][rowx] = rx0.w;
            Xs[b][kb + 4][rowx] = rx1.x; Xs[b][kb + 5][rowx] = rx1.y;
            Xs[b][kb + 6][rowx] = rx1.z; Xs[b][kb + 7][rowx] = rx1.w;
            *(float4*)&Ws[b][wr][wc4 * 4] = rw;
        }
        cur ^= 1;
    }
    float4 bv = *(const float4*)&bias[tx * 4];
#pragma unroll
    for (int i = 0; i < 4; i++) {
        int n = nodeBase + ty * 4 + i;
        if (n < N) {
            float4 o;
            o.x = acc[i][0] + bv.x; o.y = acc[i][1] + bv.y;
            o.z = acc[i][2] + bv.z; o.w = acc[i][3] + bv.w;
            *(float4*)&out[(size_t)n * 64 + tx * 4] = o;
        }
    }
}

extern "C" void kernel_launch(void* const* d_in, const int* in_sizes, int n_in,
                              void* d_out, int out_size, void* d_ws, size_t ws_size,
                              hipStream_t stream) {
    const float* feature = (const float*)d_in[0];
    const int*   eidx    = (const int*)d_in[1];
    const float* af_s    = (const float*)d_in[2];
    const float* af_d    = (const float*)d_in[3];
    const float* ar_s    = (const float*)d_in[4];
    const float* ar_d    = (const float*)d_in[5];
    const float* W       = (const float*)d_in[6];
    const float* bias    = (const float*)d_in[7];
    float* out = (float*)d_out;
    const int N = in_sizes[0] / F;
    const int E = in_sizes[1] / 2;
    const int* src = eidx;
    const int* dst = eidx + E;

    char* ws = (char*)d_ws;
    size_t off = 0;
    auto alloc = [&](size_t b) { size_t r = off; off = (off + b + 255) & ~(size_t)255; return r; };
    float* h1f = (float*)(ws + alloc((size_t)N * F * 4));
    float* h2f = (float*)(ws + alloc((size_t)N * F * 4));
    float* h1r = (float*)(ws + alloc((size_t)N * F * 4));
    float* h2r = (float*)(ws + alloc((size_t)N * F * 4));
    int*   rsF   = (int*)(ws + alloc((size_t)(N + 1) * 4));
    int*   rsR   = (int*)(ws + alloc((size_t)(N + 1) * 4));
    int*   colF  = (int*)(ws + alloc((size_t)E * 4));
    int*   colR  = (int*)(ws + alloc((size_t)E * 4));
    int*   ints4 = (int*)(ws + alloc((size_t)4 * N * 4));
    int *degF = ints4, *degR = ints4 + N, *curF = ints4 + 2 * N, *curR = ints4 + 3 * N;
    float* fls8 = (float*)(ws + alloc((size_t)8 * N * 4));
    float *sf = fls8, *df = fls8 + N, *sr = fls8 + 2 * (size_t)N, *dr = fls8 + 3 * (size_t)N;
    float *s2f = fls8 + 4 * (size_t)N, *d2f = fls8 + 5 * (size_t)N;
    float *s2r = fls8 + 6 * (size_t)N, *d2r = fls8 + 7 * (size_t)N;
    int*   bsums = (int*)(ws + alloc(256 * 4));
    float* Weff  = (float*)(ws + alloc(640 * 64 * 4));

    const int nb = (N + 1023) / 1024;
    zero_ints<<<(4 * N + 255) / 256, 256, 0, stream>>>(ints4, 4 * N);
    hist_kernel<<<(E + 255) / 256, 256, 0, stream>>>(src, dst, degF, degR, E);
    scan_pass1<<<dim3(nb, 2), 256, 0, stream>>>(degF, degR, rsF, rsR, bsums, N);
    scan_pass2<<<dim3(1, 2), 128, 0, stream>>>(bsums, nb);
    scan_pass3<<<dim3(nb, 2), 256, 0, stream>>>(rsF, rsR, bsums, N);
    scatter_kernel<<<(E + 255) / 256, 256, 0, stream>>>(src, dst, rsF, rsR, curF, curR, colF, colR, E);
    sd4_kernel<<<(N + 3) / 4, 256, 0, stream>>>(feature, af_s, af_d, ar_s, ar_d, sf, df, sr, dr, N);

    AggDir F1{feature, sf, df, rsF, colF, h1f, af_s, af_d, s2f, d2f};
    AggDir R1{feature, sr, dr, rsR, colR, h1r, ar_s, ar_d, s2r, d2r};
    agg_kernel<<<dim3((N + 15) / 16, 2), 256, 0, stream>>>(F1, R1, N);
    AggDir F2{h1f, s2f, d2f, rsF, colF, h2f, nullptr, nullptr, nullptr, nullptr};
    AggDir R2{h1r, s2r, d2r, rsR, colR, h2r, nullptr, nullptr, nullptr, nullptr};
    agg_kernel<<<dim3((N + 15) / 16, 2), 256, 0, stream>>>(F2, R2, N);

    weff_kernel<<<(640 * 64 + 255) / 256, 256, 0, stream>>>(W, Weff);
    gemm_kernel<<<(N + BN - 1) / BN, 512, 0, stream>>>(feature, h1f, h2f, h1r, h2r, Weff, bias, out, N);
}

// Round 8
// 501.591 us; speedup vs baseline: 1.2791x; 1.1760x over previous
//
#include <hip/hip_runtime.h>
#include <math.h>

#define F 128
#define OUTDIM 64
#define NEG 0.2f
#define BN4 64
#define KT2 32

// ---------------- utility ----------------
__global__ void zero_ints(int* __restrict__ p, int n) {
    int i = blockIdx.x * blockDim.x + threadIdx.x;
    if (i < n) p[i] = 0;
}

// ---------------- CSR build ----------------
__global__ void hist_kernel(const int* __restrict__ src, const int* __restrict__ dst,
                            int* __restrict__ degF, int* __restrict__ degR, int E) {
    int e = blockIdx.x * blockDim.x + threadIdx.x;
    if (e < E) {
        atomicAdd(&degF[dst[e]], 1);
        atomicAdd(&degR[src[e]], 1);
    }
}

__global__ void scan_pass1(const int* __restrict__ degF, const int* __restrict__ degR,
                           int* __restrict__ rsF, int* __restrict__ rsR,
                           int* __restrict__ bsums, int N) {
    const int arr = blockIdx.y;
    const int* deg = arr ? degR : degF;
    int* rs = arr ? rsR : rsF;
    int tid = threadIdx.x;
    int base = blockIdx.x * 1024 + tid * 4;
    int v[4];
#pragma unroll
    for (int i = 0; i < 4; i++) v[i] = (base + i < N) ? deg[base + i] : 0;
    int s1 = v[0] + v[1] + v[2] + v[3];
    __shared__ int sd[256];
    sd[tid] = s1;
    __syncthreads();
    for (int off = 1; off < 256; off <<= 1) {
        int t = (tid >= off) ? sd[tid - off] : 0;
        __syncthreads();
        sd[tid] += t;
        __syncthreads();
    }
    int run = sd[tid] - s1;
#pragma unroll
    for (int i = 0; i < 4; i++) {
        run += v[i];
        if (base + i < N) rs[base + i + 1] = run;
    }
    if (tid == 255) bsums[arr * 128 + blockIdx.x] = sd[255];
    if (tid == 0 && blockIdx.x == 0) rs[0] = 0;
}

__global__ void scan_pass2(int* __restrict__ bsums, int nb) {
    int arr = blockIdx.y;
    int tid = threadIdx.x;  // 128
    __shared__ int sd[128];
    int v = (tid < nb) ? bsums[arr * 128 + tid] : 0;
    sd[tid] = v;
    __syncthreads();
    for (int off = 1; off < 128; off <<= 1) {
        int t = (tid >= off) ? sd[tid - off] : 0;
        __syncthreads();
        sd[tid] += t;
        __syncthreads();
    }
    bsums[arr * 128 + tid] = sd[tid];
}

__global__ void scan_pass3(int* __restrict__ rsF, int* __restrict__ rsR,
                           const int* __restrict__ bsums, int N) {
    int arr = blockIdx.y;
    if (blockIdx.x == 0) return;
    int* rs = arr ? rsR : rsF;
    int off = bsums[arr * 128 + blockIdx.x - 1];
    int base = blockIdx.x * 1024 + threadIdx.x * 4;
#pragma unroll
    for (int i = 0; i < 4; i++)
        if (base + i < N) rs[base + i + 1] += off;
}

__global__ void scatter_kernel(const int* __restrict__ src, const int* __restrict__ dst,
                               const int* __restrict__ rsF, const int* __restrict__ rsR,
                               int* __restrict__ curF, int* __restrict__ curR,
                               int* __restrict__ colF, int* __restrict__ colR, int E) {
    int e = blockIdx.x * blockDim.x + threadIdx.x;
    if (e < E) {
        int s = src[e], d = dst[e];
        int pf = rsF[d] + atomicAdd(&curF[d], 1);
        colF[pf] = s;
        int pr = rsR[s] + atomicAdd(&curR[s], 1);
        colR[pr] = d;
    }
}

// ---------------- per-node attention scalars ----------------
__global__ void sd4_kernel(const float* __restrict__ x,
                           const float* __restrict__ af_s, const float* __restrict__ af_d,
                           const float* __restrict__ ar_s, const float* __restrict__ ar_d,
                           float* __restrict__ sf, float* __restrict__ df,
                           float* __restrict__ sr, float* __restrict__ dr, int N) {
    int node = blockIdx.x * 4 + (threadIdx.x >> 6);
    int lane = threadIdx.x & 63;
    if (node >= N) return;
    const float2 xv = *(const float2*)&x[(size_t)node * F + 2 * lane];
    float2 a;
    a = *(const float2*)&af_s[2 * lane]; float vsf = xv.x * a.x + xv.y * a.y;
    a = *(const float2*)&af_d[2 * lane]; float vdf = xv.x * a.x + xv.y * a.y;
    a = *(const float2*)&ar_s[2 * lane]; float vsr = xv.x * a.x + xv.y * a.y;
    a = *(const float2*)&ar_d[2 * lane]; float vdr = xv.x * a.x + xv.y * a.y;
#pragma unroll
    for (int off = 32; off > 0; off >>= 1) {
        vsf += __shfl_xor(vsf, off);
        vdf += __shfl_xor(vdf, off);
        vsr += __shfl_xor(vsr, off);
        vdr += __shfl_xor(vdr, off);
    }
    if (lane == 0) { sf[node] = vsf; df[node] = vdf; sr[node] = vsr; dr[node] = vdr; }
}

// ---------------- fused dual-direction attention hop ----------------
// quarter-wave (16 lanes x 8 floats) per node; blockIdx.y selects direction.
// 8-deep pipelined row gather; loads guarded by cnt (mean deg ~6 -> no pad traffic).
struct AggDir {
    const float* hin;   // [N][128]
    const float* s;     // [N]
    const float* d;     // [N]
    const int* rs;      // [N+1]
    const int* col;     // [E]
    float* hout;        // [N][128]
    const float* a_s;   // nullable: fused next-hop dots
    const float* a_d;
    float* s_out;
    float* d_out;
};

__global__ __launch_bounds__(256) void agg_kernel(AggDir D0, AggDir D1, int N) {
    AggDir P = blockIdx.y ? D1 : D0;
    int node = blockIdx.x * 16 + (threadIdx.x >> 4);
    int lane = threadIdx.x & 15;           // within quarter-wave
    int qbase = threadIdx.x & 48;          // quarter offset inside the wave
    if (node >= N) return;
    float di = P.d[node];
    int beg = P.rs[node], end = P.rs[node + 1];
    int deg = end - beg;
    float m = -INFINITY, l = 0.f;
    float4 a0 = make_float4(0.f, 0.f, 0.f, 0.f);
    float4 a1 = make_float4(0.f, 0.f, 0.f, 0.f);

    for (int base = 0; base < deg; base += 16) {
        int cnt = min(16, deg - base);
        int sj_l = 0;
        float e_l = -INFINITY;
        if (lane < cnt) {
            sj_l = P.col[beg + base + lane];
            float e = P.s[sj_l] + di;
            e_l = (e >= 0.f) ? e : NEG * e;
        }
        float bm = e_l;
#pragma unroll
        for (int off = 8; off > 0; off >>= 1) bm = fmaxf(bm, __shfl_xor(bm, off));
        float nm = fmaxf(m, bm);
        float p_l = (lane < cnt) ? __expf(e_l - nm) : 0.f;
        float ps = p_l;
#pragma unroll
        for (int off = 8; off > 0; off >>= 1) ps += __shfl_xor(ps, off);
        float sc = (m == -INFINITY) ? 0.f : __expf(m - nm);
        l = l * sc + ps;
        a0.x *= sc; a0.y *= sc; a0.z *= sc; a0.w *= sc;
        a1.x *= sc; a1.y *= sc; a1.z *= sc; a1.w *= sc;
        for (int j0 = 0; j0 < cnt; j0 += 8) {
            int sj[8]; float p[8]; float4 h0[8], h1[8];
#pragma unroll
            for (int u = 0; u < 8; u++) {
                sj[u] = __shfl(sj_l, qbase + j0 + u);
                p[u]  = __shfl(p_l,  qbase + j0 + u);
            }
#pragma unroll
            for (int u = 0; u < 8; u++) {
                if (j0 + u < cnt) {  // uniform per quarter-wave: no pad-load traffic
                    const float* rp = &P.hin[(size_t)sj[u] * F + 8 * lane];
                    h0[u] = *(const float4*)(rp);
                    h1[u] = *(const float4*)(rp + 4);
                } else {
                    h0[u] = make_float4(0.f, 0.f, 0.f, 0.f);
                    h1[u] = h0[u];
                }
            }
#pragma unroll
            for (int u = 0; u < 8; u++) {
                a0.x += p[u] * h0[u].x; a0.y += p[u] * h0[u].y;
                a0.z += p[u] * h0[u].z; a0.w += p[u] * h0[u].w;
                a1.x += p[u] * h1[u].x; a1.y += p[u] * h1[u].y;
                a1.z += p[u] * h1[u].z; a1.w += p[u] * h1[u].w;
            }
        }
        m = nm;
    }

    float4 o0, o1;
    if (deg > 0) {
        float inv = 1.f / (l + 1e-16f);
        o0.x = a0.x * inv; o0.y = a0.y * inv; o0.z = a0.z * inv; o0.w = a0.w * inv;
        o1.x = a1.x * inv; o1.y = a1.y * inv; o1.z = a1.z * inv; o1.w = a1.w * inv;
    } else {
        o0 = make_float4(0.f, 0.f, 0.f, 0.f);
        o1 = o0;
    }
    float* op = &P.hout[(size_t)node * F + 8 * lane];
    *(float4*)(op) = o0;
    *(float4*)(op + 4) = o1;
    if (P.a_s) {
        float4 b0, b1;
        b0 = *(const float4*)&P.a_s[8 * lane];
        b1 = *(const float4*)&P.a_s[8 * lane + 4];
        float vs = o0.x * b0.x + o0.y * b0.y + o0.z * b0.z + o0.w * b0.w
                 + o1.x * b1.x + o1.y * b1.y + o1.z * b1.z + o1.w * b1.w;
        b0 = *(const float4*)&P.a_d[8 * lane];
        b1 = *(const float4*)&P.a_d[8 * lane + 4];
        float vd = o0.x * b0.x + o0.y * b0.y + o0.z * b0.z + o0.w * b0.w
                 + o1.x * b1.x + o1.y * b1.y + o1.z * b1.z + o1.w * b1.w;
#pragma unroll
        for (int off = 8; off > 0; off >>= 1) {
            vs += __shfl_xor(vs, off);
            vd += __shfl_xor(vd, off);
        }
        if (lane == 0) { P.s_out[node] = vs; P.d_out[node] = vd; }
    }
}

// ---------------- fold W blocks: Weff[640][64] ----------------
__global__ void weff_kernel(const float* __restrict__ W, float* __restrict__ Weff) {
    int i = blockIdx.x * blockDim.x + threadIdx.x;
    if (i >= 640 * 64) return;
    int r = i >> 6, o = i & 63;
    float v;
    if (r < 128)      v = W[r * 64 + o] + W[(r + 384) * 64 + o];
    else if (r < 384) v = W[r * 64 + o];
    else              v = W[(r + 128) * 64 + o];
    Weff[i] = v;
}

// ---------------- final dense: out = [x|h1f|h2f|h1r|h2r] @ Weff + b ----------------
// BN=64, 256 threads, 4x4 micro-tile, single-buffered (R5's proven inner loop).
// 17.4KB LDS -> 6 blocks/CU co-resident: other blocks' FMAs hide each block's
// staging barrier (TLP latency hiding; no prefetch registers -> no spill).
__global__ __launch_bounds__(256) void gemm_kernel(
    const float* __restrict__ X0, const float* __restrict__ H1F,
    const float* __restrict__ H2F, const float* __restrict__ H1R,
    const float* __restrict__ H2R,
    const float* __restrict__ Weff, const float* __restrict__ bias,
    float* __restrict__ out, int N) {
    __shared__ float Xs[KT2][BN4 + 4];  // 32 x 68
    __shared__ float Ws[KT2][68];
    const float* srcs[5] = {X0, H1F, H2F, H1R, H2R};
    int tid = threadIdx.x;              // 0..255
    int tx = tid & 15, ty = tid >> 4;   // ty 0..15
    int nodeBase = blockIdx.x * BN4;
    int srow = tid >> 2;                // 0..63
    int q = tid & 3;                    // k-quarter (8 k each)
    int rowx = srow ^ (q << 4);
    int kb = q * 8;
    float acc[4][4];
#pragma unroll
    for (int i = 0; i < 4; i++)
#pragma unroll
        for (int j = 0; j < 4; j++) acc[i][j] = 0.f;

    for (int t = 0; t < 20; ++t) {
        const float* srcp = srcs[t >> 2];
        int cb = (t & 3) * 32;
        // stage X: thread loads 8 consecutive k (two float4) of one row
        {
            int n = nodeBase + srow;
            float4 v0, v1;
            if (n < N) {
                const float* p = srcp + (size_t)n * 128 + cb + kb;
                v0 = *(const float4*)(p);
                v1 = *(const float4*)(p + 4);
            } else {
                v0 = make_float4(0.f, 0.f, 0.f, 0.f);
                v1 = v0;
            }
            Xs[kb + 0][rowx] = v0.x;
            Xs[kb + 1][rowx] = v0.y;
            Xs[kb + 2][rowx] = v0.z;
            Xs[kb + 3][rowx] = v0.w;
            Xs[kb + 4][rowx] = v1.x;
            Xs[kb + 5][rowx] = v1.y;
            Xs[kb + 6][rowx] = v1.z;
            Xs[kb + 7][rowx] = v1.w;
        }
        // stage W: two float4 per thread (32x64 floats)
#pragma unroll
        for (int q2 = 0; q2 < 2; q2++) {
            int f = tid * 2 + q2;           // 0..511 float4s
            int wr = f >> 4, wc4 = f & 15;
            *(float4*)&Ws[wr][wc4 * 4] =
                *(const float4*)&Weff[(size_t)(t * 32 + wr) * 64 + wc4 * 4];
        }
        __syncthreads();
#pragma unroll
        for (int k = 0; k < KT2; k++) {
            const int flip = (k >> 3) << 4;
            float4 x4 = *(const float4*)&Xs[k][(ty * 4) ^ flip];
            float4 w4 = *(const float4*)&Ws[k][tx * 4];
            float xv[4] = {x4.x, x4.y, x4.z, x4.w};
            float wv[4] = {w4.x, w4.y, w4.z, w4.w};
#pragma unroll
            for (int i = 0; i < 4; i++)
#pragma unroll
                for (int j = 0; j < 4; j++) acc[i][j] += xv[i] * wv[j];
        }
        __syncthreads();
    }
    float4 bv = *(const float4*)&bias[tx * 4];
#pragma unroll
    for (int i = 0; i < 4; i++) {
        int n = nodeBase + ty * 4 + i;
        if (n < N) {
            float4 o;
            o.x = acc[i][0] + bv.x; o.y = acc[i][1] + bv.y;
            o.z = acc[i][2] + bv.z; o.w = acc[i][3] + bv.w;
            *(float4*)&out[(size_t)n * 64 + tx * 4] = o;
        }
    }
}

extern "C" void kernel_launch(void* const* d_in, const int* in_sizes, int n_in,
                              void* d_out, int out_size, void* d_ws, size_t ws_size,
                              hipStream_t stream) {
    const float* feature = (const float*)d_in[0];
    const int*   eidx    = (const int*)d_in[1];
    const float* af_s    = (const float*)d_in[2];
    const float* af_d    = (const float*)d_in[3];
    const float* ar_s    = (const float*)d_in[4];
    const float* ar_d    = (const float*)d_in[5];
    const float* W       = (const float*)d_in[6];
    const float* bias    = (const float*)d_in[7];
    float* out = (float*)d_out;
    const int N = in_sizes[0] / F;
    const int E = in_sizes[1] / 2;
    const int* src = eidx;
    const int* dst = eidx + E;

    char* ws = (char*)d_ws;
    size_t off = 0;
    auto alloc = [&](size_t b) { size_t r = off; off = (off + b + 255) & ~(size_t)255; return r; };
    float* h1f = (float*)(ws + alloc((size_t)N * F * 4));
    float* h2f = (float*)(ws + alloc((size_t)N * F * 4));
    float* h1r = (float*)(ws + alloc((size_t)N * F * 4));
    float* h2r = (float*)(ws + alloc((size_t)N * F * 4));
    int*   rsF   = (int*)(ws + alloc((size_t)(N + 1) * 4));
    int*   rsR   = (int*)(ws + alloc((size_t)(N + 1) * 4));
    int*   colF  = (int*)(ws + alloc((size_t)E * 4));
    int*   colR  = (int*)(ws + alloc((size_t)E * 4));
    int*   ints4 = (int*)(ws + alloc((size_t)4 * N * 4));
    int *degF = ints4, *degR = ints4 + N, *curF = ints4 + 2 * N, *curR = ints4 + 3 * N;
    float* fls8 = (float*)(ws + alloc((size_t)8 * N * 4));
    float *sf = fls8, *df = fls8 + N, *sr = fls8 + 2 * (size_t)N, *dr = fls8 + 3 * (size_t)N;
    float *s2f = fls8 + 4 * (size_t)N, *d2f = fls8 + 5 * (size_t)N;
    float *s2r = fls8 + 6 * (size_t)N, *d2r = fls8 + 7 * (size_t)N;
    int*   bsums = (int*)(ws + alloc(256 * 4));
    float* Weff  = (float*)(ws + alloc(640 * 64 * 4));

    const int nb = (N + 1023) / 1024;
    zero_ints<<<(4 * N + 255) / 256, 256, 0, stream>>>(ints4, 4 * N);
    hist_kernel<<<(E + 255) / 256, 256, 0, stream>>>(src, dst, degF, degR, E);
    scan_pass1<<<dim3(nb, 2), 256, 0, stream>>>(degF, degR, rsF, rsR, bsums, N);
    scan_pass2<<<dim3(1, 2), 128, 0, stream>>>(bsums, nb);
    scan_pass3<<<dim3(nb, 2), 256, 0, stream>>>(rsF, rsR, bsums, N);
    scatter_kernel<<<(E + 255) / 256, 256, 0, stream>>>(src, dst, rsF, rsR, curF, curR, colF, colR, E);
    sd4_kernel<<<(N + 3) / 4, 256, 0, stream>>>(feature, af_s, af_d, ar_s, ar_d, sf, df, sr, dr, N);

    AggDir F1{feature, sf, df, rsF, colF, h1f, af_s, af_d, s2f, d2f};
    AggDir R1{feature, sr, dr, rsR, colR, h1r, ar_s, ar_d, s2r, d2r};
    agg_kernel<<<dim3((N + 15) / 16, 2), 256, 0, stream>>>(F1, R1, N);
    AggDir F2{h1f, s2f, d2f, rsF, colF, h2f, nullptr, nullptr, nullptr, nullptr};
    AggDir R2{h1r, s2r, d2r, rsR, colR, h2r, nullptr, nullptr, nullptr, nullptr};
    agg_kernel<<<dim3((N + 15) / 16, 2), 256, 0, stream>>>(F2, R2, N);

    weff_kernel<<<(640 * 64 + 255) / 256, 256, 0, stream>>>(W, Weff);
    gemm_kernel<<<(N + BN4 - 1) / BN4, 256, 0, stream>>>(feature, h1f, h2f, h1r, h2r, Weff, bias, out, N);
}

// Round 9
// 500.963 us; speedup vs baseline: 1.2807x; 1.0013x over previous
//
#include <hip/hip_runtime.h>
#include <math.h>

#define F 128
#define OUTDIM 64
#define NEG 0.2f
#define BN4 64
#define KT3 64

// ---------------- bf16 helpers ----------------
__device__ __forceinline__ float blo(unsigned u) { return __uint_as_float(u << 16); }
__device__ __forceinline__ float bhi(unsigned u) { return __uint_as_float(u & 0xFFFF0000u); }
__device__ __forceinline__ unsigned bpack(float a, float b) {  // rtne both
    unsigned ua = __float_as_uint(a), ub = __float_as_uint(b);
    ua += 0x7FFFu + ((ua >> 16) & 1u);
    ub += 0x7FFFu + ((ub >> 16) & 1u);
    return (ua >> 16) | (ub & 0xFFFF0000u);
}

// ---------------- utility ----------------
__global__ void zero_ints(int* __restrict__ p, int n) {
    int i = blockIdx.x * blockDim.x + threadIdx.x;
    if (i < n) p[i] = 0;
}

// ---------------- CSR build ----------------
__global__ void hist_kernel(const int* __restrict__ src, const int* __restrict__ dst,
                            int* __restrict__ degF, int* __restrict__ degR, int E) {
    int e = blockIdx.x * blockDim.x + threadIdx.x;
    if (e < E) {
        atomicAdd(&degF[dst[e]], 1);
        atomicAdd(&degR[src[e]], 1);
    }
}

__global__ void scan_pass1(const int* __restrict__ degF, const int* __restrict__ degR,
                           int* __restrict__ rsF, int* __restrict__ rsR,
                           int* __restrict__ bsums, int N) {
    const int arr = blockIdx.y;
    const int* deg = arr ? degR : degF;
    int* rs = arr ? rsR : rsF;
    int tid = threadIdx.x;
    int base = blockIdx.x * 1024 + tid * 4;
    int v[4];
#pragma unroll
    for (int i = 0; i < 4; i++) v[i] = (base + i < N) ? deg[base + i] : 0;
    int s1 = v[0] + v[1] + v[2] + v[3];
    __shared__ int sd[256];
    sd[tid] = s1;
    __syncthreads();
    for (int off = 1; off < 256; off <<= 1) {
        int t = (tid >= off) ? sd[tid - off] : 0;
        __syncthreads();
        sd[tid] += t;
        __syncthreads();
    }
    int run = sd[tid] - s1;
#pragma unroll
    for (int i = 0; i < 4; i++) {
        run += v[i];
        if (base + i < N) rs[base + i + 1] = run;
    }
    if (tid == 255) bsums[arr * 128 + blockIdx.x] = sd[255];
    if (tid == 0 && blockIdx.x == 0) rs[0] = 0;
}

__global__ void scan_pass2(int* __restrict__ bsums, int nb) {
    int arr = blockIdx.y;
    int tid = threadIdx.x;  // 128
    __shared__ int sd[128];
    int v = (tid < nb) ? bsums[arr * 128 + tid] : 0;
    sd[tid] = v;
    __syncthreads();
    for (int off = 1; off < 128; off <<= 1) {
        int t = (tid >= off) ? sd[tid - off] : 0;
        __syncthreads();
        sd[tid] += t;
        __syncthreads();
    }
    bsums[arr * 128 + tid] = sd[tid];
}

__global__ void scan_pass3(int* __restrict__ rsF, int* __restrict__ rsR,
                           const int* __restrict__ bsums, int N) {
    int arr = blockIdx.y;
    if (blockIdx.x == 0) return;
    int* rs = arr ? rsR : rsF;
    int off = bsums[arr * 128 + blockIdx.x - 1];
    int base = blockIdx.x * 1024 + threadIdx.x * 4;
#pragma unroll
    for (int i = 0; i < 4; i++)
        if (base + i < N) rs[base + i + 1] += off;
}

__global__ void scatter_kernel(const int* __restrict__ src, const int* __restrict__ dst,
                               const int* __restrict__ rsF, const int* __restrict__ rsR,
                               int* __restrict__ curF, int* __restrict__ curR,
                               int* __restrict__ colF, int* __restrict__ colR, int E) {
    int e = blockIdx.x * blockDim.x + threadIdx.x;
    if (e < E) {
        int s = src[e], d = dst[e];
        int pf = rsF[d] + atomicAdd(&curF[d], 1);
        colF[pf] = s;
        int pr = rsR[s] + atomicAdd(&curR[s], 1);
        colR[pr] = d;
    }
}

// ---------------- per-node attention scalars ----------------
__global__ void sd4_kernel(const float* __restrict__ x,
                           const float* __restrict__ af_s, const float* __restrict__ af_d,
                           const float* __restrict__ ar_s, const float* __restrict__ ar_d,
                           float* __restrict__ sf, float* __restrict__ df,
                           float* __restrict__ sr, float* __restrict__ dr, int N) {
    int node = blockIdx.x * 4 + (threadIdx.x >> 6);
    int lane = threadIdx.x & 63;
    if (node >= N) return;
    const float2 xv = *(const float2*)&x[(size_t)node * F + 2 * lane];
    float2 a;
    a = *(const float2*)&af_s[2 * lane]; float vsf = xv.x * a.x + xv.y * a.y;
    a = *(const float2*)&af_d[2 * lane]; float vdf = xv.x * a.x + xv.y * a.y;
    a = *(const float2*)&ar_s[2 * lane]; float vsr = xv.x * a.x + xv.y * a.y;
    a = *(const float2*)&ar_d[2 * lane]; float vdr = xv.x * a.x + xv.y * a.y;
#pragma unroll
    for (int off = 32; off > 0; off >>= 1) {
        vsf += __shfl_xor(vsf, off);
        vdf += __shfl_xor(vdf, off);
        vsr += __shfl_xor(vsr, off);
        vdr += __shfl_xor(vdr, off);
    }
    if (lane == 0) { sf[node] = vsf; df[node] = vdf; sr[node] = vsr; dr[node] = vdr; }
}

// ---------------- fused dual-direction attention hop ----------------
// quarter-wave (16 lanes x 8 floats) per node; blockIdx.y selects direction.
// BFIN: gather rows from bf16 [N][64 u32]; BFOUT: write only bf16 output.
struct AggDir {
    const float* hin;        // [N][128] fp32 (BFIN=false)
    const unsigned* hin_bf;  // [N][64]  bf16x2 (BFIN=true)
    const float* s;          // [N]
    const float* d;          // [N]
    const int* rs;           // [N+1]
    const int* col;          // [E]
    float* hout;             // [N][128] fp32 (BFOUT=false)
    unsigned* hout_bf;       // [N][64]  bf16x2 (BFOUT=true)
    const float* a_s;        // nullable: fused next-hop dots
    const float* a_d;
    float* s_out;
    float* d_out;
};

template <bool BFIN, bool BFOUT>
__global__ __launch_bounds__(256) void agg_kernel(AggDir D0, AggDir D1, int N) {
    AggDir P = blockIdx.y ? D1 : D0;
    int node = blockIdx.x * 16 + (threadIdx.x >> 4);
    int lane = threadIdx.x & 15;           // within quarter-wave
    int qbase = threadIdx.x & 48;          // quarter offset inside the wave
    if (node >= N) return;
    float di = P.d[node];
    int beg = P.rs[node], end = P.rs[node + 1];
    int deg = end - beg;
    float m = -INFINITY, l = 0.f;
    float4 a0 = make_float4(0.f, 0.f, 0.f, 0.f);
    float4 a1 = make_float4(0.f, 0.f, 0.f, 0.f);

    for (int base = 0; base < deg; base += 16) {
        int cnt = min(16, deg - base);
        int sj_l = 0;
        float e_l = -INFINITY;
        if (lane < cnt) {
            sj_l = P.col[beg + base + lane];
            float e = P.s[sj_l] + di;
            e_l = (e >= 0.f) ? e : NEG * e;
        }
        float bm = e_l;
#pragma unroll
        for (int off = 8; off > 0; off >>= 1) bm = fmaxf(bm, __shfl_xor(bm, off));
        float nm = fmaxf(m, bm);
        float p_l = (lane < cnt) ? __expf(e_l - nm) : 0.f;
        float ps = p_l;
#pragma unroll
        for (int off = 8; off > 0; off >>= 1) ps += __shfl_xor(ps, off);
        float sc = (m == -INFINITY) ? 0.f : __expf(m - nm);
        l = l * sc + ps;
        a0.x *= sc; a0.y *= sc; a0.z *= sc; a0.w *= sc;
        a1.x *= sc; a1.y *= sc; a1.z *= sc; a1.w *= sc;
        for (int j0 = 0; j0 < cnt; j0 += 8) {
            int sj[8]; float p[8]; float4 h0[8], h1[8];
#pragma unroll
            for (int u = 0; u < 8; u++) {
                sj[u] = __shfl(sj_l, qbase + j0 + u);
                p[u]  = __shfl(p_l,  qbase + j0 + u);
            }
#pragma unroll
            for (int u = 0; u < 8; u++) {
                if (j0 + u < cnt) {  // uniform per quarter-wave
                    if (BFIN) {
                        uint4 hb = *(const uint4*)&P.hin_bf[(size_t)sj[u] * 64 + 4 * lane];
                        h0[u].x = blo(hb.x); h0[u].y = bhi(hb.x);
                        h0[u].z = blo(hb.y); h0[u].w = bhi(hb.y);
                        h1[u].x = blo(hb.z); h1[u].y = bhi(hb.z);
                        h1[u].z = blo(hb.w); h1[u].w = bhi(hb.w);
                    } else {
                        const float* rp = &P.hin[(size_t)sj[u] * F + 8 * lane];
                        h0[u] = *(const float4*)(rp);
                        h1[u] = *(const float4*)(rp + 4);
                    }
                } else {
                    h0[u] = make_float4(0.f, 0.f, 0.f, 0.f);
                    h1[u] = h0[u];
                }
            }
#pragma unroll
            for (int u = 0; u < 8; u++) {
                a0.x += p[u] * h0[u].x; a0.y += p[u] * h0[u].y;
                a0.z += p[u] * h0[u].z; a0.w += p[u] * h0[u].w;
                a1.x += p[u] * h1[u].x; a1.y += p[u] * h1[u].y;
                a1.z += p[u] * h1[u].z; a1.w += p[u] * h1[u].w;
            }
        }
        m = nm;
    }

    float4 o0, o1;
    if (deg > 0) {
        float inv = 1.f / (l + 1e-16f);
        o0.x = a0.x * inv; o0.y = a0.y * inv; o0.z = a0.z * inv; o0.w = a0.w * inv;
        o1.x = a1.x * inv; o1.y = a1.y * inv; o1.z = a1.z * inv; o1.w = a1.w * inv;
    } else {
        o0 = make_float4(0.f, 0.f, 0.f, 0.f);
        o1 = o0;
    }
    if (BFOUT) {
        uint4 hb;
        hb.x = bpack(o0.x, o0.y); hb.y = bpack(o0.z, o0.w);
        hb.z = bpack(o1.x, o1.y); hb.w = bpack(o1.z, o1.w);
        *(uint4*)&P.hout_bf[(size_t)node * 64 + 4 * lane] = hb;
    } else {
        float* op = &P.hout[(size_t)node * F + 8 * lane];
        *(float4*)(op) = o0;
        *(float4*)(op + 4) = o1;
    }
    if (P.a_s) {
        float4 b0, b1;
        b0 = *(const float4*)&P.a_s[8 * lane];
        b1 = *(const float4*)&P.a_s[8 * lane + 4];
        float vs = o0.x * b0.x + o0.y * b0.y + o0.z * b0.z + o0.w * b0.w
                 + o1.x * b1.x + o1.y * b1.y + o1.z * b1.z + o1.w * b1.w;
        b0 = *(const float4*)&P.a_d[8 * lane];
        b1 = *(const float4*)&P.a_d[8 * lane + 4];
        float vd = o0.x * b0.x + o0.y * b0.y + o0.z * b0.z + o0.w * b0.w
                 + o1.x * b1.x + o1.y * b1.y + o1.z * b1.z + o1.w * b1.w;
#pragma unroll
        for (int off = 8; off > 0; off >>= 1) {
            vs += __shfl_xor(vs, off);
            vd += __shfl_xor(vd, off);
        }
        if (lane == 0) { P.s_out[node] = vs; P.d_out[node] = vd; }
    }
}

// ---------------- fold W blocks: Weff[640][64] ----------------
__global__ void weff_kernel(const float* __restrict__ W, float* __restrict__ Weff) {
    int i = blockIdx.x * blockDim.x + threadIdx.x;
    if (i >= 640 * 64) return;
    int r = i >> 6, o = i & 63;
    float v;
    if (r < 128)      v = W[r * 64 + o] + W[(r + 384) * 64 + o];
    else if (r < 384) v = W[r * 64 + o];
    else              v = W[(r + 128) * 64 + o];
    Weff[i] = v;
}

// ---------------- final dense: out = [x|h1f|h2f|h1r|h2r] @ Weff + b ----------------
// BN=64, KT=64 (10 tiles, 20 barriers vs 40), 256 threads, 4x4 micro-tile.
// h1 sources staged from bf16. LDS 34.8KB -> 4 blocks/CU.
// X swizzle rowx = srow ^ (q<<4), q = k-quarter of 16: writes 2 lanes/bank (free),
// read float4 base (ty*4)^flip valid since flip only touches bits 4-5.
__global__ __launch_bounds__(256) void gemm_kernel(
    const float* __restrict__ X0, const unsigned* __restrict__ H1FB,
    const float* __restrict__ H2F, const unsigned* __restrict__ H1RB,
    const float* __restrict__ H2R,
    const float* __restrict__ Weff, const float* __restrict__ bias,
    float* __restrict__ out, int N) {
    __shared__ float Xs[KT3][BN4 + 4];  // 64 x 68
    __shared__ float Ws[KT3][68];
    int tid = threadIdx.x;              // 0..255
    int tx = tid & 15, ty = tid >> 4;   // ty 0..15
    int nodeBase = blockIdx.x * BN4;
    int srow = tid >> 2;                // 0..63
    int q = tid & 3;                    // k-quarter (16 k each)
    int rowx = srow ^ (q << 4);
    int kb = q * 16;
    int wrow = tid >> 2, wc0 = (tid & 3) * 4;  // W stage: 4 float4/thread, same row
    float acc[4][4];
#pragma unroll
    for (int i = 0; i < 4; i++)
#pragma unroll
        for (int j = 0; j < 4; j++) acc[i][j] = 0.f;

    for (int t = 0; t < 10; ++t) {
        const int si = t >> 1;
        const int cb = (t & 1) * 64;
        const int n = nodeBase + srow;
        float vv[16];
        if (si == 1 || si == 3) {  // bf16 source
            const unsigned* bsrc = (si == 1) ? H1FB : H1RB;
            uint4 b0, b1;
            if (n < N) {
                const unsigned* p = bsrc + (size_t)n * 64 + (cb + kb) / 2;
                b0 = *(const uint4*)(p);
                b1 = *(const uint4*)(p + 4);
            } else {
                b0 = make_uint4(0u, 0u, 0u, 0u); b1 = b0;
            }
            vv[0] = blo(b0.x);  vv[1] = bhi(b0.x);  vv[2] = blo(b0.y);  vv[3] = bhi(b0.y);
            vv[4] = blo(b0.z);  vv[5] = bhi(b0.z);  vv[6] = blo(b0.w);  vv[7] = bhi(b0.w);
            vv[8] = blo(b1.x);  vv[9] = bhi(b1.x);  vv[10] = blo(b1.y); vv[11] = bhi(b1.y);
            vv[12] = blo(b1.z); vv[13] = bhi(b1.z); vv[14] = blo(b1.w); vv[15] = bhi(b1.w);
        } else {
            const float* fsrc = (si == 0) ? X0 : (si == 2) ? H2F : H2R;
            float4 v0, v1, v2, v3;
            if (n < N) {
                const float* p = fsrc + (size_t)n * 128 + cb + kb;
                v0 = *(const float4*)(p);
                v1 = *(const float4*)(p + 4);
                v2 = *(const float4*)(p + 8);
                v3 = *(const float4*)(p + 12);
            } else {
                v0 = make_float4(0.f, 0.f, 0.f, 0.f); v1 = v0; v2 = v0; v3 = v0;
            }
            vv[0] = v0.x;  vv[1] = v0.y;  vv[2] = v0.z;  vv[3] = v0.w;
            vv[4] = v1.x;  vv[5] = v1.y;  vv[6] = v1.z;  vv[7] = v1.w;
            vv[8] = v2.x;  vv[9] = v2.y;  vv[10] = v2.z; vv[11] = v2.w;
            vv[12] = v3.x; vv[13] = v3.y; vv[14] = v3.z; vv[15] = v3.w;
        }
#pragma unroll
        for (int j = 0; j < 16; j++) Xs[kb + j][rowx] = vv[j];
        // stage W: 4 consecutive float4 per thread (one row chunk)
#pragma unroll
        for (int q2 = 0; q2 < 4; q2++) {
            *(float4*)&Ws[wrow][(wc0 + q2) * 4] =
                *(const float4*)&Weff[(size_t)(t * 64 + wrow) * 64 + (wc0 + q2) * 4];
        }
        __syncthreads();
#pragma unroll
        for (int k = 0; k < KT3; k++) {
            const int flip = (k >> 4) << 4;
            float4 x4 = *(const float4*)&Xs[k][(ty * 4) ^ flip];
            float4 w4 = *(const float4*)&Ws[k][tx * 4];
            float xv[4] = {x4.x, x4.y, x4.z, x4.w};
            float wv[4] = {w4.x, w4.y, w4.z, w4.w};
#pragma unroll
            for (int i = 0; i < 4; i++)
#pragma unroll
                for (int j = 0; j < 4; j++) acc[i][j] += xv[i] * wv[j];
        }
        __syncthreads();
    }
    float4 bv = *(const float4*)&bias[tx * 4];
#pragma unroll
    for (int i = 0; i < 4; i++) {
        int n = nodeBase + ty * 4 + i;
        if (n < N) {
            float4 o;
            o.x = acc[i][0] + bv.x; o.y = acc[i][1] + bv.y;
            o.z = acc[i][2] + bv.z; o.w = acc[i][3] + bv.w;
            *(float4*)&out[(size_t)n * 64 + tx * 4] = o;
        }
    }
}

extern "C" void kernel_launch(void* const* d_in, const int* in_sizes, int n_in,
                              void* d_out, int out_size, void* d_ws, size_t ws_size,
                              hipStream_t stream) {
    const float* feature = (const float*)d_in[0];
    const int*   eidx    = (const int*)d_in[1];
    const float* af_s    = (const float*)d_in[2];
    const float* af_d    = (const float*)d_in[3];
    const float* ar_s    = (const float*)d_in[4];
    const float* ar_d    = (const float*)d_in[5];
    const float* W       = (const float*)d_in[6];
    const float* bias    = (const float*)d_in[7];
    float* out = (float*)d_out;
    const int N = in_sizes[0] / F;
    const int E = in_sizes[1] / 2;
    const int* src = eidx;
    const int* dst = eidx + E;

    char* ws = (char*)d_ws;
    size_t off = 0;
    auto alloc = [&](size_t b) { size_t r = off; off = (off + b + 255) & ~(size_t)255; return r; };
    float*    h2f  = (float*)(ws + alloc((size_t)N * F * 4));
    float*    h2r  = (float*)(ws + alloc((size_t)N * F * 4));
    unsigned* h1fb = (unsigned*)(ws + alloc((size_t)N * 64 * 4));
    unsigned* h1rb = (unsigned*)(ws + alloc((size_t)N * 64 * 4));
    int*   rsF   = (int*)(ws + alloc((size_t)(N + 1) * 4));
    int*   rsR   = (int*)(ws + alloc((size_t)(N + 1) * 4));
    int*   colF  = (int*)(ws + alloc((size_t)E * 4));
    int*   colR  = (int*)(ws + alloc((size_t)E * 4));
    int*   ints4 = (int*)(ws + alloc((size_t)4 * N * 4));
    int *degF = ints4, *degR = ints4 + N, *curF = ints4 + 2 * N, *curR = ints4 + 3 * N;
    float* fls8 = (float*)(ws + alloc((size_t)8 * N * 4));
    float *sf = fls8, *df = fls8 + N, *sr = fls8 + 2 * (size_t)N, *dr = fls8 + 3 * (size_t)N;
    float *s2f = fls8 + 4 * (size_t)N, *d2f = fls8 + 5 * (size_t)N;
    float *s2r = fls8 + 6 * (size_t)N, *d2r = fls8 + 7 * (size_t)N;
    int*   bsums = (int*)(ws + alloc(256 * 4));
    float* Weff  = (float*)(ws + alloc(640 * 64 * 4));

    const int nb = (N + 1023) / 1024;
    zero_ints<<<(4 * N + 255) / 256, 256, 0, stream>>>(ints4, 4 * N);
    hist_kernel<<<(E + 255) / 256, 256, 0, stream>>>(src, dst, degF, degR, E);
    scan_pass1<<<dim3(nb, 2), 256, 0, stream>>>(degF, degR, rsF, rsR, bsums, N);
    scan_pass2<<<dim3(1, 2), 128, 0, stream>>>(bsums, nb);
    scan_pass3<<<dim3(nb, 2), 256, 0, stream>>>(rsF, rsR, bsums, N);
    scatter_kernel<<<(E + 255) / 256, 256, 0, stream>>>(src, dst, rsF, rsR, curF, curR, colF, colR, E);
    sd4_kernel<<<(N + 3) / 4, 256, 0, stream>>>(feature, af_s, af_d, ar_s, ar_d, sf, df, sr, dr, N);

    // hop 1: gather fp32 feature, write bf16 h1 + fused next-hop dots (fp32-exact)
    AggDir F1{feature, nullptr, sf, df, rsF, colF, nullptr, h1fb, af_s, af_d, s2f, d2f};
    AggDir R1{feature, nullptr, sr, dr, rsR, colR, nullptr, h1rb, ar_s, ar_d, s2r, d2r};
    agg_kernel<false, true><<<dim3((N + 15) / 16, 2), 256, 0, stream>>>(F1, R1, N);
    // hop 2: gather bf16 h1, write fp32 h2
    AggDir F2{nullptr, h1fb, s2f, d2f, rsF, colF, h2f, nullptr, nullptr, nullptr, nullptr, nullptr};
    AggDir R2{nullptr, h1rb, s2r, d2r, rsR, colR, h2r, nullptr, nullptr, nullptr, nullptr, nullptr};
    agg_kernel<true, false><<<dim3((N + 15) / 16, 2), 256, 0, stream>>>(F2, R2, N);

    weff_kernel<<<(640 * 64 + 255) / 256, 256, 0, stream>>>(W, Weff);
    gemm_kernel<<<(N + BN4 - 1) / BN4, 256, 0, stream>>>(feature, h1fb, h2f, h1rb, h2r, Weff, bias, out, N);
}

// Round 10
// 464.213 us; speedup vs baseline: 1.3821x; 1.0792x over previous
//
#include <hip/hip_runtime.h>
#include <math.h>

#define F 128
#define OUTDIM 64
#define NEG 0.2f
#define BN4 64
#define KT2 32

// ---------------- bf16 helpers ----------------
__device__ __forceinline__ float blo(unsigned u) { return __uint_as_float(u << 16); }
__device__ __forceinline__ float bhi(unsigned u) { return __uint_as_float(u & 0xFFFF0000u); }
__device__ __forceinline__ unsigned bpack(float a, float b) {  // rtne both
    unsigned ua = __float_as_uint(a), ub = __float_as_uint(b);
    ua += 0x7FFFu + ((ua >> 16) & 1u);
    ub += 0x7FFFu + ((ub >> 16) & 1u);
    return (ua >> 16) | (ub & 0xFFFF0000u);
}

// ---------------- utility ----------------
__global__ void zero_ints(int* __restrict__ p, int n) {
    int i = blockIdx.x * blockDim.x + threadIdx.x;
    if (i < n) p[i] = 0;
}

// ---------------- CSR build ----------------
__global__ void hist_kernel(const int* __restrict__ src, const int* __restrict__ dst,
                            int* __restrict__ degF, int* __restrict__ degR, int E) {
    int e = blockIdx.x * blockDim.x + threadIdx.x;
    if (e < E) {
        atomicAdd(&degF[dst[e]], 1);
        atomicAdd(&degR[src[e]], 1);
    }
}

__global__ void scan_pass1(const int* __restrict__ degF, const int* __restrict__ degR,
                           int* __restrict__ rsF, int* __restrict__ rsR,
                           int* __restrict__ bsums, int N) {
    const int arr = blockIdx.y;
    const int* deg = arr ? degR : degF;
    int* rs = arr ? rsR : rsF;
    int tid = threadIdx.x;
    int base = blockIdx.x * 1024 + tid * 4;
    int v[4];
#pragma unroll
    for (int i = 0; i < 4; i++) v[i] = (base + i < N) ? deg[base + i] : 0;
    int s1 = v[0] + v[1] + v[2] + v[3];
    __shared__ int sd[256];
    sd[tid] = s1;
    __syncthreads();
    for (int off = 1; off < 256; off <<= 1) {
        int t = (tid >= off) ? sd[tid - off] : 0;
        __syncthreads();
        sd[tid] += t;
        __syncthreads();
    }
    int run = sd[tid] - s1;
#pragma unroll
    for (int i = 0; i < 4; i++) {
        run += v[i];
        if (base + i < N) rs[base + i + 1] = run;
    }
    if (tid == 255) bsums[arr * 128 + blockIdx.x] = sd[255];
    if (tid == 0 && blockIdx.x == 0) rs[0] = 0;
}

__global__ void scan_pass2(int* __restrict__ bsums, int nb) {
    int arr = blockIdx.y;
    int tid = threadIdx.x;  // 128
    __shared__ int sd[128];
    int v = (tid < nb) ? bsums[arr * 128 + tid] : 0;
    sd[tid] = v;
    __syncthreads();
    for (int off = 1; off < 128; off <<= 1) {
        int t = (tid >= off) ? sd[tid - off] : 0;
        __syncthreads();
        sd[tid] += t;
        __syncthreads();
    }
    bsums[arr * 128 + tid] = sd[tid];
}

__global__ void scan_pass3(int* __restrict__ rsF, int* __restrict__ rsR,
                           const int* __restrict__ bsums, int N) {
    int arr = blockIdx.y;
    if (blockIdx.x == 0) return;
    int* rs = arr ? rsR : rsF;
    int off = bsums[arr * 128 + blockIdx.x - 1];
    int base = blockIdx.x * 1024 + threadIdx.x * 4;
#pragma unroll
    for (int i = 0; i < 4; i++)
        if (base + i < N) rs[base + i + 1] += off;
}

__global__ void scatter_kernel(const int* __restrict__ src, const int* __restrict__ dst,
                               const int* __restrict__ rsF, const int* __restrict__ rsR,
                               int* __restrict__ curF, int* __restrict__ curR,
                               int* __restrict__ colF, int* __restrict__ colR, int E) {
    int e = blockIdx.x * blockDim.x + threadIdx.x;
    if (e < E) {
        int s = src[e], d = dst[e];
        int pf = rsF[d] + atomicAdd(&curF[d], 1);
        colF[pf] = s;
        int pr = rsR[s] + atomicAdd(&curR[s], 1);
        colR[pr] = d;
    }
}

// ---------------- per-node attention scalars ----------------
__global__ void sd4_kernel(const float* __restrict__ x,
                           const float* __restrict__ af_s, const float* __restrict__ af_d,
                           const float* __restrict__ ar_s, const float* __restrict__ ar_d,
                           float* __restrict__ sf, float* __restrict__ df,
                           float* __restrict__ sr, float* __restrict__ dr, int N) {
    int node = blockIdx.x * 4 + (threadIdx.x >> 6);
    int lane = threadIdx.x & 63;
    if (node >= N) return;
    const float2 xv = *(const float2*)&x[(size_t)node * F + 2 * lane];
    float2 a;
    a = *(const float2*)&af_s[2 * lane]; float vsf = xv.x * a.x + xv.y * a.y;
    a = *(const float2*)&af_d[2 * lane]; float vdf = xv.x * a.x + xv.y * a.y;
    a = *(const float2*)&ar_s[2 * lane]; float vsr = xv.x * a.x + xv.y * a.y;
    a = *(const float2*)&ar_d[2 * lane]; float vdr = xv.x * a.x + xv.y * a.y;
#pragma unroll
    for (int off = 32; off > 0; off >>= 1) {
        vsf += __shfl_xor(vsf, off);
        vdf += __shfl_xor(vdf, off);
        vsr += __shfl_xor(vsr, off);
        vdr += __shfl_xor(vdr, off);
    }
    if (lane == 0) { sf[node] = vsf; df[node] = vdf; sr[node] = vsr; dr[node] = vdr; }
}

// ---------------- fused dual-direction attention hop ----------------
// quarter-wave (16 lanes x 8 floats) per node; blockIdx.y selects direction.
// 4-deep gather pipeline (depth 8 pushed VGPR>128 -> 2 waves/SIMD; depth 4
// targets <=128 VGPR -> 4 waves/SIMD for latency hiding).
struct AggDir {
    const float* hin;        // [N][128] fp32 (BFIN=false)
    const unsigned* hin_bf;  // [N][64]  bf16x2 (BFIN=true)
    const float* s;          // [N]
    const float* d;          // [N]
    const int* rs;           // [N+1]
    const int* col;          // [E]
    float* hout;             // [N][128] fp32 (BFOUT=false)
    unsigned* hout_bf;       // [N][64]  bf16x2 (BFOUT=true)
    const float* a_s;        // nullable: fused next-hop dots
    const float* a_d;
    float* s_out;
    float* d_out;
};

template <bool BFIN, bool BFOUT>
__global__ __launch_bounds__(256) void agg_kernel(AggDir D0, AggDir D1, int N) {
    AggDir P = blockIdx.y ? D1 : D0;
    int node = blockIdx.x * 16 + (threadIdx.x >> 4);
    int lane = threadIdx.x & 15;           // within quarter-wave
    int qbase = threadIdx.x & 48;          // quarter offset inside the wave
    if (node >= N) return;
    float di = P.d[node];
    int beg = P.rs[node], end = P.rs[node + 1];
    int deg = end - beg;
    float m = -INFINITY, l = 0.f;
    float4 a0 = make_float4(0.f, 0.f, 0.f, 0.f);
    float4 a1 = make_float4(0.f, 0.f, 0.f, 0.f);

    for (int base = 0; base < deg; base += 16) {
        int cnt = min(16, deg - base);
        int sj_l = 0;
        float e_l = -INFINITY;
        if (lane < cnt) {
            sj_l = P.col[beg + base + lane];
            float e = P.s[sj_l] + di;
            e_l = (e >= 0.f) ? e : NEG * e;
        }
        float bm = e_l;
#pragma unroll
        for (int off = 8; off > 0; off >>= 1) bm = fmaxf(bm, __shfl_xor(bm, off));
        float nm = fmaxf(m, bm);
        float p_l = (lane < cnt) ? __expf(e_l - nm) : 0.f;
        float ps = p_l;
#pragma unroll
        for (int off = 8; off > 0; off >>= 1) ps += __shfl_xor(ps, off);
        float sc = (m == -INFINITY) ? 0.f : __expf(m - nm);
        l = l * sc + ps;
        a0.x *= sc; a0.y *= sc; a0.z *= sc; a0.w *= sc;
        a1.x *= sc; a1.y *= sc; a1.z *= sc; a1.w *= sc;
        for (int j0 = 0; j0 < cnt; j0 += 4) {
            int sj[4]; float p[4]; float4 h0[4], h1[4];
#pragma unroll
            for (int u = 0; u < 4; u++) {
                sj[u] = __shfl(sj_l, qbase + j0 + u);
                p[u]  = __shfl(p_l,  qbase + j0 + u);
            }
#pragma unroll
            for (int u = 0; u < 4; u++) {
                if (j0 + u < cnt) {  // uniform per quarter-wave
                    if (BFIN) {
                        uint4 hb = *(const uint4*)&P.hin_bf[(size_t)sj[u] * 64 + 4 * lane];
                        h0[u].x = blo(hb.x); h0[u].y = bhi(hb.x);
                        h0[u].z = blo(hb.y); h0[u].w = bhi(hb.y);
                        h1[u].x = blo(hb.z); h1[u].y = bhi(hb.z);
                        h1[u].z = blo(hb.w); h1[u].w = bhi(hb.w);
                    } else {
                        const float* rp = &P.hin[(size_t)sj[u] * F + 8 * lane];
                        h0[u] = *(const float4*)(rp);
                        h1[u] = *(const float4*)(rp + 4);
                    }
                } else {
                    h0[u] = make_float4(0.f, 0.f, 0.f, 0.f);
                    h1[u] = h0[u];
                }
            }
#pragma unroll
            for (int u = 0; u < 4; u++) {
                a0.x += p[u] * h0[u].x; a0.y += p[u] * h0[u].y;
                a0.z += p[u] * h0[u].z; a0.w += p[u] * h0[u].w;
                a1.x += p[u] * h1[u].x; a1.y += p[u] * h1[u].y;
                a1.z += p[u] * h1[u].z; a1.w += p[u] * h1[u].w;
            }
        }
        m = nm;
    }

    float4 o0, o1;
    if (deg > 0) {
        float inv = 1.f / (l + 1e-16f);
        o0.x = a0.x * inv; o0.y = a0.y * inv; o0.z = a0.z * inv; o0.w = a0.w * inv;
        o1.x = a1.x * inv; o1.y = a1.y * inv; o1.z = a1.z * inv; o1.w = a1.w * inv;
    } else {
        o0 = make_float4(0.f, 0.f, 0.f, 0.f);
        o1 = o0;
    }
    if (BFOUT) {
        uint4 hb;
        hb.x = bpack(o0.x, o0.y); hb.y = bpack(o0.z, o0.w);
        hb.z = bpack(o1.x, o1.y); hb.w = bpack(o1.z, o1.w);
        *(uint4*)&P.hout_bf[(size_t)node * 64 + 4 * lane] = hb;
    } else {
        float* op = &P.hout[(size_t)node * F + 8 * lane];
        *(float4*)(op) = o0;
        *(float4*)(op + 4) = o1;
    }
    if (P.a_s) {
        float4 b0, b1;
        b0 = *(const float4*)&P.a_s[8 * lane];
        b1 = *(const float4*)&P.a_s[8 * lane + 4];
        float vs = o0.x * b0.x + o0.y * b0.y + o0.z * b0.z + o0.w * b0.w
                 + o1.x * b1.x + o1.y * b1.y + o1.z * b1.z + o1.w * b1.w;
        b0 = *(const float4*)&P.a_d[8 * lane];
        b1 = *(const float4*)&P.a_d[8 * lane + 4];
        float vd = o0.x * b0.x + o0.y * b0.y + o0.z * b0.z + o0.w * b0.w
                 + o1.x * b1.x + o1.y * b1.y + o1.z * b1.z + o1.w * b1.w;
#pragma unroll
        for (int off = 8; off > 0; off >>= 1) {
            vs += __shfl_xor(vs, off);
            vd += __shfl_xor(vd, off);
        }
        if (lane == 0) { P.s_out[node] = vs; P.d_out[node] = vd; }
    }
}

// ---------------- fold W blocks: Weff[640][64] ----------------
__global__ void weff_kernel(const float* __restrict__ W, float* __restrict__ Weff) {
    int i = blockIdx.x * blockDim.x + threadIdx.x;
    if (i >= 640 * 64) return;
    int r = i >> 6, o = i & 63;
    float v;
    if (r < 128)      v = W[r * 64 + o] + W[(r + 384) * 64 + o];
    else if (r < 384) v = W[r * 64 + o];
    else              v = W[(r + 128) * 64 + o];
    Weff[i] = v;
}

// ---------------- final dense: out = [x|h1f|h2f|h1r|h2r] @ Weff + b ----------------
// R8 proven shape: BN=64, KT=32, 256 threads, 4x4 micro-tile, single-buffered,
// 17.4KB LDS -> 6 blocks/CU. h1 tiles staged from bf16 (1 uint4/thread).
__global__ __launch_bounds__(256) void gemm_kernel(
    const float* __restrict__ X0, const unsigned* __restrict__ H1FB,
    const float* __restrict__ H2F, const unsigned* __restrict__ H1RB,
    const float* __restrict__ H2R,
    const float* __restrict__ Weff, const float* __restrict__ bias,
    float* __restrict__ out, int N) {
    __shared__ float Xs[KT2][BN4 + 4];  // 32 x 68
    __shared__ float Ws[KT2][68];
    int tid = threadIdx.x;              // 0..255
    int tx = tid & 15, ty = tid >> 4;   // ty 0..15
    int nodeBase = blockIdx.x * BN4;
    int srow = tid >> 2;                // 0..63
    int q = tid & 3;                    // k-quarter (8 k each)
    int rowx = srow ^ (q << 4);
    int kb = q * 8;
    float acc[4][4];
#pragma unroll
    for (int i = 0; i < 4; i++)
#pragma unroll
        for (int j = 0; j < 4; j++) acc[i][j] = 0.f;

    for (int t = 0; t < 20; ++t) {
        const int si = t >> 2;
        const int cb = (t & 3) * 32;
        const int n = nodeBase + srow;
        float vv[8];
        if (si == 1 || si == 3) {  // bf16 source
            const unsigned* bsrc = (si == 1) ? H1FB : H1RB;
            uint4 b0;
            if (n < N) b0 = *(const uint4*)(bsrc + (size_t)n * 64 + (cb + kb) / 2);
            else       b0 = make_uint4(0u, 0u, 0u, 0u);
            vv[0] = blo(b0.x); vv[1] = bhi(b0.x); vv[2] = blo(b0.y); vv[3] = bhi(b0.y);
            vv[4] = blo(b0.z); vv[5] = bhi(b0.z); vv[6] = blo(b0.w); vv[7] = bhi(b0.w);
        } else {
            const float* fsrc = (si == 0) ? X0 : (si == 2) ? H2F : H2R;
            float4 v0, v1;
            if (n < N) {
                const float* p = fsrc + (size_t)n * 128 + cb + kb;
                v0 = *(const float4*)(p);
                v1 = *(const float4*)(p + 4);
            } else {
                v0 = make_float4(0.f, 0.f, 0.f, 0.f); v1 = v0;
            }
            vv[0] = v0.x; vv[1] = v0.y; vv[2] = v0.z; vv[3] = v0.w;
            vv[4] = v1.x; vv[5] = v1.y; vv[6] = v1.z; vv[7] = v1.w;
        }
#pragma unroll
        for (int j = 0; j < 8; j++) Xs[kb + j][rowx] = vv[j];
        // stage W: two float4 per thread (32x64 floats)
#pragma unroll
        for (int q2 = 0; q2 < 2; q2++) {
            int f = tid * 2 + q2;           // 0..511 float4s
            int wr = f >> 4, wc4 = f & 15;
            *(float4*)&Ws[wr][wc4 * 4] =
                *(const float4*)&Weff[(size_t)(t * 32 + wr) * 64 + wc4 * 4];
        }
        __syncthreads();
#pragma unroll
        for (int k = 0; k < KT2; k++) {
            const int flip = (k >> 3) << 4;
            float4 x4 = *(const float4*)&Xs[k][(ty * 4) ^ flip];
            float4 w4 = *(const float4*)&Ws[k][tx * 4];
            float xv[4] = {x4.x, x4.y, x4.z, x4.w};
            float wv[4] = {w4.x, w4.y, w4.z, w4.w};
#pragma unroll
            for (int i = 0; i < 4; i++)
#pragma unroll
                for (int j = 0; j < 4; j++) acc[i][j] += xv[i] * wv[j];
        }
        __syncthreads();
    }
    float4 bv = *(const float4*)&bias[tx * 4];
#pragma unroll
    for (int i = 0; i < 4; i++) {
        int n = nodeBase + ty * 4 + i;
        if (n < N) {
            float4 o;
            o.x = acc[i][0] + bv.x; o.y = acc[i][1] + bv.y;
            o.z = acc[i][2] + bv.z; o.w = acc[i][3] + bv.w;
            *(float4*)&out[(size_t)n * 64 + tx * 4] = o;
        }
    }
}

extern "C" void kernel_launch(void* const* d_in, const int* in_sizes, int n_in,
                              void* d_out, int out_size, void* d_ws, size_t ws_size,
                              hipStream_t stream) {
    const float* feature = (const float*)d_in[0];
    const int*   eidx    = (const int*)d_in[1];
    const float* af_s    = (const float*)d_in[2];
    const float* af_d    = (const float*)d_in[3];
    const float* ar_s    = (const float*)d_in[4];
    const float* ar_d    = (const float*)d_in[5];
    const float* W       = (const float*)d_in[6];
    const float* bias    = (const float*)d_in[7];
    float* out = (float*)d_out;
    const int N = in_sizes[0] / F;
    const int E = in_sizes[1] / 2;
    const int* src = eidx;
    const int* dst = eidx + E;

    char* ws = (char*)d_ws;
    size_t off = 0;
    auto alloc = [&](size_t b) { size_t r = off; off = (off + b + 255) & ~(size_t)255; return r; };
    float*    h2f  = (float*)(ws + alloc((size_t)N * F * 4));
    float*    h2r  = (float*)(ws + alloc((size_t)N * F * 4));
    unsigned* h1fb = (unsigned*)(ws + alloc((size_t)N * 64 * 4));
    unsigned* h1rb = (unsigned*)(ws + alloc((size_t)N * 64 * 4));
    int*   rsF   = (int*)(ws + alloc((size_t)(N + 1) * 4));
    int*   rsR   = (int*)(ws + alloc((size_t)(N + 1) * 4));
    int*   colF  = (int*)(ws + alloc((size_t)E * 4));
    int*   colR  = (int*)(ws + alloc((size_t)E * 4));
    int*   ints4 = (int*)(ws + alloc((size_t)4 * N * 4));
    int *degF = ints4, *degR = ints4 + N, *curF = ints4 + 2 * N, *curR = ints4 + 3 * N;
    float* fls8 = (float*)(ws + alloc((size_t)8 * N * 4));
    float *sf = fls8, *df = fls8 + N, *sr = fls8 + 2 * (size_t)N, *dr = fls8 + 3 * (size_t)N;
    float *s2f = fls8 + 4 * (size_t)N, *d2f = fls8 + 5 * (size_t)N;
    float *s2r = fls8 + 6 * (size_t)N, *d2r = fls8 + 7 * (size_t)N;
    int*   bsums = (int*)(ws + alloc(256 * 4));
    float* Weff  = (float*)(ws + alloc(640 * 64 * 4));

    const int nb = (N + 1023) / 1024;
    zero_ints<<<(4 * N + 255) / 256, 256, 0, stream>>>(ints4, 4 * N);
    hist_kernel<<<(E + 255) / 256, 256, 0, stream>>>(src, dst, degF, degR, E);
    scan_pass1<<<dim3(nb, 2), 256, 0, stream>>>(degF, degR, rsF, rsR, bsums, N);
    scan_pass2<<<dim3(1, 2), 128, 0, stream>>>(bsums, nb);
    scan_pass3<<<dim3(nb, 2), 256, 0, stream>>>(rsF, rsR, bsums, N);
    scatter_kernel<<<(E + 255) / 256, 256, 0, stream>>>(src, dst, rsF, rsR, curF, curR, colF, colR, E);
    sd4_kernel<<<(N + 3) / 4, 256, 0, stream>>>(feature, af_s, af_d, ar_s, ar_d, sf, df, sr, dr, N);

    // hop 1: gather fp32 feature, write bf16 h1 + fused next-hop dots (fp32-exact)
    AggDir F1{feature, nullptr, sf, df, rsF, colF, nullptr, h1fb, af_s, af_d, s2f, d2f};
    AggDir R1{feature, nullptr, sr, dr, rsR, colR, nullptr, h1rb, ar_s, ar_d, s2r, d2r};
    agg_kernel<false, true><<<dim3((N + 15) / 16, 2), 256, 0, stream>>>(F1, R1, N);
    // hop 2: gather bf16 h1, write fp32 h2
    AggDir F2{nullptr, h1fb, s2f, d2f, rsF, colF, h2f, nullptr, nullptr, nullptr, nullptr, nullptr};
    AggDir R2{nullptr, h1rb, s2r, d2r, rsR, colR, h2r, nullptr, nullptr, nullptr, nullptr, nullptr};
    agg_kernel<true, false><<<dim3((N + 15) / 16, 2), 256, 0, stream>>>(F2, R2, N);

    weff_kernel<<<(640 * 64 + 255) / 256, 256, 0, stream>>>(W, Weff);
    gemm_kernel<<<(N + BN4 - 1) / BN4, 256, 0, stream>>>(feature, h1fb, h2f, h1rb, h2r, Weff, bias, out, N);
}

// Round 11
// 401.517 us; speedup vs baseline: 1.5979x; 1.1561x over previous
//
#include <hip/hip_runtime.h>
#include <math.h>

#define F 128
#define OUTDIM 64
#define NEG 0.2f

typedef __attribute__((ext_vector_type(8))) short bf16x8;
typedef __attribute__((ext_vector_type(4))) float f32x4;

// ---------------- bf16 helpers ----------------
__device__ __forceinline__ float blo(unsigned u) { return __uint_as_float(u << 16); }
__device__ __forceinline__ float bhi(unsigned u) { return __uint_as_float(u & 0xFFFF0000u); }
__device__ __forceinline__ unsigned bpack(float a, float b) {  // rtne both
    unsigned ua = __float_as_uint(a), ub = __float_as_uint(b);
    ua += 0x7FFFu + ((ua >> 16) & 1u);
    ub += 0x7FFFu + ((ub >> 16) & 1u);
    return (ua >> 16) | (ub & 0xFFFF0000u);
}

// ---------------- utility ----------------
__global__ void zero_ints(int* __restrict__ p, int n) {
    int i = blockIdx.x * blockDim.x + threadIdx.x;
    if (i < n) p[i] = 0;
}

// ---------------- CSR build ----------------
__global__ void hist_kernel(const int* __restrict__ src, const int* __restrict__ dst,
                            int* __restrict__ degF, int* __restrict__ degR, int E) {
    int e = blockIdx.x * blockDim.x + threadIdx.x;
    if (e < E) {
        atomicAdd(&degF[dst[e]], 1);
        atomicAdd(&degR[src[e]], 1);
    }
}

__global__ void scan_pass1(const int* __restrict__ degF, const int* __restrict__ degR,
                           int* __restrict__ rsF, int* __restrict__ rsR,
                           int* __restrict__ bsums, int N) {
    const int arr = blockIdx.y;
    const int* deg = arr ? degR : degF;
    int* rs = arr ? rsR : rsF;
    int tid = threadIdx.x;
    int base = blockIdx.x * 1024 + tid * 4;
    int v[4];
#pragma unroll
    for (int i = 0; i < 4; i++) v[i] = (base + i < N) ? deg[base + i] : 0;
    int s1 = v[0] + v[1] + v[2] + v[3];
    __shared__ int sd[256];
    sd[tid] = s1;
    __syncthreads();
    for (int off = 1; off < 256; off <<= 1) {
        int t = (tid >= off) ? sd[tid - off] : 0;
        __syncthreads();
        sd[tid] += t;
        __syncthreads();
    }
    int run = sd[tid] - s1;
#pragma unroll
    for (int i = 0; i < 4; i++) {
        run += v[i];
        if (base + i < N) rs[base + i + 1] = run;
    }
    if (tid == 255) bsums[arr * 128 + blockIdx.x] = sd[255];
    if (tid == 0 && blockIdx.x == 0) rs[0] = 0;
}

__global__ void scan_pass2(int* __restrict__ bsums, int nb) {
    int arr = blockIdx.y;
    int tid = threadIdx.x;  // 128
    __shared__ int sd[128];
    int v = (tid < nb) ? bsums[arr * 128 + tid] : 0;
    sd[tid] = v;
    __syncthreads();
    for (int off = 1; off < 128; off <<= 1) {
        int t = (tid >= off) ? sd[tid - off] : 0;
        __syncthreads();
        sd[tid] += t;
        __syncthreads();
    }
    bsums[arr * 128 + tid] = sd[tid];
}

__global__ void scan_pass3(int* __restrict__ rsF, int* __restrict__ rsR,
                           const int* __restrict__ bsums, int N) {
    int arr = blockIdx.y;
    if (blockIdx.x == 0) return;
    int* rs = arr ? rsR : rsF;
    int off = bsums[arr * 128 + blockIdx.x - 1];
    int base = blockIdx.x * 1024 + threadIdx.x * 4;
#pragma unroll
    for (int i = 0; i < 4; i++)
        if (base + i < N) rs[base + i + 1] += off;
}

__global__ void scatter_kernel(const int* __restrict__ src, const int* __restrict__ dst,
                               const int* __restrict__ rsF, const int* __restrict__ rsR,
                               int* __restrict__ curF, int* __restrict__ curR,
                               int* __restrict__ colF, int* __restrict__ colR, int E) {
    int e = blockIdx.x * blockDim.x + threadIdx.x;
    if (e < E) {
        int s = src[e], d = dst[e];
        int pf = rsF[d] + atomicAdd(&curF[d], 1);
        colF[pf] = s;
        int pr = rsR[s] + atomicAdd(&curR[s], 1);
        colR[pr] = d;
    }
}

// ---------------- per-node attention scalars + bf16 feature copy ----------------
__global__ void sd4_kernel(const float* __restrict__ x,
                           const float* __restrict__ af_s, const float* __restrict__ af_d,
                           const float* __restrict__ ar_s, const float* __restrict__ ar_d,
                           float* __restrict__ sf, float* __restrict__ df,
                           float* __restrict__ sr, float* __restrict__ dr,
                           unsigned* __restrict__ xbf, int N) {
    int node = blockIdx.x * 4 + (threadIdx.x >> 6);
    int lane = threadIdx.x & 63;
    if (node >= N) return;
    const float2 xv = *(const float2*)&x[(size_t)node * F + 2 * lane];
    xbf[(size_t)node * 64 + lane] = bpack(xv.x, xv.y);
    float2 a;
    a = *(const float2*)&af_s[2 * lane]; float vsf = xv.x * a.x + xv.y * a.y;
    a = *(const float2*)&af_d[2 * lane]; float vdf = xv.x * a.x + xv.y * a.y;
    a = *(const float2*)&ar_s[2 * lane]; float vsr = xv.x * a.x + xv.y * a.y;
    a = *(const float2*)&ar_d[2 * lane]; float vdr = xv.x * a.x + xv.y * a.y;
#pragma unroll
    for (int off = 32; off > 0; off >>= 1) {
        vsf += __shfl_xor(vsf, off);
        vdf += __shfl_xor(vdf, off);
        vsr += __shfl_xor(vsr, off);
        vdr += __shfl_xor(vdr, off);
    }
    if (lane == 0) { sf[node] = vsf; df[node] = vdf; sr[node] = vsr; dr[node] = vdr; }
}

// ---------------- fused dual-direction attention hop ----------------
// quarter-wave (16 lanes x 8 floats) per node; blockIdx.y selects direction.
// 4-deep gather pipeline (depth 8 pushed VGPR>128 -> 2 waves/SIMD).
struct AggDir {
    const float* hin;        // [N][128] fp32 (BFIN=false)
    const unsigned* hin_bf;  // [N][64]  bf16x2 (BFIN=true)
    const float* s;          // [N]
    const float* d;          // [N]
    const int* rs;           // [N+1]
    const int* col;          // [E]
    float* hout;             // [N][128] fp32 (BFOUT=false)
    unsigned* hout_bf;       // [N][64]  bf16x2 (BFOUT=true)
    const float* a_s;        // nullable: fused next-hop dots
    const float* a_d;
    float* s_out;
    float* d_out;
};

template <bool BFIN, bool BFOUT>
__global__ __launch_bounds__(256) void agg_kernel(AggDir D0, AggDir D1, int N) {
    AggDir P = blockIdx.y ? D1 : D0;
    int node = blockIdx.x * 16 + (threadIdx.x >> 4);
    int lane = threadIdx.x & 15;           // within quarter-wave
    int qbase = threadIdx.x & 48;          // quarter offset inside the wave
    if (node >= N) return;
    float di = P.d[node];
    int beg = P.rs[node], end = P.rs[node + 1];
    int deg = end - beg;
    float m = -INFINITY, l = 0.f;
    float4 a0 = make_float4(0.f, 0.f, 0.f, 0.f);
    float4 a1 = make_float4(0.f, 0.f, 0.f, 0.f);

    for (int base = 0; base < deg; base += 16) {
        int cnt = min(16, deg - base);
        int sj_l = 0;
        float e_l = -INFINITY;
        if (lane < cnt) {
            sj_l = P.col[beg + base + lane];
            float e = P.s[sj_l] + di;
            e_l = (e >= 0.f) ? e : NEG * e;
        }
        float bm = e_l;
#pragma unroll
        for (int off = 8; off > 0; off >>= 1) bm = fmaxf(bm, __shfl_xor(bm, off));
        float nm = fmaxf(m, bm);
        float p_l = (lane < cnt) ? __expf(e_l - nm) : 0.f;
        float ps = p_l;
#pragma unroll
        for (int off = 8; off > 0; off >>= 1) ps += __shfl_xor(ps, off);
        float sc = (m == -INFINITY) ? 0.f : __expf(m - nm);
        l = l * sc + ps;
        a0.x *= sc; a0.y *= sc; a0.z *= sc; a0.w *= sc;
        a1.x *= sc; a1.y *= sc; a1.z *= sc; a1.w *= sc;
        for (int j0 = 0; j0 < cnt; j0 += 4) {
            int sj[4]; float p[4]; float4 h0[4], h1[4];
#pragma unroll
            for (int u = 0; u < 4; u++) {
                sj[u] = __shfl(sj_l, qbase + j0 + u);
                p[u]  = __shfl(p_l,  qbase + j0 + u);
            }
#pragma unroll
            for (int u = 0; u < 4; u++) {
                if (j0 + u < cnt) {  // uniform per quarter-wave
                    if (BFIN) {
                        uint4 hb = *(const uint4*)&P.hin_bf[(size_t)sj[u] * 64 + 4 * lane];
                        h0[u].x = blo(hb.x); h0[u].y = bhi(hb.x);
                        h0[u].z = blo(hb.y); h0[u].w = bhi(hb.y);
                        h1[u].x = blo(hb.z); h1[u].y = bhi(hb.z);
                        h1[u].z = blo(hb.w); h1[u].w = bhi(hb.w);
                    } else {
                        const float* rp = &P.hin[(size_t)sj[u] * F + 8 * lane];
                        h0[u] = *(const float4*)(rp);
                        h1[u] = *(const float4*)(rp + 4);
                    }
                } else {
                    h0[u] = make_float4(0.f, 0.f, 0.f, 0.f);
                    h1[u] = h0[u];
                }
            }
#pragma unroll
            for (int u = 0; u < 4; u++) {
                a0.x += p[u] * h0[u].x; a0.y += p[u] * h0[u].y;
                a0.z += p[u] * h0[u].z; a0.w += p[u] * h0[u].w;
                a1.x += p[u] * h1[u].x; a1.y += p[u] * h1[u].y;
                a1.z += p[u] * h1[u].z; a1.w += p[u] * h1[u].w;
            }
        }
        m = nm;
    }

    float4 o0, o1;
    if (deg > 0) {
        float inv = 1.f / (l + 1e-16f);
        o0.x = a0.x * inv; o0.y = a0.y * inv; o0.z = a0.z * inv; o0.w = a0.w * inv;
        o1.x = a1.x * inv; o1.y = a1.y * inv; o1.z = a1.z * inv; o1.w = a1.w * inv;
    } else {
        o0 = make_float4(0.f, 0.f, 0.f, 0.f);
        o1 = o0;
    }
    if (BFOUT) {
        uint4 hb;
        hb.x = bpack(o0.x, o0.y); hb.y = bpack(o0.z, o0.w);
        hb.z = bpack(o1.x, o1.y); hb.w = bpack(o1.z, o1.w);
        *(uint4*)&P.hout_bf[(size_t)node * 64 + 4 * lane] = hb;
    } else {
        float* op = &P.hout[(size_t)node * F + 8 * lane];
        *(float4*)(op) = o0;
        *(float4*)(op + 4) = o1;
    }
    if (P.a_s) {
        float4 b0, b1;
        b0 = *(const float4*)&P.a_s[8 * lane];
        b1 = *(const float4*)&P.a_s[8 * lane + 4];
        float vs = o0.x * b0.x + o0.y * b0.y + o0.z * b0.z + o0.w * b0.w
                 + o1.x * b1.x + o1.y * b1.y + o1.z * b1.z + o1.w * b1.w;
        b0 = *(const float4*)&P.a_d[8 * lane];
        b1 = *(const float4*)&P.a_d[8 * lane + 4];
        float vd = o0.x * b0.x + o0.y * b0.y + o0.z * b0.z + o0.w * b0.w
                 + o1.x * b1.x + o1.y * b1.y + o1.z * b1.z + o1.w * b1.w;
#pragma unroll
        for (int off = 8; off > 0; off >>= 1) {
            vs += __shfl_xor(vs, off);
            vd += __shfl_xor(vd, off);
        }
        if (lane == 0) { P.s_out[node] = vs; P.d_out[node] = vd; }
    }
}

// ---------------- fold W blocks -> transposed bf16: WeffT[64][640] ----------------
// concat order k: [0,128)=x, [128,384)=h1f,h2f, [384,640)=h1r,h2r (x blocks folded).
__global__ void wefft_kernel(const float* __restrict__ W, unsigned short* __restrict__ Wt) {
    int i = blockIdx.x * blockDim.x + threadIdx.x;
    if (i >= 64 * 640) return;
    int n = i / 640, k = i % 640;
    float v;
    if (k < 128)      v = W[k * 64 + n] + W[(k + 384) * 64 + n];
    else if (k < 384) v = W[k * 64 + n];
    else              v = W[(k + 128) * 64 + n];
    Wt[(size_t)n * 640 + k] = (unsigned short)(bpack(v, 0.f) & 0xFFFFu);
}

// ---------------- final dense via MFMA: out = Xcat_bf16 @ WeffT^T + b ----------------
// 256 thr = 4 waves; wave computes 16 rows x 64 cols. A/B frags loaded DIRECTLY
// from global (k-contiguous bf16x8, m92-verified layout: A row=lane&15,
// k=(lane>>4)*8; D col=lane&15, row=(lane>>4)*4+reg). No LDS, no barriers.
__global__ __launch_bounds__(256) void gemm_mfma(
    const unsigned* __restrict__ XBF, const unsigned* __restrict__ H1FB,
    const unsigned* __restrict__ H2FB, const unsigned* __restrict__ H1RB,
    const unsigned* __restrict__ H2RB,
    const unsigned short* __restrict__ Wt,  // [64][640] bf16
    const float* __restrict__ bias, float* __restrict__ out, int N) {
    const unsigned* srcs[5] = {XBF, H1FB, H2FB, H1RB, H2RB};
    int wid = threadIdx.x >> 6;
    int lane = threadIdx.x & 63;
    int r = lane & 15;
    int kg = lane >> 4;                  // k-group: k offset kg*8
    int rowBase = blockIdx.x * 64 + wid * 16;
    int arow = rowBase + r;
    f32x4 acc[4];
#pragma unroll
    for (int c = 0; c < 4; c++) acc[c] = (f32x4){0.f, 0.f, 0.f, 0.f};

    for (int t = 0; t < 20; ++t) {
        const unsigned short* xsrc = (const unsigned short*)srcs[t >> 2];
        int kb = (t & 3) * 32 + kg * 8;  // k within the 128-wide panel
        bf16x8 a;
        if (arow < N) a = *(const bf16x8*)(xsrc + (size_t)arow * 128 + kb);
        else          a = (bf16x8){0, 0, 0, 0, 0, 0, 0, 0};
        int kfull = t * 32 + kg * 8;
#pragma unroll
        for (int c = 0; c < 4; c++) {
            bf16x8 b = *(const bf16x8*)(Wt + (size_t)(c * 16 + r) * 640 + kfull);
            acc[c] = __builtin_amdgcn_mfma_f32_16x16x32_bf16(a, b, acc[c], 0, 0, 0);
        }
    }
#pragma unroll
    for (int c = 0; c < 4; c++) {
        int col = c * 16 + r;
        float bv = bias[col];
#pragma unroll
        for (int q = 0; q < 4; q++) {
            int row = rowBase + kg * 4 + q;
            if (row < N) out[(size_t)row * 64 + col] = acc[c][q] + bv;
        }
    }
}

extern "C" void kernel_launch(void* const* d_in, const int* in_sizes, int n_in,
                              void* d_out, int out_size, void* d_ws, size_t ws_size,
                              hipStream_t stream) {
    const float* feature = (const float*)d_in[0];
    const int*   eidx    = (const int*)d_in[1];
    const float* af_s    = (const float*)d_in[2];
    const float* af_d    = (const float*)d_in[3];
    const float* ar_s    = (const float*)d_in[4];
    const float* ar_d    = (const float*)d_in[5];
    const float* W       = (const float*)d_in[6];
    const float* bias    = (const float*)d_in[7];
    float* out = (float*)d_out;
    const int N = in_sizes[0] / F;
    const int E = in_sizes[1] / 2;
    const int* src = eidx;
    const int* dst = eidx + E;

    char* ws = (char*)d_ws;
    size_t off = 0;
    auto alloc = [&](size_t b) { size_t r = off; off = (off + b + 255) & ~(size_t)255; return r; };
    unsigned* xbf  = (unsigned*)(ws + alloc((size_t)N * 64 * 4));
    unsigned* h1fb = (unsigned*)(ws + alloc((size_t)N * 64 * 4));
    unsigned* h1rb = (unsigned*)(ws + alloc((size_t)N * 64 * 4));
    unsigned* h2fb = (unsigned*)(ws + alloc((size_t)N * 64 * 4));
    unsigned* h2rb = (unsigned*)(ws + alloc((size_t)N * 64 * 4));
    int*   rsF   = (int*)(ws + alloc((size_t)(N + 1) * 4));
    int*   rsR   = (int*)(ws + alloc((size_t)(N + 1) * 4));
    int*   colF  = (int*)(ws + alloc((size_t)E * 4));
    int*   colR  = (int*)(ws + alloc((size_t)E * 4));
    int*   ints4 = (int*)(ws + alloc((size_t)4 * N * 4));
    int *degF = ints4, *degR = ints4 + N, *curF = ints4 + 2 * N, *curR = ints4 + 3 * N;
    float* fls8 = (float*)(ws + alloc((size_t)8 * N * 4));
    float *sf = fls8, *df = fls8 + N, *sr = fls8 + 2 * (size_t)N, *dr = fls8 + 3 * (size_t)N;
    float *s2f = fls8 + 4 * (size_t)N, *d2f = fls8 + 5 * (size_t)N;
    float *s2r = fls8 + 6 * (size_t)N, *d2r = fls8 + 7 * (size_t)N;
    int*   bsums = (int*)(ws + alloc(256 * 4));
    unsigned short* WeffT = (unsigned short*)(ws + alloc(64 * 640 * 2));

    const int nb = (N + 1023) / 1024;
    zero_ints<<<(4 * N + 255) / 256, 256, 0, stream>>>(ints4, 4 * N);
    hist_kernel<<<(E + 255) / 256, 256, 0, stream>>>(src, dst, degF, degR, E);
    scan_pass1<<<dim3(nb, 2), 256, 0, stream>>>(degF, degR, rsF, rsR, bsums, N);
    scan_pass2<<<dim3(1, 2), 128, 0, stream>>>(bsums, nb);
    scan_pass3<<<dim3(nb, 2), 256, 0, stream>>>(rsF, rsR, bsums, N);
    scatter_kernel<<<(E + 255) / 256, 256, 0, stream>>>(src, dst, rsF, rsR, curF, curR, colF, colR, E);
    sd4_kernel<<<(N + 3) / 4, 256, 0, stream>>>(feature, af_s, af_d, ar_s, ar_d,
                                                sf, df, sr, dr, xbf, N);

    // hop 1: gather fp32 feature, write bf16 h1 + fused next-hop dots (fp32-exact)
    AggDir F1{feature, nullptr, sf, df, rsF, colF, nullptr, h1fb, af_s, af_d, s2f, d2f};
    AggDir R1{feature, nullptr, sr, dr, rsR, colR, nullptr, h1rb, ar_s, ar_d, s2r, d2r};
    agg_kernel<false, true><<<dim3((N + 15) / 16, 2), 256, 0, stream>>>(F1, R1, N);
    // hop 2: gather bf16 h1, write bf16 h2
    AggDir F2{nullptr, h1fb, s2f, d2f, rsF, colF, nullptr, h2fb, nullptr, nullptr, nullptr, nullptr};
    AggDir R2{nullptr, h1rb, s2r, d2r, rsR, colR, nullptr, h2rb, nullptr, nullptr, nullptr, nullptr};
    agg_kernel<true, true><<<dim3((N + 15) / 16, 2), 256, 0, stream>>>(F2, R2, N);

    wefft_kernel<<<(64 * 640 + 255) / 256, 256, 0, stream>>>(W, WeffT);
    gemm_mfma<<<(N + 63) / 64, 256, 0, stream>>>(xbf, h1fb, h2fb, h1rb, h2rb,
                                                 WeffT, bias, out, N);
}

// Round 12
// 372.568 us; speedup vs baseline: 1.7221x; 1.0777x over previous
//
#include <hip/hip_runtime.h>
#include <math.h>

#define F 128
#define OUTDIM 64
#define NEG 0.2f

typedef __attribute__((ext_vector_type(8))) short bf16x8;
typedef __attribute__((ext_vector_type(4))) float f32x4;

// ---------------- bf16 helpers ----------------
__device__ __forceinline__ float blo(unsigned u) { return __uint_as_float(u << 16); }
__device__ __forceinline__ float bhi(unsigned u) { return __uint_as_float(u & 0xFFFF0000u); }
__device__ __forceinline__ unsigned bpack(float a, float b) {  // rtne both
    unsigned ua = __float_as_uint(a), ub = __float_as_uint(b);
    ua += 0x7FFFu + ((ua >> 16) & 1u);
    ub += 0x7FFFu + ((ub >> 16) & 1u);
    return (ua >> 16) | (ub & 0xFFFF0000u);
}

// ---------------- utility ----------------
__global__ void zero_ints(int* __restrict__ p, int n) {
    int i = blockIdx.x * blockDim.x + threadIdx.x;
    if (i < n) p[i] = 0;
}

// ---------------- CSR build ----------------
__global__ void hist_kernel(const int* __restrict__ src, const int* __restrict__ dst,
                            int* __restrict__ degF, int* __restrict__ degR, int E) {
    int e = blockIdx.x * blockDim.x + threadIdx.x;
    if (e < E) {
        atomicAdd(&degF[dst[e]], 1);
        atomicAdd(&degR[src[e]], 1);
    }
}

__global__ void scan_pass1(const int* __restrict__ degF, const int* __restrict__ degR,
                           int* __restrict__ rsF, int* __restrict__ rsR,
                           int* __restrict__ bsums, int N) {
    const int arr = blockIdx.y;
    const int* deg = arr ? degR : degF;
    int* rs = arr ? rsR : rsF;
    int tid = threadIdx.x;
    int base = blockIdx.x * 1024 + tid * 4;
    int v[4];
#pragma unroll
    for (int i = 0; i < 4; i++) v[i] = (base + i < N) ? deg[base + i] : 0;
    int s1 = v[0] + v[1] + v[2] + v[3];
    __shared__ int sd[256];
    sd[tid] = s1;
    __syncthreads();
    for (int off = 1; off < 256; off <<= 1) {
        int t = (tid >= off) ? sd[tid - off] : 0;
        __syncthreads();
        sd[tid] += t;
        __syncthreads();
    }
    int run = sd[tid] - s1;
#pragma unroll
    for (int i = 0; i < 4; i++) {
        run += v[i];
        if (base + i < N) rs[base + i + 1] = run;
    }
    if (tid == 255) bsums[arr * 128 + blockIdx.x] = sd[255];
    if (tid == 0 && blockIdx.x == 0) rs[0] = 0;
}

__global__ void scan_pass2(int* __restrict__ bsums, int nb) {
    int arr = blockIdx.y;
    int tid = threadIdx.x;  // 128
    __shared__ int sd[128];
    int v = (tid < nb) ? bsums[arr * 128 + tid] : 0;
    sd[tid] = v;
    __syncthreads();
    for (int off = 1; off < 128; off <<= 1) {
        int t = (tid >= off) ? sd[tid - off] : 0;
        __syncthreads();
        sd[tid] += t;
        __syncthreads();
    }
    bsums[arr * 128 + tid] = sd[tid];
}

__global__ void scan_pass3(int* __restrict__ rsF, int* __restrict__ rsR,
                           const int* __restrict__ bsums, int N) {
    int arr = blockIdx.y;
    if (blockIdx.x == 0) return;
    int* rs = arr ? rsR : rsF;
    int off = bsums[arr * 128 + blockIdx.x - 1];
    int base = blockIdx.x * 1024 + threadIdx.x * 4;
#pragma unroll
    for (int i = 0; i < 4; i++)
        if (base + i < N) rs[base + i + 1] += off;
}

__global__ void scatter_kernel(const int* __restrict__ src, const int* __restrict__ dst,
                               const int* __restrict__ rsF, const int* __restrict__ rsR,
                               int* __restrict__ curF, int* __restrict__ curR,
                               int* __restrict__ colF, int* __restrict__ colR, int E) {
    int e = blockIdx.x * blockDim.x + threadIdx.x;
    if (e < E) {
        int s = src[e], d = dst[e];
        int pf = rsF[d] + atomicAdd(&curF[d], 1);
        colF[pf] = s;
        int pr = rsR[s] + atomicAdd(&curR[s], 1);
        colR[pr] = d;
    }
}

// ---------------- per-node attention scalars + bf16 feature copy ----------------
__global__ void sd4_kernel(const float* __restrict__ x,
                           const float* __restrict__ af_s, const float* __restrict__ af_d,
                           const float* __restrict__ ar_s, const float* __restrict__ ar_d,
                           float* __restrict__ sf, float* __restrict__ df,
                           float* __restrict__ sr, float* __restrict__ dr,
                           unsigned* __restrict__ xbf, int N) {
    int node = blockIdx.x * 4 + (threadIdx.x >> 6);
    int lane = threadIdx.x & 63;
    if (node >= N) return;
    const float2 xv = *(const float2*)&x[(size_t)node * F + 2 * lane];
    xbf[(size_t)node * 64 + lane] = bpack(xv.x, xv.y);
    float2 a;
    a = *(const float2*)&af_s[2 * lane]; float vsf = xv.x * a.x + xv.y * a.y;
    a = *(const float2*)&af_d[2 * lane]; float vdf = xv.x * a.x + xv.y * a.y;
    a = *(const float2*)&ar_s[2 * lane]; float vsr = xv.x * a.x + xv.y * a.y;
    a = *(const float2*)&ar_d[2 * lane]; float vdr = xv.x * a.x + xv.y * a.y;
#pragma unroll
    for (int off = 32; off > 0; off >>= 1) {
        vsf += __shfl_xor(vsf, off);
        vdf += __shfl_xor(vdf, off);
        vsr += __shfl_xor(vsr, off);
        vdr += __shfl_xor(vdr, off);
    }
    if (lane == 0) { sf[node] = vsf; df[node] = vdf; sr[node] = vsr; dr[node] = vdr; }
}

// ---------------- fused dual-direction attention hop ----------------
// quarter-wave (16 lanes) per node; blockIdx.y selects direction.
// Both hops gather bf16 rows (256 B/row) -> gather traffic halved vs fp32.
// 4-deep gather pipeline (depth 8 pushed VGPR>128 -> 2 waves/SIMD).
struct AggDir {
    const unsigned* hin_bf;  // [N][64]  bf16x2
    const float* s;          // [N]
    const float* d;          // [N]
    const int* rs;           // [N+1]
    const int* col;          // [E]
    unsigned* hout_bf;       // [N][64]  bf16x2
    const float* a_s;        // nullable: fused next-hop dots
    const float* a_d;
    float* s_out;
    float* d_out;
};

__global__ __launch_bounds__(256) void agg_kernel(AggDir D0, AggDir D1, int N) {
    AggDir P = blockIdx.y ? D1 : D0;
    int node = blockIdx.x * 16 + (threadIdx.x >> 4);
    int lane = threadIdx.x & 15;           // within quarter-wave
    int qbase = threadIdx.x & 48;          // quarter offset inside the wave
    if (node >= N) return;
    float di = P.d[node];
    int beg = P.rs[node], end = P.rs[node + 1];
    int deg = end - beg;
    float m = -INFINITY, l = 0.f;
    float4 a0 = make_float4(0.f, 0.f, 0.f, 0.f);
    float4 a1 = make_float4(0.f, 0.f, 0.f, 0.f);

    for (int base = 0; base < deg; base += 16) {
        int cnt = min(16, deg - base);
        int sj_l = 0;
        float e_l = -INFINITY;
        if (lane < cnt) {
            sj_l = P.col[beg + base + lane];
            float e = P.s[sj_l] + di;
            e_l = (e >= 0.f) ? e : NEG * e;
        }
        float bm = e_l;
#pragma unroll
        for (int off = 8; off > 0; off >>= 1) bm = fmaxf(bm, __shfl_xor(bm, off));
        float nm = fmaxf(m, bm);
        float p_l = (lane < cnt) ? __expf(e_l - nm) : 0.f;
        float ps = p_l;
#pragma unroll
        for (int off = 8; off > 0; off >>= 1) ps += __shfl_xor(ps, off);
        float sc = (m == -INFINITY) ? 0.f : __expf(m - nm);
        l = l * sc + ps;
        a0.x *= sc; a0.y *= sc; a0.z *= sc; a0.w *= sc;
        a1.x *= sc; a1.y *= sc; a1.z *= sc; a1.w *= sc;
        for (int j0 = 0; j0 < cnt; j0 += 4) {
            int sj[4]; float p[4]; float4 h0[4], h1[4];
#pragma unroll
            for (int u = 0; u < 4; u++) {
                sj[u] = __shfl(sj_l, qbase + j0 + u);
                p[u]  = __shfl(p_l,  qbase + j0 + u);
            }
#pragma unroll
            for (int u = 0; u < 4; u++) {
                if (j0 + u < cnt) {  // uniform per quarter-wave
                    uint4 hb = *(const uint4*)&P.hin_bf[(size_t)sj[u] * 64 + 4 * lane];
                    h0[u].x = blo(hb.x); h0[u].y = bhi(hb.x);
                    h0[u].z = blo(hb.y); h0[u].w = bhi(hb.y);
                    h1[u].x = blo(hb.z); h1[u].y = bhi(hb.z);
                    h1[u].z = blo(hb.w); h1[u].w = bhi(hb.w);
                } else {
                    h0[u] = make_float4(0.f, 0.f, 0.f, 0.f);
                    h1[u] = h0[u];
                }
            }
#pragma unroll
            for (int u = 0; u < 4; u++) {
                a0.x += p[u] * h0[u].x; a0.y += p[u] * h0[u].y;
                a0.z += p[u] * h0[u].z; a0.w += p[u] * h0[u].w;
                a1.x += p[u] * h1[u].x; a1.y += p[u] * h1[u].y;
                a1.z += p[u] * h1[u].z; a1.w += p[u] * h1[u].w;
            }
        }
        m = nm;
    }

    float4 o0, o1;
    if (deg > 0) {
        float inv = 1.f / (l + 1e-16f);
        o0.x = a0.x * inv; o0.y = a0.y * inv; o0.z = a0.z * inv; o0.w = a0.w * inv;
        o1.x = a1.x * inv; o1.y = a1.y * inv; o1.z = a1.z * inv; o1.w = a1.w * inv;
    } else {
        o0 = make_float4(0.f, 0.f, 0.f, 0.f);
        o1 = o0;
    }
    uint4 hb;
    hb.x = bpack(o0.x, o0.y); hb.y = bpack(o0.z, o0.w);
    hb.z = bpack(o1.x, o1.y); hb.w = bpack(o1.z, o1.w);
    *(uint4*)&P.hout_bf[(size_t)node * 64 + 4 * lane] = hb;
    if (P.a_s) {
        float4 b0, b1;
        b0 = *(const float4*)&P.a_s[8 * lane];
        b1 = *(const float4*)&P.a_s[8 * lane + 4];
        float vs = o0.x * b0.x + o0.y * b0.y + o0.z * b0.z + o0.w * b0.w
                 + o1.x * b1.x + o1.y * b1.y + o1.z * b1.z + o1.w * b1.w;
        b0 = *(const float4*)&P.a_d[8 * lane];
        b1 = *(const float4*)&P.a_d[8 * lane + 4];
        float vd = o0.x * b0.x + o0.y * b0.y + o0.z * b0.z + o0.w * b0.w
                 + o1.x * b1.x + o1.y * b1.y + o1.z * b1.z + o1.w * b1.w;
#pragma unroll
        for (int off = 8; off > 0; off >>= 1) {
            vs += __shfl_xor(vs, off);
            vd += __shfl_xor(vd, off);
        }
        if (lane == 0) { P.s_out[node] = vs; P.d_out[node] = vd; }
    }
}

// ---------------- fold W blocks -> transposed bf16: WeffT[64][640] ----------------
// concat order k: [0,128)=x, [128,384)=h1f,h2f, [384,640)=h1r,h2r (x blocks folded).
__global__ void wefft_kernel(const float* __restrict__ W, unsigned short* __restrict__ Wt) {
    int i = blockIdx.x * blockDim.x + threadIdx.x;
    if (i >= 64 * 640) return;
    int n = i / 640, k = i % 640;
    float v;
    if (k < 128)      v = W[k * 64 + n] + W[(k + 384) * 64 + n];
    else if (k < 384) v = W[k * 64 + n];
    else              v = W[(k + 128) * 64 + n];
    Wt[(size_t)n * 640 + k] = (unsigned short)(bpack(v, 0.f) & 0xFFFFu);
}

// ---------------- final dense via MFMA: out = Xcat_bf16 @ WeffT^T + b ----------------
// 256 thr = 4 waves; wave computes 16 rows x 64 cols. A/B frags loaded DIRECTLY
// from global (k-contiguous bf16x8). D layout: col=lane&15, row=(lane>>4)*4+reg.
__global__ __launch_bounds__(256) void gemm_mfma(
    const unsigned* __restrict__ XBF, const unsigned* __restrict__ H1FB,
    const unsigned* __restrict__ H2FB, const unsigned* __restrict__ H1RB,
    const unsigned* __restrict__ H2RB,
    const unsigned short* __restrict__ Wt,  // [64][640] bf16
    const float* __restrict__ bias, float* __restrict__ out, int N) {
    const unsigned* srcs[5] = {XBF, H1FB, H2FB, H1RB, H2RB};
    int wid = threadIdx.x >> 6;
    int lane = threadIdx.x & 63;
    int r = lane & 15;
    int kg = lane >> 4;                  // k-group: k offset kg*8
    int rowBase = blockIdx.x * 64 + wid * 16;
    int arow = rowBase + r;
    f32x4 acc[4];
#pragma unroll
    for (int c = 0; c < 4; c++) acc[c] = (f32x4){0.f, 0.f, 0.f, 0.f};

    for (int t = 0; t < 20; ++t) {
        const unsigned short* xsrc = (const unsigned short*)srcs[t >> 2];
        int kb = (t & 3) * 32 + kg * 8;  // k within the 128-wide panel
        bf16x8 a;
        if (arow < N) a = *(const bf16x8*)(xsrc + (size_t)arow * 128 + kb);
        else          a = (bf16x8){0, 0, 0, 0, 0, 0, 0, 0};
        int kfull = t * 32 + kg * 8;
#pragma unroll
        for (int c = 0; c < 4; c++) {
            bf16x8 b = *(const bf16x8*)(Wt + (size_t)(c * 16 + r) * 640 + kfull);
            acc[c] = __builtin_amdgcn_mfma_f32_16x16x32_bf16(a, b, acc[c], 0, 0, 0);
        }
    }
#pragma unroll
    for (int c = 0; c < 4; c++) {
        int col = c * 16 + r;
        float bv = bias[col];
#pragma unroll
        for (int q = 0; q < 4; q++) {
            int row = rowBase + kg * 4 + q;
            if (row < N) out[(size_t)row * 64 + col] = acc[c][q] + bv;
        }
    }
}

extern "C" void kernel_launch(void* const* d_in, const int* in_sizes, int n_in,
                              void* d_out, int out_size, void* d_ws, size_t ws_size,
                              hipStream_t stream) {
    const float* feature = (const float*)d_in[0];
    const int*   eidx    = (const int*)d_in[1];
    const float* af_s    = (const float*)d_in[2];
    const float* af_d    = (const float*)d_in[3];
    const float* ar_s    = (const float*)d_in[4];
    const float* ar_d    = (const float*)d_in[5];
    const float* W       = (const float*)d_in[6];
    const float* bias    = (const float*)d_in[7];
    float* out = (float*)d_out;
    const int N = in_sizes[0] / F;
    const int E = in_sizes[1] / 2;
    const int* src = eidx;
    const int* dst = eidx + E;

    char* ws = (char*)d_ws;
    size_t off = 0;
    auto alloc = [&](size_t b) { size_t r = off; off = (off + b + 255) & ~(size_t)255; return r; };
    unsigned* xbf  = (unsigned*)(ws + alloc((size_t)N * 64 * 4));
    unsigned* h1fb = (unsigned*)(ws + alloc((size_t)N * 64 * 4));
    unsigned* h1rb = (unsigned*)(ws + alloc((size_t)N * 64 * 4));
    unsigned* h2fb = (unsigned*)(ws + alloc((size_t)N * 64 * 4));
    unsigned* h2rb = (unsigned*)(ws + alloc((size_t)N * 64 * 4));
    int*   rsF   = (int*)(ws + alloc((size_t)(N + 1) * 4));
    int*   rsR   = (int*)(ws + alloc((size_t)(N + 1) * 4));
    int*   colF  = (int*)(ws + alloc((size_t)E * 4));
    int*   colR  = (int*)(ws + alloc((size_t)E * 4));
    int*   ints4 = (int*)(ws + alloc((size_t)4 * N * 4));
    int *degF = ints4, *degR = ints4 + N, *curF = ints4 + 2 * N, *curR = ints4 + 3 * N;
    float* fls8 = (float*)(ws + alloc((size_t)8 * N * 4));
    float *sf = fls8, *df = fls8 + N, *sr = fls8 + 2 * (size_t)N, *dr = fls8 + 3 * (size_t)N;
    float *s2f = fls8 + 4 * (size_t)N, *d2f = fls8 + 5 * (size_t)N;
    float *s2r = fls8 + 6 * (size_t)N, *d2r = fls8 + 7 * (size_t)N;
    int*   bsums = (int*)(ws + alloc(256 * 4));
    unsigned short* WeffT = (unsigned short*)(ws + alloc(64 * 640 * 2));

    const int nb = (N + 1023) / 1024;
    zero_ints<<<(4 * N + 255) / 256, 256, 0, stream>>>(ints4, 4 * N);
    hist_kernel<<<(E + 255) / 256, 256, 0, stream>>>(src, dst, degF, degR, E);
    scan_pass1<<<dim3(nb, 2), 256, 0, stream>>>(degF, degR, rsF, rsR, bsums, N);
    scan_pass2<<<dim3(1, 2), 128, 0, stream>>>(bsums, nb);
    scan_pass3<<<dim3(nb, 2), 256, 0, stream>>>(rsF, rsR, bsums, N);
    scatter_kernel<<<(E + 255) / 256, 256, 0, stream>>>(src, dst, rsF, rsR, curF, curR, colF, colR, E);
    sd4_kernel<<<(N + 3) / 4, 256, 0, stream>>>(feature, af_s, af_d, ar_s, ar_d,
                                                sf, df, sr, dr, xbf, N);

    // hop 1: gather bf16 feature (xbf), write bf16 h1 + fused next-hop dots
    AggDir F1{xbf, sf, df, rsF, colF, h1fb, af_s, af_d, s2f, d2f};
    AggDir R1{xbf, sr, dr, rsR, colR, h1rb, ar_s, ar_d, s2r, d2r};
    agg_kernel<<<dim3((N + 15) / 16, 2), 256, 0, stream>>>(F1, R1, N);
    // hop 2: gather bf16 h1, write bf16 h2
    AggDir F2{h1fb, s2f, d2f, rsF, colF, h2fb, nullptr, nullptr, nullptr, nullptr};
    AggDir R2{h1rb, s2r, d2r, rsR, colR, h2rb, nullptr, nullptr, nullptr, nullptr};
    agg_kernel<<<dim3((N + 15) / 16, 2), 256, 0, stream>>>(F2, R2, N);

    wefft_kernel<<<(64 * 640 + 255) / 256, 256, 0, stream>>>(W, WeffT);
    gemm_mfma<<<(N + 63) / 64, 256, 0, stream>>>(xbf, h1fb, h2fb, h1rb, h2rb,
                                                 WeffT, bias, out, N);
}

// Round 14
// 315.370 us; speedup vs baseline: 2.0344x; 1.1814x over previous
//
#include <hip/hip_runtime.h>
#include <math.h>

#define F 128
#define OUTDIM 64
#define NEG 0.2f

typedef __attribute__((ext_vector_type(8))) short bf16x8;
typedef __attribute__((ext_vector_type(4))) float f32x4;

// ---------------- bf16 helpers ----------------
__device__ __forceinline__ float blo(unsigned u) { return __uint_as_float(u << 16); }
__device__ __forceinline__ float bhi(unsigned u) { return __uint_as_float(u & 0xFFFF0000u); }
__device__ __forceinline__ unsigned bpack(float a, float b) {  // rtne both
    unsigned ua = __float_as_uint(a), ub = __float_as_uint(b);
    ua += 0x7FFFu + ((ua >> 16) & 1u);
    ub += 0x7FFFu + ((ub >> 16) & 1u);
    return (ua >> 16) | (ub & 0xFFFF0000u);
}

// ---------------- utility ----------------
__global__ void zero_ints(int* __restrict__ p, int n) {
    int i = blockIdx.x * blockDim.x + threadIdx.x;
    if (i < n) p[i] = 0;
}

// ---------------- CSR build ----------------
// hist also records each edge's arrival rank (atomicAdd return) so the
// scatter pass needs NO atomics (R12: scatter was 94us, VALUBusy 0.3% --
// stalled on 1.2M returning device-atomics + dependent random stores).
__global__ void hist_kernel(const int* __restrict__ src, const int* __restrict__ dst,
                            int* __restrict__ degF, int* __restrict__ degR,
                            int* __restrict__ rankF, int* __restrict__ rankR, int E) {
    int e = blockIdx.x * blockDim.x + threadIdx.x;
    if (e < E) {
        rankF[e] = atomicAdd(&degF[dst[e]], 1);
        rankR[e] = atomicAdd(&degR[src[e]], 1);
    }
}

__global__ void scan_pass1(const int* __restrict__ degF, const int* __restrict__ degR,
                           int* __restrict__ rsF, int* __restrict__ rsR,
                           int* __restrict__ bsums, int N) {
    const int arr = blockIdx.y;
    const int* deg = arr ? degR : degF;
    int* rs = arr ? rsR : rsF;
    int tid = threadIdx.x;
    int base = blockIdx.x * 1024 + tid * 4;
    int v[4];
#pragma unroll
    for (int i = 0; i < 4; i++) v[i] = (base + i < N) ? deg[base + i] : 0;
    int s1 = v[0] + v[1] + v[2] + v[3];
    __shared__ int sd[256];
    sd[tid] = s1;
    __syncthreads();
    for (int off = 1; off < 256; off <<= 1) {
        int t = (tid >= off) ? sd[tid - off] : 0;
        __syncthreads();
        sd[tid] += t;
        __syncthreads();
    }
    int run = sd[tid] - s1;
#pragma unroll
    for (int i = 0; i < 4; i++) {
        run += v[i];
        if (base + i < N) rs[base + i + 1] = run;
    }
    if (tid == 255) bsums[arr * 128 + blockIdx.x] = sd[255];
    if (tid == 0 && blockIdx.x == 0) rs[0] = 0;
}

__global__ void scan_pass2(int* __restrict__ bsums, int nb) {
    int arr = blockIdx.y;
    int tid = threadIdx.x;  // 128
    __shared__ int sd[128];
    int v = (tid < nb) ? bsums[arr * 128 + tid] : 0;
    sd[tid] = v;
    __syncthreads();
    for (int off = 1; off < 128; off <<= 1) {
        int t = (tid >= off) ? sd[tid - off] : 0;
        __syncthreads();
        sd[tid] += t;
        __syncthreads();
    }
    bsums[arr * 128 + tid] = sd[tid];
}

__global__ void scan_pass3(int* __restrict__ rsF, int* __restrict__ rsR,
                           const int* __restrict__ bsums, int N) {
    int arr = blockIdx.y;
    if (blockIdx.x == 0) return;
    int* rs = arr ? rsR : rsF;
    int off = bsums[arr * 128 + blockIdx.x - 1];
    int base = blockIdx.x * 1024 + threadIdx.x * 4;
#pragma unroll
    for (int i = 0; i < 4; i++)
        if (base + i < N) rs[base + i + 1] += off;
}

// atomic-free: position = rs[node] + precomputed rank
__global__ void scatter_kernel(const int* __restrict__ src, const int* __restrict__ dst,
                               const int* __restrict__ rsF, const int* __restrict__ rsR,
                               const int* __restrict__ rankF, const int* __restrict__ rankR,
                               int* __restrict__ colF, int* __restrict__ colR, int E) {
    int e = blockIdx.x * blockDim.x + threadIdx.x;
    if (e < E) {
        int s = src[e], d = dst[e];
        colF[rsF[d] + rankF[e]] = s;
        colR[rsR[s] + rankR[e]] = d;
    }
}

// ---------------- per-node attention scalars + bf16 feature copy ----------------
__global__ void sd4_kernel(const float* __restrict__ x,
                           const float* __restrict__ af_s, const float* __restrict__ af_d,
                           const float* __restrict__ ar_s, const float* __restrict__ ar_d,
                           float* __restrict__ sf, float* __restrict__ df,
                           float* __restrict__ sr, float* __restrict__ dr,
                           unsigned* __restrict__ xbf, int N) {
    int node = blockIdx.x * 4 + (threadIdx.x >> 6);
    int lane = threadIdx.x & 63;
    if (node >= N) return;
    const float2 xv = *(const float2*)&x[(size_t)node * F + 2 * lane];
    xbf[(size_t)node * 64 + lane] = bpack(xv.x, xv.y);
    float2 a;
    a = *(const float2*)&af_s[2 * lane]; float vsf = xv.x * a.x + xv.y * a.y;
    a = *(const float2*)&af_d[2 * lane]; float vdf = xv.x * a.x + xv.y * a.y;
    a = *(const float2*)&ar_s[2 * lane]; float vsr = xv.x * a.x + xv.y * a.y;
    a = *(const float2*)&ar_d[2 * lane]; float vdr = xv.x * a.x + xv.y * a.y;
#pragma unroll
    for (int off = 32; off > 0; off >>= 1) {
        vsf += __shfl_xor(vsf, off);
        vdf += __shfl_xor(vdf, off);
        vsr += __shfl_xor(vsr, off);
        vdr += __shfl_xor(vdr, off);
    }
    if (lane == 0) { sf[node] = vsf; df[node] = vdf; sr[node] = vsr; dr[node] = vdr; }
}

// ---------------- fused dual-direction attention hop ----------------
// quarter-wave (16 lanes) per node; blockIdx.y selects direction.
// Both hops gather bf16 rows (256 B/row). 4-deep gather pipeline.
struct AggDir {
    const unsigned* hin_bf;  // [N][64]  bf16x2
    const float* s;          // [N]
    const float* d;          // [N]
    const int* rs;           // [N+1]
    const int* col;          // [E]
    unsigned* hout_bf;       // [N][64]  bf16x2
    const float* a_s;        // nullable: fused next-hop dots
    const float* a_d;
    float* s_out;
    float* d_out;
};

__global__ __launch_bounds__(256) void agg_kernel(AggDir D0, AggDir D1, int N) {
    AggDir P = blockIdx.y ? D1 : D0;
    int node = blockIdx.x * 16 + (threadIdx.x >> 4);
    int lane = threadIdx.x & 15;           // within quarter-wave
    int qbase = threadIdx.x & 48;          // quarter offset inside the wave
    if (node >= N) return;
    float di = P.d[node];
    int beg = P.rs[node], end = P.rs[node + 1];
    int deg = end - beg;
    float m = -INFINITY, l = 0.f;
    float4 a0 = make_float4(0.f, 0.f, 0.f, 0.f);
    float4 a1 = make_float4(0.f, 0.f, 0.f, 0.f);

    for (int base = 0; base < deg; base += 16) {
        int cnt = min(16, deg - base);
        int sj_l = 0;
        float e_l = -INFINITY;
        if (lane < cnt) {
            sj_l = P.col[beg + base + lane];
            float e = P.s[sj_l] + di;
            e_l = (e >= 0.f) ? e : NEG * e;
        }
        float bm = e_l;
#pragma unroll
        for (int off = 8; off > 0; off >>= 1) bm = fmaxf(bm, __shfl_xor(bm, off));
        float nm = fmaxf(m, bm);
        float p_l = (lane < cnt) ? __expf(e_l - nm) : 0.f;
        float ps = p_l;
#pragma unroll
        for (int off = 8; off > 0; off >>= 1) ps += __shfl_xor(ps, off);
        float sc = (m == -INFINITY) ? 0.f : __expf(m - nm);
        l = l * sc + ps;
        a0.x *= sc; a0.y *= sc; a0.z *= sc; a0.w *= sc;
        a1.x *= sc; a1.y *= sc; a1.z *= sc; a1.w *= sc;
        for (int j0 = 0; j0 < cnt; j0 += 4) {
            int sj[4]; float p[4]; float4 h0[4], h1[4];
#pragma unroll
            for (int u = 0; u < 4; u++) {
                sj[u] = __shfl(sj_l, qbase + j0 + u);
                p[u]  = __shfl(p_l,  qbase + j0 + u);
            }
#pragma unroll
            for (int u = 0; u < 4; u++) {
                if (j0 + u < cnt) {  // uniform per quarter-wave
                    uint4 hb = *(const uint4*)&P.hin_bf[(size_t)sj[u] * 64 + 4 * lane];
                    h0[u].x = blo(hb.x); h0[u].y = bhi(hb.x);
                    h0[u].z = blo(hb.y); h0[u].w = bhi(hb.y);
                    h1[u].x = blo(hb.z); h1[u].y = bhi(hb.z);
                    h1[u].z = blo(hb.w); h1[u].w = bhi(hb.w);
                } else {
                    h0[u] = make_float4(0.f, 0.f, 0.f, 0.f);
                    h1[u] = h0[u];
                }
            }
#pragma unroll
            for (int u = 0; u < 4; u++) {
                a0.x += p[u] * h0[u].x; a0.y += p[u] * h0[u].y;
                a0.z += p[u] * h0[u].z; a0.w += p[u] * h0[u].w;
                a1.x += p[u] * h1[u].x; a1.y += p[u] * h1[u].y;
                a1.z += p[u] * h1[u].z; a1.w += p[u] * h1[u].w;
            }
        }
        m = nm;
    }

    float4 o0, o1;
    if (deg > 0) {
        float inv = 1.f / (l + 1e-16f);
        o0.x = a0.x * inv; o0.y = a0.y * inv; o0.z = a0.z * inv; o0.w = a0.w * inv;
        o1.x = a1.x * inv; o1.y = a1.y * inv; o1.z = a1.z * inv; o1.w = a1.w * inv;
    } else {
        o0 = make_float4(0.f, 0.f, 0.f, 0.f);
        o1 = o0;
    }
    uint4 hb;
    hb.x = bpack(o0.x, o0.y); hb.y = bpack(o0.z, o0.w);
    hb.z = bpack(o1.x, o1.y); hb.w = bpack(o1.z, o1.w);
    *(uint4*)&P.hout_bf[(size_t)node * 64 + 4 * lane] = hb;
    if (P.a_s) {
        float4 b0, b1;
        b0 = *(const float4*)&P.a_s[8 * lane];
        b1 = *(const float4*)&P.a_s[8 * lane + 4];
        float vs = o0.x * b0.x + o0.y * b0.y + o0.z * b0.z + o0.w * b0.w
                 + o1.x * b1.x + o1.y * b1.y + o1.z * b1.z + o1.w * b1.w;
        b0 = *(const float4*)&P.a_d[8 * lane];
        b1 = *(const float4*)&P.a_d[8 * lane + 4];
        float vd = o0.x * b0.x + o0.y * b0.y + o0.z * b0.z + o0.w * b0.w
                 + o1.x * b1.x + o1.y * b1.y + o1.z * b1.z + o1.w * b1.w;
#pragma unroll
        for (int off = 8; off > 0; off >>= 1) {
            vs += __shfl_xor(vs, off);
            vd += __shfl_xor(vd, off);
        }
        if (lane == 0) { P.s_out[node] = vs; P.d_out[node] = vd; }
    }
}

// ---------------- fold W blocks -> transposed bf16: WeffT[64][640] ----------------
__global__ void wefft_kernel(const float* __restrict__ W, unsigned short* __restrict__ Wt) {
    int i = blockIdx.x * blockDim.x + threadIdx.x;
    if (i >= 64 * 640) return;
    int n = i / 640, k = i % 640;
    float v;
    if (k < 128)      v = W[k * 64 + n] + W[(k + 384) * 64 + n];
    else if (k < 384) v = W[k * 64 + n];
    else              v = W[(k + 128) * 64 + n];
    Wt[(size_t)n * 640 + k] = (unsigned short)(bpack(v, 0.f) & 0xFFFFu);
}

// ---------------- final dense via MFMA: out = Xcat_bf16 @ WeffT^T + b ----------------
__global__ __launch_bounds__(256) void gemm_mfma(
    const unsigned* __restrict__ XBF, const unsigned* __restrict__ H1FB,
    const unsigned* __restrict__ H2FB, const unsigned* __restrict__ H1RB,
    const unsigned* __restrict__ H2RB,
    const unsigned short* __restrict__ Wt,  // [64][640] bf16
    const float* __restrict__ bias, float* __restrict__ out, int N) {
    const unsigned* srcs[5] = {XBF, H1FB, H2FB, H1RB, H2RB};
    int wid = threadIdx.x >> 6;
    int lane = threadIdx.x & 63;
    int r = lane & 15;
    int kg = lane >> 4;                  // k-group: k offset kg*8
    int rowBase = blockIdx.x * 64 + wid * 16;
    int arow = rowBase + r;
    f32x4 acc[4];
#pragma unroll
    for (int c = 0; c < 4; c++) acc[c] = (f32x4){0.f, 0.f, 0.f, 0.f};

    for (int t = 0; t < 20; ++t) {
        const unsigned short* xsrc = (const unsigned short*)srcs[t >> 2];
        int kb = (t & 3) * 32 + kg * 8;  // k within the 128-wide panel
        bf16x8 a;
        if (arow < N) a = *(const bf16x8*)(xsrc + (size_t)arow * 128 + kb);
        else          a = (bf16x8){0, 0, 0, 0, 0, 0, 0, 0};
        int kfull = t * 32 + kg * 8;
#pragma unroll
        for (int c = 0; c < 4; c++) {
            bf16x8 b = *(const bf16x8*)(Wt + (size_t)(c * 16 + r) * 640 + kfull);
            acc[c] = __builtin_amdgcn_mfma_f32_16x16x32_bf16(a, b, acc[c], 0, 0, 0);
        }
    }
#pragma unroll
    for (int c = 0; c < 4; c++) {
        int col = c * 16 + r;
        float bv = bias[col];
#pragma unroll
        for (int q = 0; q < 4; q++) {
            int row = rowBase + kg * 4 + q;
            if (row < N) out[(size_t)row * 64 + col] = acc[c][q] + bv;
        }
    }
}

extern "C" void kernel_launch(void* const* d_in, const int* in_sizes, int n_in,
                              void* d_out, int out_size, void* d_ws, size_t ws_size,
                              hipStream_t stream) {
    const float* feature = (const float*)d_in[0];
    const int*   eidx    = (const int*)d_in[1];
    const float* af_s    = (const float*)d_in[2];
    const float* af_d    = (const float*)d_in[3];
    const float* ar_s    = (const float*)d_in[4];
    const float* ar_d    = (const float*)d_in[5];
    const float* W       = (const float*)d_in[6];
    const float* bias    = (const float*)d_in[7];
    float* out = (float*)d_out;
    const int N = in_sizes[0] / F;
    const int E = in_sizes[1] / 2;
    const int* src = eidx;
    const int* dst = eidx + E;

    char* ws = (char*)d_ws;
    size_t off = 0;
    auto alloc = [&](size_t b) { size_t r = off; off = (off + b + 255) & ~(size_t)255; return r; };
    unsigned* xbf  = (unsigned*)(ws + alloc((size_t)N * 64 * 4));
    unsigned* h1fb = (unsigned*)(ws + alloc((size_t)N * 64 * 4));
    unsigned* h1rb = (unsigned*)(ws + alloc((size_t)N * 64 * 4));
    unsigned* h2fb = (unsigned*)(ws + alloc((size_t)N * 64 * 4));
    unsigned* h2rb = (unsigned*)(ws + alloc((size_t)N * 64 * 4));
    int*   rsF   = (int*)(ws + alloc((size_t)(N + 1) * 4));
    int*   rsR   = (int*)(ws + alloc((size_t)(N + 1) * 4));
    int*   colF  = (int*)(ws + alloc((size_t)E * 4));
    int*   colR  = (int*)(ws + alloc((size_t)E * 4));
    int*   rankF = (int*)(ws + alloc((size_t)E * 4));
    int*   rankR = (int*)(ws + alloc((size_t)E * 4));
    int*   ints2 = (int*)(ws + alloc((size_t)2 * N * 4));
    int *degF = ints2, *degR = ints2 + N;
    float* fls8 = (float*)(ws + alloc((size_t)8 * N * 4));
    float *sf = fls8, *df = fls8 + N, *sr = fls8 + 2 * (size_t)N, *dr = fls8 + 3 * (size_t)N;
    float *s2f = fls8 + 4 * (size_t)N, *d2f = fls8 + 5 * (size_t)N;
    float *s2r = fls8 + 6 * (size_t)N, *d2r = fls8 + 7 * (size_t)N;
    int*   bsums = (int*)(ws + alloc(256 * 4));
    unsigned short* WeffT = (unsigned short*)(ws + alloc(64 * 640 * 2));

    const int nb = (N + 1023) / 1024;
    zero_ints<<<(2 * N + 255) / 256, 256, 0, stream>>>(ints2, 2 * N);
    hist_kernel<<<(E + 255) / 256, 256, 0, stream>>>(src, dst, degF, degR, rankF, rankR, E);
    scan_pass1<<<dim3(nb, 2), 256, 0, stream>>>(degF, degR, rsF, rsR, bsums, N);
    scan_pass2<<<dim3(1, 2), 128, 0, stream>>>(bsums, nb);
    scan_pass3<<<dim3(nb, 2), 256, 0, stream>>>(rsF, rsR, bsums, N);
    scatter_kernel<<<(E + 255) / 256, 256, 0, stream>>>(src, dst, rsF, rsR, rankF, rankR,
                                                        colF, colR, E);
    sd4_kernel<<<(N + 3) / 4, 256, 0, stream>>>(feature, af_s, af_d, ar_s, ar_d,
                                                sf, df, sr, dr, xbf, N);

    // hop 1: gather bf16 feature (xbf), write bf16 h1 + fused next-hop dots
    AggDir F1{xbf, sf, df, rsF, colF, h1fb, af_s, af_d, s2f, d2f};
    AggDir R1{xbf, sr, dr, rsR, colR, h1rb, ar_s, ar_d, s2r, d2r};
    agg_kernel<<<dim3((N + 15) / 16, 2), 256, 0, stream>>>(F1, R1, N);
    // hop 2: gather bf16 h1, write bf16 h2
    AggDir F2{h1fb, s2f, d2f, rsF, colF, h2fb, nullptr, nullptr, nullptr, nullptr};
    AggDir R2{h1rb, s2r, d2r, rsR, colR, h2rb, nullptr, nullptr, nullptr, nullptr};
    agg_kernel<<<dim3((N + 15) / 16, 2), 256, 0, stream>>>(F2, R2, N);

    wefft_kernel<<<(64 * 640 + 255) / 256, 256, 0, stream>>>(W, WeffT);
    gemm_mfma<<<(N + 63) / 64, 256, 0, stream>>>(xbf, h1fb, h2fb, h1rb, h2rb,
                                                 WeffT, bias, out, N);
}

// Round 16
// 294.061 us; speedup vs baseline: 2.1818x; 1.0725x over previous
//
#include <hip/hip_runtime.h>
#include <math.h>

#define F 128
#define OUTDIM 64
#define NEG 0.2f

typedef __attribute__((ext_vector_type(8))) short bf16x8;
typedef __attribute__((ext_vector_type(4))) float f32x4;

// ---------------- bf16 helpers ----------------
__device__ __forceinline__ float blo(unsigned u) { return __uint_as_float(u << 16); }
__device__ __forceinline__ float bhi(unsigned u) { return __uint_as_float(u & 0xFFFF0000u); }
__device__ __forceinline__ unsigned bpack(float a, float b) {  // rtne both
    unsigned ua = __float_as_uint(a), ub = __float_as_uint(b);
    ua += 0x7FFFu + ((ua >> 16) & 1u);
    ub += 0x7FFFu + ((ub >> 16) & 1u);
    return (ua >> 16) | (ub & 0xFFFF0000u);
}

// ---------------- utility ----------------
__global__ void zero_ints(int* __restrict__ p, int n) {
    int i = blockIdx.x * blockDim.x + threadIdx.x;
    if (i < n) p[i] = 0;
}

// ---------------- CSR build ----------------
// hist records each edge's arrival rank (atomicAdd return) so scatter needs NO atomics.
__global__ void hist_kernel(const int* __restrict__ src, const int* __restrict__ dst,
                            int* __restrict__ degF, int* __restrict__ degR,
                            int* __restrict__ rankF, int* __restrict__ rankR, int E) {
    int e = blockIdx.x * blockDim.x + threadIdx.x;
    if (e < E) {
        rankF[e] = atomicAdd(&degF[dst[e]], 1);
        rankR[e] = atomicAdd(&degR[src[e]], 1);
    }
}

__global__ void scan_pass1(const int* __restrict__ degF, const int* __restrict__ degR,
                           int* __restrict__ rsF, int* __restrict__ rsR,
                           int* __restrict__ bsums, int N) {
    const int arr = blockIdx.y;
    const int* deg = arr ? degR : degF;
    int* rs = arr ? rsR : rsF;
    int tid = threadIdx.x;
    int base = blockIdx.x * 1024 + tid * 4;
    int v[4];
#pragma unroll
    for (int i = 0; i < 4; i++) v[i] = (base + i < N) ? deg[base + i] : 0;
    int s1 = v[0] + v[1] + v[2] + v[3];
    __shared__ int sd[256];
    sd[tid] = s1;
    __syncthreads();
    for (int off = 1; off < 256; off <<= 1) {
        int t = (tid >= off) ? sd[tid - off] : 0;
        __syncthreads();
        sd[tid] += t;
        __syncthreads();
    }
    int run = sd[tid] - s1;
#pragma unroll
    for (int i = 0; i < 4; i++) {
        run += v[i];
        if (base + i < N) rs[base + i + 1] = run;
    }
    if (tid == 255) bsums[arr * 128 + blockIdx.x] = sd[255];
    if (tid == 0 && blockIdx.x == 0) rs[0] = 0;
}

__global__ void scan_pass2(int* __restrict__ bsums, int nb) {
    int arr = blockIdx.y;
    int tid = threadIdx.x;  // 128
    __shared__ int sd[128];
    int v = (tid < nb) ? bsums[arr * 128 + tid] : 0;
    sd[tid] = v;
    __syncthreads();
    for (int off = 1; off < 128; off <<= 1) {
        int t = (tid >= off) ? sd[tid - off] : 0;
        __syncthreads();
        sd[tid] += t;
        __syncthreads();
    }
    bsums[arr * 128 + tid] = sd[tid];
}

__global__ void scan_pass3(int* __restrict__ rsF, int* __restrict__ rsR,
                           const int* __restrict__ bsums, int N) {
    int arr = blockIdx.y;
    if (blockIdx.x == 0) return;
    int* rs = arr ? rsR : rsF;
    int off = bsums[arr * 128 + blockIdx.x - 1];
    int base = blockIdx.x * 1024 + threadIdx.x * 4;
#pragma unroll
    for (int i = 0; i < 4; i++)
        if (base + i < N) rs[base + i + 1] += off;
}

// atomic-free: position = rs[node] + precomputed rank
__global__ void scatter_kernel(const int* __restrict__ src, const int* __restrict__ dst,
                               const int* __restrict__ rsF, const int* __restrict__ rsR,
                               const int* __restrict__ rankF, const int* __restrict__ rankR,
                               int* __restrict__ colF, int* __restrict__ colR, int E) {
    int e = blockIdx.x * blockDim.x + threadIdx.x;
    if (e < E) {
        int s = src[e], d = dst[e];
        colF[rsF[d] + rankF[e]] = s;
        colR[rsR[s] + rankR[e]] = d;
    }
}

// ---------------- per-node attention scalars + bf16 feature copy ----------------
__global__ void sd4_kernel(const float* __restrict__ x,
                           const float* __restrict__ af_s, const float* __restrict__ af_d,
                           const float* __restrict__ ar_s, const float* __restrict__ ar_d,
                           float* __restrict__ sf, float* __restrict__ df,
                           float* __restrict__ sr, float* __restrict__ dr,
                           unsigned* __restrict__ xbf, int N) {
    int node = blockIdx.x * 4 + (threadIdx.x >> 6);
    int lane = threadIdx.x & 63;
    if (node >= N) return;
    const float2 xv = *(const float2*)&x[(size_t)node * F + 2 * lane];
    xbf[(size_t)node * 64 + lane] = bpack(xv.x, xv.y);
    float2 a;
    a = *(const float2*)&af_s[2 * lane]; float vsf = xv.x * a.x + xv.y * a.y;
    a = *(const float2*)&af_d[2 * lane]; float vdf = xv.x * a.x + xv.y * a.y;
    a = *(const float2*)&ar_s[2 * lane]; float vsr = xv.x * a.x + xv.y * a.y;
    a = *(const float2*)&ar_d[2 * lane]; float vdr = xv.x * a.x + xv.y * a.y;
#pragma unroll
    for (int off = 32; off > 0; off >>= 1) {
        vsf += __shfl_xor(vsf, off);
        vdf += __shfl_xor(vdf, off);
        vsr += __shfl_xor(vsr, off);
        vdr += __shfl_xor(vdr, off);
    }
    if (lane == 0) { sf[node] = vsf; df[node] = vdf; sr[node] = vsr; dr[node] = vdr; }
}

// ---------------- fused dual-direction attention hop ----------------
// quarter-wave (16 lanes) per node; blockIdx.y selects direction.
// Both hops gather bf16 rows (256 B/row). 4-deep gather pipeline.
struct AggDir {
    const unsigned* hin_bf;  // [N][64]  bf16x2
    const float* s;          // [N]
    const float* d;          // [N]
    const int* rs;           // [N+1]
    const int* col;          // [E]
    unsigned* hout_bf;       // [N][64]  bf16x2
    const float* a_s;        // nullable: fused next-hop dots
    const float* a_d;
    float* s_out;
    float* d_out;
};

__global__ __launch_bounds__(256) void agg_kernel(AggDir D0, AggDir D1, int N) {
    AggDir P = blockIdx.y ? D1 : D0;
    int node = blockIdx.x * 16 + (threadIdx.x >> 4);
    int lane = threadIdx.x & 15;           // within quarter-wave
    int qbase = threadIdx.x & 48;          // quarter offset inside the wave
    if (node >= N) return;
    float di = P.d[node];
    int beg = P.rs[node], end = P.rs[node + 1];
    int deg = end - beg;
    float m = -INFINITY, l = 0.f;
    float4 a0 = make_float4(0.f, 0.f, 0.f, 0.f);
    float4 a1 = make_float4(0.f, 0.f, 0.f, 0.f);

    for (int base = 0; base < deg; base += 16) {
        int cnt = min(16, deg - base);
        int sj_l = 0;
        float e_l = -INFINITY;
        if (lane < cnt) {
            sj_l = P.col[beg + base + lane];
            float e = P.s[sj_l] + di;
            e_l = (e >= 0.f) ? e : NEG * e;
        }
        float bm = e_l;
#pragma unroll
        for (int off = 8; off > 0; off >>= 1) bm = fmaxf(bm, __shfl_xor(bm, off));
        float nm = fmaxf(m, bm);
        float p_l = (lane < cnt) ? __expf(e_l - nm) : 0.f;
        float ps = p_l;
#pragma unroll
        for (int off = 8; off > 0; off >>= 1) ps += __shfl_xor(ps, off);
        float sc = (m == -INFINITY) ? 0.f : __expf(m - nm);
        l = l * sc + ps;
        a0.x *= sc; a0.y *= sc; a0.z *= sc; a0.w *= sc;
        a1.x *= sc; a1.y *= sc; a1.z *= sc; a1.w *= sc;
        for (int j0 = 0; j0 < cnt; j0 += 4) {
            int sj[4]; float p[4]; float4 h0[4], h1[4];
#pragma unroll
            for (int u = 0; u < 4; u++) {
                sj[u] = __shfl(sj_l, qbase + j0 + u);
                p[u]  = __shfl(p_l,  qbase + j0 + u);
            }
#pragma unroll
            for (int u = 0; u < 4; u++) {
                if (j0 + u < cnt) {  // uniform per quarter-wave
                    uint4 hb = *(const uint4*)&P.hin_bf[(size_t)sj[u] * 64 + 4 * lane];
                    h0[u].x = blo(hb.x); h0[u].y = bhi(hb.x);
                    h0[u].z = blo(hb.y); h0[u].w = bhi(hb.y);
                    h1[u].x = blo(hb.z); h1[u].y = bhi(hb.z);
                    h1[u].z = blo(hb.w); h1[u].w = bhi(hb.w);
                } else {
                    h0[u] = make_float4(0.f, 0.f, 0.f, 0.f);
                    h1[u] = h0[u];
                }
            }
#pragma unroll
            for (int u = 0; u < 4; u++) {
                a0.x += p[u] * h0[u].x; a0.y += p[u] * h0[u].y;
                a0.z += p[u] * h0[u].z; a0.w += p[u] * h0[u].w;
                a1.x += p[u] * h1[u].x; a1.y += p[u] * h1[u].y;
                a1.z += p[u] * h1[u].z; a1.w += p[u] * h1[u].w;
            }
        }
        m = nm;
    }

    float4 o0, o1;
    if (deg > 0) {
        float inv = 1.f / (l + 1e-16f);
        o0.x = a0.x * inv; o0.y = a0.y * inv; o0.z = a0.z * inv; o0.w = a0.w * inv;
        o1.x = a1.x * inv; o1.y = a1.y * inv; o1.z = a1.z * inv; o1.w = a1.w * inv;
    } else {
        o0 = make_float4(0.f, 0.f, 0.f, 0.f);
        o1 = o0;
    }
    uint4 hb;
    hb.x = bpack(o0.x, o0.y); hb.y = bpack(o0.z, o0.w);
    hb.z = bpack(o1.x, o1.y); hb.w = bpack(o1.z, o1.w);
    *(uint4*)&P.hout_bf[(size_t)node * 64 + 4 * lane] = hb;
    if (P.a_s) {
        float4 b0, b1;
        b0 = *(const float4*)&P.a_s[8 * lane];
        b1 = *(const float4*)&P.a_s[8 * lane + 4];
        float vs = o0.x * b0.x + o0.y * b0.y + o0.z * b0.z + o0.w * b0.w
                 + o1.x * b1.x + o1.y * b1.y + o1.z * b1.z + o1.w * b1.w;
        b0 = *(const float4*)&P.a_d[8 * lane];
        b1 = *(const float4*)&P.a_d[8 * lane + 4];
        float vd = o0.x * b0.x + o0.y * b0.y + o0.z * b0.z + o0.w * b0.w
                 + o1.x * b1.x + o1.y * b1.y + o1.z * b1.z + o1.w * b1.w;
#pragma unroll
        for (int off = 8; off > 0; off >>= 1) {
            vs += __shfl_xor(vs, off);
            vd += __shfl_xor(vd, off);
        }
        if (lane == 0) { P.s_out[node] = vs; P.d_out[node] = vd; }
    }
}

// ---------------- fold W blocks -> transposed bf16: WeffT[64][640] ----------------
__global__ void wefft_kernel(const float* __restrict__ W, unsigned short* __restrict__ Wt) {
    int i = blockIdx.x * blockDim.x + threadIdx.x;
    if (i >= 64 * 640) return;
    int n = i / 640, k = i % 640;
    float v;
    if (k < 128)      v = W[k * 64 + n] + W[(k + 384) * 64 + n];
    else if (k < 384) v = W[k * 64 + n];
    else              v = W[(k + 128) * 64 + n];
    Wt[(size_t)n * 640 + k] = (unsigned short)(bpack(v, 0.f) & 0xFFFFu);
}

// ---------------- final dense via MFMA: out = Xcat_bf16 @ WeffT^T + b ----------------
// R14 bug: srcs[t>>2] runtime-indexed pointer array -> scratch (rule #20) ->
// dependent scratch-load -> A-load -> MFMA chain each iter (MfmaUtil 3.5%).
// Fix: 5 statically-expanded panels (compile-time pointers) + 2 row-tiles/wave
// (block=128 rows, grid 782 -> 3 blocks/CU balanced). Unrolled 4-step panels
// let 8 A-loads + 16 B-loads issue ahead of the MFMA group.
__global__ __launch_bounds__(256) void gemm_mfma(
    const unsigned* __restrict__ XBF, const unsigned* __restrict__ H1FB,
    const unsigned* __restrict__ H2FB, const unsigned* __restrict__ H1RB,
    const unsigned* __restrict__ H2RB,
    const unsigned short* __restrict__ Wt,  // [64][640] bf16
    const float* __restrict__ bias, float* __restrict__ out, int N) {
    int wid = threadIdx.x >> 6;
    int lane = threadIdx.x & 63;
    int r = lane & 15;
    int kg = lane >> 4;                   // k-group: k offset kg*8
    int rowBase = blockIdx.x * 128 + wid * 32;  // wave: 2 row-tiles of 16
    int arow0 = rowBase + r;
    int arow1 = rowBase + 16 + r;
    f32x4 acc[2][4];
#pragma unroll
    for (int m = 0; m < 2; m++)
#pragma unroll
        for (int c = 0; c < 4; c++) acc[m][c] = (f32x4){0.f, 0.f, 0.f, 0.f};
    const bf16x8 zro = (bf16x8){0, 0, 0, 0, 0, 0, 0, 0};

#define PANEL(XP, KOFF)                                                          \
    {                                                                            \
        const unsigned short* xsrc = (const unsigned short*)(XP);                \
        _Pragma("unroll")                                                        \
        for (int tt = 0; tt < 4; ++tt) {                                         \
            int kb = tt * 32 + kg * 8;                                           \
            bf16x8 a0 = (arow0 < N) ? *(const bf16x8*)(xsrc + (size_t)arow0 * 128 + kb) : zro; \
            bf16x8 a1 = (arow1 < N) ? *(const bf16x8*)(xsrc + (size_t)arow1 * 128 + kb) : zro; \
            _Pragma("unroll")                                                    \
            for (int c = 0; c < 4; c++) {                                        \
                bf16x8 b = *(const bf16x8*)(Wt + (size_t)(c * 16 + r) * 640 + (KOFF) + kb); \
                acc[0][c] = __builtin_amdgcn_mfma_f32_16x16x32_bf16(a0, b, acc[0][c], 0, 0, 0); \
                acc[1][c] = __builtin_amdgcn_mfma_f32_16x16x32_bf16(a1, b, acc[1][c], 0, 0, 0); \
            }                                                                    \
        }                                                                        \
    }

    PANEL(XBF, 0)
    PANEL(H1FB, 128)
    PANEL(H2FB, 256)
    PANEL(H1RB, 384)
    PANEL(H2RB, 512)
#undef PANEL

#pragma unroll
    for (int m = 0; m < 2; m++)
#pragma unroll
        for (int c = 0; c < 4; c++) {
            int col = c * 16 + r;
            float bv = bias[col];
#pragma unroll
            for (int q = 0; q < 4; q++) {
                int row = rowBase + m * 16 + kg * 4 + q;
                if (row < N) out[(size_t)row * 64 + col] = acc[m][c][q] + bv;
            }
        }
}

extern "C" void kernel_launch(void* const* d_in, const int* in_sizes, int n_in,
                              void* d_out, int out_size, void* d_ws, size_t ws_size,
                              hipStream_t stream) {
    const float* feature = (const float*)d_in[0];
    const int*   eidx    = (const int*)d_in[1];
    const float* af_s    = (const float*)d_in[2];
    const float* af_d    = (const float*)d_in[3];
    const float* ar_s    = (const float*)d_in[4];
    const float* ar_d    = (const float*)d_in[5];
    const float* W       = (const float*)d_in[6];
    const float* bias    = (const float*)d_in[7];
    float* out = (float*)d_out;
    const int N = in_sizes[0] / F;
    const int E = in_sizes[1] / 2;
    const int* src = eidx;
    const int* dst = eidx + E;

    char* ws = (char*)d_ws;
    size_t off = 0;
    auto alloc = [&](size_t b) { size_t r = off; off = (off + b + 255) & ~(size_t)255; return r; };
    unsigned* xbf  = (unsigned*)(ws + alloc((size_t)N * 64 * 4));
    unsigned* h1fb = (unsigned*)(ws + alloc((size_t)N * 64 * 4));
    unsigned* h1rb = (unsigned*)(ws + alloc((size_t)N * 64 * 4));
    unsigned* h2fb = (unsigned*)(ws + alloc((size_t)N * 64 * 4));
    unsigned* h2rb = (unsigned*)(ws + alloc((size_t)N * 64 * 4));
    int*   rsF   = (int*)(ws + alloc((size_t)(N + 1) * 4));
    int*   rsR   = (int*)(ws + alloc((size_t)(N + 1) * 4));
    int*   colF  = (int*)(ws + alloc((size_t)E * 4));
    int*   colR  = (int*)(ws + alloc((size_t)E * 4));
    int*   rankF = (int*)(ws + alloc((size_t)E * 4));
    int*   rankR = (int*)(ws + alloc((size_t)E * 4));
    int*   ints2 = (int*)(ws + alloc((size_t)2 * N * 4));
    int *degF = ints2, *degR = ints2 + N;
    float* fls8 = (float*)(ws + alloc((size_t)8 * N * 4));
    float *sf = fls8, *df = fls8 + N, *sr = fls8 + 2 * (size_t)N, *dr = fls8 + 3 * (size_t)N;
    float *s2f = fls8 + 4 * (size_t)N, *d2f = fls8 + 5 * (size_t)N;
    float *s2r = fls8 + 6 * (size_t)N, *d2r = fls8 + 7 * (size_t)N;
    int*   bsums = (int*)(ws + alloc(256 * 4));
    unsigned short* WeffT = (unsigned short*)(ws + alloc(64 * 640 * 2));

    const int nb = (N + 1023) / 1024;
    zero_ints<<<(2 * N + 255) / 256, 256, 0, stream>>>(ints2, 2 * N);
    hist_kernel<<<(E + 255) / 256, 256, 0, stream>>>(src, dst, degF, degR, rankF, rankR, E);
    scan_pass1<<<dim3(nb, 2), 256, 0, stream>>>(degF, degR, rsF, rsR, bsums, N);
    scan_pass2<<<dim3(1, 2), 128, 0, stream>>>(bsums, nb);
    scan_pass3<<<dim3(nb, 2), 256, 0, stream>>>(rsF, rsR, bsums, N);
    scatter_kernel<<<(E + 255) / 256, 256, 0, stream>>>(src, dst, rsF, rsR, rankF, rankR,
                                                        colF, colR, E);
    sd4_kernel<<<(N + 3) / 4, 256, 0, stream>>>(feature, af_s, af_d, ar_s, ar_d,
                                                sf, df, sr, dr, xbf, N);

    // hop 1: gather bf16 feature (xbf), write bf16 h1 + fused next-hop dots
    AggDir F1{xbf, sf, df, rsF, colF, h1fb, af_s, af_d, s2f, d2f};
    AggDir R1{xbf, sr, dr, rsR, colR, h1rb, ar_s, ar_d, s2r, d2r};
    agg_kernel<<<dim3((N + 15) / 16, 2), 256, 0, stream>>>(F1, R1, N);
    // hop 2: gather bf16 h1, write bf16 h2
    AggDir F2{h1fb, s2f, d2f, rsF, colF, h2fb, nullptr, nullptr, nullptr, nullptr};
    AggDir R2{h1rb, s2r, d2r, rsR, colR, h2rb, nullptr, nullptr, nullptr, nullptr};
    agg_kernel<<<dim3((N + 15) / 16, 2), 256, 0, stream>>>(F2, R2, N);

    wefft_kernel<<<(64 * 640 + 255) / 256, 256, 0, stream>>>(W, WeffT);
    gemm_mfma<<<(N + 127) / 128, 256, 0, stream>>>(xbf, h1fb, h2fb, h1rb, h2rb,
                                                   WeffT, bias, out, N);
}

// Round 19
// 284.138 us; speedup vs baseline: 2.2580x; 1.0349x over previous
//
#include <hip/hip_runtime.h>
#include <math.h>

#define F 128
#define OUTDIM 64
#define NEG 0.2f

typedef __attribute__((ext_vector_type(8))) short bf16x8;
typedef __attribute__((ext_vector_type(4))) float f32x4;

// ---------------- bf16 helpers ----------------
__device__ __forceinline__ float blo(unsigned u) { return __uint_as_float(u << 16); }
__device__ __forceinline__ float bhi(unsigned u) { return __uint_as_float(u & 0xFFFF0000u); }
__device__ __forceinline__ unsigned bpack(float a, float b) {  // rtne both
    unsigned ua = __float_as_uint(a), ub = __float_as_uint(b);
    ua += 0x7FFFu + ((ua >> 16) & 1u);
    ub += 0x7FFFu + ((ub >> 16) & 1u);
    return (ua >> 16) | (ub & 0xFFFF0000u);
}

// ---------------- utility ----------------
__global__ void zero_ints(int* __restrict__ p, int n) {
    int i = blockIdx.x * blockDim.x + threadIdx.x;
    if (i < n) p[i] = 0;
}

// ---------------- CSR build ----------------
// hist records each edge's arrival rank (atomicAdd return) so scatter needs NO atomics.
__global__ void hist_kernel(const int* __restrict__ src, const int* __restrict__ dst,
                            int* __restrict__ degF, int* __restrict__ degR,
                            int* __restrict__ rankF, int* __restrict__ rankR, int E) {
    int e = blockIdx.x * blockDim.x + threadIdx.x;
    if (e < E) {
        rankF[e] = atomicAdd(&degF[dst[e]], 1);
        rankR[e] = atomicAdd(&degR[src[e]], 1);
    }
}

__global__ void scan_pass1(const int* __restrict__ degF, const int* __restrict__ degR,
                           int* __restrict__ rsF, int* __restrict__ rsR,
                           int* __restrict__ bsums, int N) {
    const int arr = blockIdx.y;
    const int* deg = arr ? degR : degF;
    int* rs = arr ? rsR : rsF;
    int tid = threadIdx.x;
    int base = blockIdx.x * 1024 + tid * 4;
    int v[4];
#pragma unroll
    for (int i = 0; i < 4; i++) v[i] = (base + i < N) ? deg[base + i] : 0;
    int s1 = v[0] + v[1] + v[2] + v[3];
    __shared__ int sd[256];
    sd[tid] = s1;
    __syncthreads();
    for (int off = 1; off < 256; off <<= 1) {
        int t = (tid >= off) ? sd[tid - off] : 0;
        __syncthreads();
        sd[tid] += t;
        __syncthreads();
    }
    int run = sd[tid] - s1;
#pragma unroll
    for (int i = 0; i < 4; i++) {
        run += v[i];
        if (base + i < N) rs[base + i + 1] = run;
    }
    if (tid == 255) bsums[arr * 128 + blockIdx.x] = sd[255];
    if (tid == 0 && blockIdx.x == 0) rs[0] = 0;
}

__global__ void scan_pass2(int* __restrict__ bsums, int nb) {
    int arr = blockIdx.y;
    int tid = threadIdx.x;  // 128
    __shared__ int sd[128];
    int v = (tid < nb) ? bsums[arr * 128 + tid] : 0;
    sd[tid] = v;
    __syncthreads();
    for (int off = 1; off < 128; off <<= 1) {
        int t = (tid >= off) ? sd[tid - off] : 0;
        __syncthreads();
        sd[tid] += t;
        __syncthreads();
    }
    bsums[arr * 128 + tid] = sd[tid];
}

__global__ void scan_pass3(int* __restrict__ rsF, int* __restrict__ rsR,
                           const int* __restrict__ bsums, int N) {
    int arr = blockIdx.y;
    if (blockIdx.x == 0) return;
    int* rs = arr ? rsR : rsF;
    int off = bsums[arr * 128 + blockIdx.x - 1];
    int base = blockIdx.x * 1024 + threadIdx.x * 4;
#pragma unroll
    for (int i = 0; i < 4; i++)
        if (base + i < N) rs[base + i + 1] += off;
}

// atomic-free: position = rs[node] + precomputed rank
__global__ void scatter_kernel(const int* __restrict__ src, const int* __restrict__ dst,
                               const int* __restrict__ rsF, const int* __restrict__ rsR,
                               const int* __restrict__ rankF, const int* __restrict__ rankR,
                               int* __restrict__ colF, int* __restrict__ colR, int E) {
    int e = blockIdx.x * blockDim.x + threadIdx.x;
    if (e < E) {
        int s = src[e], d = dst[e];
        colF[rsF[d] + rankF[e]] = s;
        colR[rsR[s] + rankR[e]] = d;
    }
}

// ---------------- per-node attention scalars + bf16 feature copy ----------------
__global__ void sd4_kernel(const float* __restrict__ x,
                           const float* __restrict__ af_s, const float* __restrict__ af_d,
                           const float* __restrict__ ar_s, const float* __restrict__ ar_d,
                           float* __restrict__ sf, float* __restrict__ df,
                           float* __restrict__ sr, float* __restrict__ dr,
                           unsigned* __restrict__ xbf, int N) {
    int node = blockIdx.x * 4 + (threadIdx.x >> 6);
    int lane = threadIdx.x & 63;
    if (node >= N) return;
    const float2 xv = *(const float2*)&x[(size_t)node * F + 2 * lane];
    xbf[(size_t)node * 64 + lane] = bpack(xv.x, xv.y);
    float2 a;
    a = *(const float2*)&af_s[2 * lane]; float vsf = xv.x * a.x + xv.y * a.y;
    a = *(const float2*)&af_d[2 * lane]; float vdf = xv.x * a.x + xv.y * a.y;
    a = *(const float2*)&ar_s[2 * lane]; float vsr = xv.x * a.x + xv.y * a.y;
    a = *(const float2*)&ar_d[2 * lane]; float vdr = xv.x * a.x + xv.y * a.y;
#pragma unroll
    for (int off = 32; off > 0; off >>= 1) {
        vsf += __shfl_xor(vsf, off);
        vdf += __shfl_xor(vdf, off);
        vsr += __shfl_xor(vsr, off);
        vdr += __shfl_xor(vdr, off);
    }
    if (lane == 0) { sf[node] = vsf; df[node] = vdf; sr[node] = vsr; dr[node] = vdr; }
}

// ---------------- fused dual-direction attention hop ----------------
// quarter-wave (16 lanes) per node; blockIdx.y selects direction.
// bf16 rows (256 B) -> 8-deep gather pipeline is only 8 x uint4 = 32 VGPR
// of staged data (R10 cut depth to 4 when rows were fp32/64 VGPR; R16 showed
// VGPR_Count=36 with headroom and BW at 3.2 of ~5 TB/s -> deepen for MLP).
struct AggDir {
    const unsigned* hin_bf;  // [N][64]  bf16x2
    const float* s;          // [N]
    const float* d;          // [N]
    const int* rs;           // [N+1]
    const int* col;          // [E]
    unsigned* hout_bf;       // [N][64]  bf16x2
    const float* a_s;        // nullable: fused next-hop dots
    const float* a_d;
    float* s_out;
    float* d_out;
};

__global__ __launch_bounds__(256) void agg_kernel(AggDir D0, AggDir D1, int N) {
    AggDir P = blockIdx.y ? D1 : D0;
    int node = blockIdx.x * 16 + (threadIdx.x >> 4);
    int lane = threadIdx.x & 15;           // within quarter-wave
    int qbase = threadIdx.x & 48;          // quarter offset inside the wave
    if (node >= N) return;
    float di = P.d[node];
    int beg = P.rs[node], end = P.rs[node + 1];
    int deg = end - beg;
    float m = -INFINITY, l = 0.f;
    float4 a0 = make_float4(0.f, 0.f, 0.f, 0.f);
    float4 a1 = make_float4(0.f, 0.f, 0.f, 0.f);

    for (int base = 0; base < deg; base += 16) {
        int cnt = min(16, deg - base);
        int sj_l = 0;
        float e_l = -INFINITY;
        if (lane < cnt) {
            sj_l = P.col[beg + base + lane];
            float e = P.s[sj_l] + di;
            e_l = (e >= 0.f) ? e : NEG * e;
        }
        float bm = e_l;
#pragma unroll
        for (int off = 8; off > 0; off >>= 1) bm = fmaxf(bm, __shfl_xor(bm, off));
        float nm = fmaxf(m, bm);
        float p_l = (lane < cnt) ? __expf(e_l - nm) : 0.f;
        float ps = p_l;
#pragma unroll
        for (int off = 8; off > 0; off >>= 1) ps += __shfl_xor(ps, off);
        float sc = (m == -INFINITY) ? 0.f : __expf(m - nm);
        l = l * sc + ps;
        a0.x *= sc; a0.y *= sc; a0.z *= sc; a0.w *= sc;
        a1.x *= sc; a1.y *= sc; a1.z *= sc; a1.w *= sc;
        // 8-deep gather: stage raw bf16x2 lines (uint4), convert at FMA time
        for (int j0 = 0; j0 < cnt; j0 += 8) {
            int sj[8]; float p[8]; uint4 hb[8];
#pragma unroll
            for (int u = 0; u < 8; u++) {
                sj[u] = __shfl(sj_l, qbase + j0 + u);
                p[u]  = __shfl(p_l,  qbase + j0 + u);
            }
#pragma unroll
            for (int u = 0; u < 8; u++) {
                if (j0 + u < cnt) {  // uniform per quarter-wave
                    hb[u] = *(const uint4*)&P.hin_bf[(size_t)sj[u] * 64 + 4 * lane];
                } else {
                    hb[u] = make_uint4(0u, 0u, 0u, 0u);
                }
            }
#pragma unroll
            for (int u = 0; u < 8; u++) {
                a0.x += p[u] * blo(hb[u].x); a0.y += p[u] * bhi(hb[u].x);
                a0.z += p[u] * blo(hb[u].y); a0.w += p[u] * bhi(hb[u].y);
                a1.x += p[u] * blo(hb[u].z); a1.y += p[u] * bhi(hb[u].z);
                a1.z += p[u] * blo(hb[u].w); a1.w += p[u] * bhi(hb[u].w);
            }
        }
        m = nm;
    }

    float4 o0, o1;
    if (deg > 0) {
        float inv = 1.f / (l + 1e-16f);
        o0.x = a0.x * inv; o0.y = a0.y * inv; o0.z = a0.z * inv; o0.w = a0.w * inv;
        o1.x = a1.x * inv; o1.y = a1.y * inv; o1.z = a1.z * inv; o1.w = a1.w * inv;
    } else {
        o0 = make_float4(0.f, 0.f, 0.f, 0.f);
        o1 = o0;
    }
    uint4 hb;
    hb.x = bpack(o0.x, o0.y); hb.y = bpack(o0.z, o0.w);
    hb.z = bpack(o1.x, o1.y); hb.w = bpack(o1.z, o1.w);
    *(uint4*)&P.hout_bf[(size_t)node * 64 + 4 * lane] = hb;
    if (P.a_s) {
        float4 b0, b1;
        b0 = *(const float4*)&P.a_s[8 * lane];
        b1 = *(const float4*)&P.a_s[8 * lane + 4];
        float vs = o0.x * b0.x + o0.y * b0.y + o0.z * b0.z + o0.w * b0.w
                 + o1.x * b1.x + o1.y * b1.y + o1.z * b1.z + o1.w * b1.w;
        b0 = *(const float4*)&P.a_d[8 * lane];
        b1 = *(const float4*)&P.a_d[8 * lane + 4];
        float vd = o0.x * b0.x + o0.y * b0.y + o0.z * b0.z + o0.w * b0.w
                 + o1.x * b1.x + o1.y * b1.y + o1.z * b1.z + o1.w * b1.w;
#pragma unroll
        for (int off = 8; off > 0; off >>= 1) {
            vs += __shfl_xor(vs, off);
            vd += __shfl_xor(vd, off);
        }
        if (lane == 0) { P.s_out[node] = vs; P.d_out[node] = vd; }
    }
}

// ---------------- fold W blocks -> transposed bf16: WeffT[64][640] ----------------
__global__ void wefft_kernel(const float* __restrict__ W, unsigned short* __restrict__ Wt) {
    int i = blockIdx.x * blockDim.x + threadIdx.x;
    if (i >= 64 * 640) return;
    int n = i / 640, k = i % 640;
    float v;
    if (k < 128)      v = W[k * 64 + n] + W[(k + 384) * 64 + n];
    else if (k < 384) v = W[k * 64 + n];
    else              v = W[(k + 128) * 64 + n];
    Wt[(size_t)n * 640 + k] = (unsigned short)(bpack(v, 0.f) & 0xFFFFu);
}

// ---------------- final dense via MFMA: out = Xcat_bf16 @ WeffT^T + b ----------------
// 5 statically-expanded panels (compile-time pointers, rule #20) + 2 row-tiles/wave.
__global__ __launch_bounds__(256) void gemm_mfma(
    const unsigned* __restrict__ XBF, const unsigned* __restrict__ H1FB,
    const unsigned* __restrict__ H2FB, const unsigned* __restrict__ H1RB,
    const unsigned* __restrict__ H2RB,
    const unsigned short* __restrict__ Wt,  // [64][640] bf16
    const float* __restrict__ bias, float* __restrict__ out, int N) {
    int wid = threadIdx.x >> 6;
    int lane = threadIdx.x & 63;
    int r = lane & 15;
    int kg = lane >> 4;                   // k-group: k offset kg*8
    int rowBase = blockIdx.x * 128 + wid * 32;  // wave: 2 row-tiles of 16
    int arow0 = rowBase + r;
    int arow1 = rowBase + 16 + r;
    f32x4 acc[2][4];
#pragma unroll
    for (int m = 0; m < 2; m++)
#pragma unroll
        for (int c = 0; c < 4; c++) acc[m][c] = (f32x4){0.f, 0.f, 0.f, 0.f};
    const bf16x8 zro = (bf16x8){0, 0, 0, 0, 0, 0, 0, 0};

#define PANEL(XP, KOFF)                                                          \
    {                                                                            \
        const unsigned short* xsrc = (const unsigned short*)(XP);                \
        _Pragma("unroll")                                                        \
        for (int tt = 0; tt < 4; ++tt) {                                         \
            int kb = tt * 32 + kg * 8;                                           \
            bf16x8 a0 = (arow0 < N) ? *(const bf16x8*)(xsrc + (size_t)arow0 * 128 + kb) : zro; \
            bf16x8 a1 = (arow1 < N) ? *(const bf16x8*)(xsrc + (size_t)arow1 * 128 + kb) : zro; \
            _Pragma("unroll")                                                    \
            for (int c = 0; c < 4; c++) {                                        \
                bf16x8 b = *(const bf16x8*)(Wt + (size_t)(c * 16 + r) * 640 + (KOFF) + kb); \
                acc[0][c] = __builtin_amdgcn_mfma_f32_16x16x32_bf16(a0, b, acc[0][c], 0, 0, 0); \
                acc[1][c] = __builtin_amdgcn_mfma_f32_16x16x32_bf16(a1, b, acc[1][c], 0, 0, 0); \
            }                                                                    \
        }                                                                        \
    }

    PANEL(XBF, 0)
    PANEL(H1FB, 128)
    PANEL(H2FB, 256)
    PANEL(H1RB, 384)
    PANEL(H2RB, 512)
#undef PANEL

#pragma unroll
    for (int m = 0; m < 2; m++)
#pragma unroll
        for (int c = 0; c < 4; c++) {
            int col = c * 16 + r;
            float bv = bias[col];
#pragma unroll
            for (int q = 0; q < 4; q++) {
                int row = rowBase + m * 16 + kg * 4 + q;
                if (row < N) out[(size_t)row * 64 + col] = acc[m][c][q] + bv;
            }
        }
}

extern "C" void kernel_launch(void* const* d_in, const int* in_sizes, int n_in,
                              void* d_out, int out_size, void* d_ws, size_t ws_size,
                              hipStream_t stream) {
    const float* feature = (const float*)d_in[0];
    const int*   eidx    = (const int*)d_in[1];
    const float* af_s    = (const float*)d_in[2];
    const float* af_d    = (const float*)d_in[3];
    const float* ar_s    = (const float*)d_in[4];
    const float* ar_d    = (const float*)d_in[5];
    const float* W       = (const float*)d_in[6];
    const float* bias    = (const float*)d_in[7];
    float* out = (float*)d_out;
    const int N = in_sizes[0] / F;
    const int E = in_sizes[1] / 2;
    const int* src = eidx;
    const int* dst = eidx + E;

    char* ws = (char*)d_ws;
    size_t off = 0;
    auto alloc = [&](size_t b) { size_t r = off; off = (off + b + 255) & ~(size_t)255; return r; };
    unsigned* xbf  = (unsigned*)(ws + alloc((size_t)N * 64 * 4));
    unsigned* h1fb = (unsigned*)(ws + alloc((size_t)N * 64 * 4));
    unsigned* h1rb = (unsigned*)(ws + alloc((size_t)N * 64 * 4));
    unsigned* h2fb = (unsigned*)(ws + alloc((size_t)N * 64 * 4));
    unsigned* h2rb = (unsigned*)(ws + alloc((size_t)N * 64 * 4));
    int*   rsF   = (int*)(ws + alloc((size_t)(N + 1) * 4));
    int*   rsR   = (int*)(ws + alloc((size_t)(N + 1) * 4));
    int*   colF  = (int*)(ws + alloc((size_t)E * 4));
    int*   colR  = (int*)(ws + alloc((size_t)E * 4));
    int*   rankF = (int*)(ws + alloc((size_t)E * 4));
    int*   rankR = (int*)(ws + alloc((size_t)E * 4));
    int*   ints2 = (int*)(ws + alloc((size_t)2 * N * 4));
    int *degF = ints2, *degR = ints2 + N;
    float* fls8 = (float*)(ws + alloc((size_t)8 * N * 4));
    float *sf = fls8, *df = fls8 + N, *sr = fls8 + 2 * (size_t)N, *dr = fls8 + 3 * (size_t)N;
    float *s2f = fls8 + 4 * (size_t)N, *d2f = fls8 + 5 * (size_t)N;
    float *s2r = fls8 + 6 * (size_t)N, *d2r = fls8 + 7 * (size_t)N;
    int*   bsums = (int*)(ws + alloc(256 * 4));
    unsigned short* WeffT = (unsigned short*)(ws + alloc(64 * 640 * 2));

    const int nb = (N + 1023) / 1024;
    zero_ints<<<(2 * N + 255) / 256, 256, 0, stream>>>(ints2, 2 * N);
    hist_kernel<<<(E + 255) / 256, 256, 0, stream>>>(src, dst, degF, degR, rankF, rankR, E);
    scan_pass1<<<dim3(nb, 2), 256, 0, stream>>>(degF, degR, rsF, rsR, bsums, N);
    scan_pass2<<<dim3(1, 2), 128, 0, stream>>>(bsums, nb);
    scan_pass3<<<dim3(nb, 2), 256, 0, stream>>>(rsF, rsR, bsums, N);
    scatter_kernel<<<(E + 255) / 256, 256, 0, stream>>>(src, dst, rsF, rsR, rankF, rankR,
                                                        colF, colR, E);
    sd4_kernel<<<(N + 3) / 4, 256, 0, stream>>>(feature, af_s, af_d, ar_s, ar_d,
                                                sf, df, sr, dr, xbf, N);

    // hop 1: gather bf16 feature (xbf), write bf16 h1 + fused next-hop dots
    AggDir F1{xbf, sf, df, rsF, colF, h1fb, af_s, af_d, s2f, d2f};
    AggDir R1{xbf, sr, dr, rsR, colR, h1rb, ar_s, ar_d, s2r, d2r};
    agg_kernel<<<dim3((N + 15) / 16, 2), 256, 0, stream>>>(F1, R1, N);
    // hop 2: gather bf16 h1, write bf16 h2
    AggDir F2{h1fb, s2f, d2f, rsF, colF, h2fb, nullptr, nullptr, nullptr, nullptr};
    AggDir R2{h1rb, s2r, d2r, rsR, colR, h2rb, nullptr, nullptr, nullptr, nullptr};
    agg_kernel<<<dim3((N + 15) / 16, 2), 256, 0, stream>>>(F2, R2, N);

    wefft_kernel<<<(64 * 640 + 255) / 256, 256, 0, stream>>>(W, WeffT);
    gemm_mfma<<<(N + 127) / 128, 256, 0, stream>>>(xbf, h1fb, h2fb, h1rb, h2rb,
                                                   WeffT, bias, out, N);
}